// Round 11
// baseline (236.176 us; speedup 1.0000x reference)
//
#include <hip/hip_runtime.h>
#include <hip/hip_bf16.h>
#include <math.h>

#define TT 8192
#define DD 512
#define HH 1024
#define EE 16
#define NSLOT 18432   // 144 * 128 max padded slots
#define MAXTILES 144
#define BM 128
#define RETRYCAP 1024

typedef __attribute__((ext_vector_type(8))) short bf16x8;
typedef __attribute__((ext_vector_type(8))) unsigned short u16x8;
typedef __attribute__((ext_vector_type(4))) float f32x4;

__device__ __forceinline__ unsigned short f2bf(float f) {
  union { float f; unsigned u; } v; v.f = f;
  unsigned r = v.u + 0x7fffu + ((v.u >> 16) & 1u);
  return (unsigned short)(r >> 16);
}

__device__ __forceinline__ float bf2f(unsigned short u) {
  union { unsigned u; float f; } v; v.u = ((unsigned)u) << 16;
  return v.f;
}

__device__ __forceinline__ void gload16(const void* g, void* l) {
  __builtin_amdgcn_global_load_lds(
      (const __attribute__((address_space(1))) unsigned int*)g,
      (__attribute__((address_space(3))) unsigned int*)l, 16, 0, 0);
}

// Abramowitz-Stegun 7.1.26 erf approx (|err| <= 1.5e-7)
__device__ __forceinline__ float gelu_f(float v) {
  float s = fabsf(v) * 0.70710678118654752f;
  float t = 1.0f / (1.0f + 0.3275911f * s);
  float poly = t * (0.254829592f +
              t * (-0.284496736f +
              t * (1.421413741f +
              t * (-1.453152027f +
              t * 1.061405429f))));
  float erfa = 1.0f - poly * __expf(-s * s);
  float erfv = (v >= 0.f) ? erfa : -erfa;
  return 0.5f * v * (1.0f + erfv);
}

// ------- transpose+convert: in f32 [nmat][R][C] -> out bf16 [nmat][C][R] -------
__global__ __launch_bounds__(256) void transpose_cv_kernel(
    const float* __restrict__ in, unsigned short* __restrict__ out, int R, int C) {
  int mat = blockIdx.z;
  int c0 = blockIdx.x * 64;
  int r0 = blockIdx.y * 64;
  const float* src = in + (size_t)mat * R * C;
  unsigned short* dst = out + (size_t)mat * R * C;
  __shared__ unsigned short t[64][68];
  int tid = threadIdx.x;
#pragma unroll
  for (int p = 0; p < 4; p++) {
    int r = tid >> 2;
    int c4 = (tid & 3) + p * 4;
    float4 v = *(const float4*)(src + (size_t)(r0 + r) * C + c0 + c4 * 4);
    t[c4 * 4 + 0][r] = f2bf(v.x);
    t[c4 * 4 + 1][r] = f2bf(v.y);
    t[c4 * 4 + 2][r] = f2bf(v.z);
    t[c4 * 4 + 3][r] = f2bf(v.w);
  }
  __syncthreads();
#pragma unroll
  for (int p = 0; p < 4; p++) {
    int oc = (tid >> 4) + p * 16;
    int ch = tid & 15;
    ushort4 v = *(ushort4*)(&t[oc][ch * 4]);
    *(ushort4*)(dst + (size_t)(c0 + oc) * R + r0 + ch * 4) = v;
  }
}

// ---------------- gate via MFMA (proven R8) ----------------
__global__ __launch_bounds__(256) void gate_mfma_kernel(
    const float* __restrict__ x, const float* __restrict__ Wg,
    const float* __restrict__ bg, unsigned short* __restrict__ xb,
    int* __restrict__ gate_e, float* __restrict__ gate_w,
    int* __restrict__ counts, int* __restrict__ nretry,
    int* __restrict__ retry) {
  __shared__ __align__(16) unsigned short As[128][40];
  __shared__ int cnt_s[EE];
  int tid = threadIdx.x;
  int lane = tid & 63;
  int wave = tid >> 6;
  int tok0 = blockIdx.x * 128;
  if (tid < EE) cnt_s[tid] = 0;
  int e = lane & 15;
  int kb = (lane >> 4) * 8;
  bf16x8 bfrag[16];
#pragma unroll
  for (int ks = 0; ks < 16; ks++) {
    int kbase = ks * 32 + kb;
#pragma unroll
    for (int j = 0; j < 8; j++)
      bfrag[ks][j] = (short)f2bf(Wg[(kbase + j) * EE + e]);
  }
  float bge = bg[e];
  f32x4 acc[2];
  {
    f32x4 z = {0.f, 0.f, 0.f, 0.f};
    acc[0] = z; acc[1] = z;
  }
  int srow = tid >> 1;
  int sc0 = (tid & 1) * 16;
  const float* xrow = x + (size_t)(tok0 + srow) * DD + sc0;
  unsigned short* xbrow = xb + (size_t)(tok0 + srow) * DD + sc0;
  for (int ks = 0; ks < 16; ks++) {
    int k0 = ks * 32;
    __syncthreads();
    float4 v0 = *(const float4*)(xrow + k0);
    float4 v1 = *(const float4*)(xrow + k0 + 4);
    float4 v2 = *(const float4*)(xrow + k0 + 8);
    float4 v3 = *(const float4*)(xrow + k0 + 12);
    u16x8 w0, w1;
    w0[0] = f2bf(v0.x); w0[1] = f2bf(v0.y); w0[2] = f2bf(v0.z); w0[3] = f2bf(v0.w);
    w0[4] = f2bf(v1.x); w0[5] = f2bf(v1.y); w0[6] = f2bf(v1.z); w0[7] = f2bf(v1.w);
    w1[0] = f2bf(v2.x); w1[1] = f2bf(v2.y); w1[2] = f2bf(v2.z); w1[3] = f2bf(v2.w);
    w1[4] = f2bf(v3.x); w1[5] = f2bf(v3.y); w1[6] = f2bf(v3.z); w1[7] = f2bf(v3.w);
    *(u16x8*)(xbrow + k0) = w0;
    *(u16x8*)(xbrow + k0 + 8) = w1;
    *(u16x8*)(&As[srow][sc0]) = w0;
    *(u16x8*)(&As[srow][sc0 + 8]) = w1;
    __syncthreads();
    bf16x8 a0 = *(const bf16x8*)(&As[wave * 32 + (lane & 15)][kb]);
    bf16x8 a1 = *(const bf16x8*)(&As[wave * 32 + 16 + (lane & 15)][kb]);
    acc[0] = __builtin_amdgcn_mfma_f32_16x16x32_bf16(a0, bfrag[ks], acc[0], 0, 0, 0);
    acc[1] = __builtin_amdgcn_mfma_f32_16x16x32_bf16(a1, bfrag[ks], acc[1], 0, 0, 0);
  }
#pragma unroll
  for (int m = 0; m < 2; m++) {
#pragma unroll
    for (int r = 0; r < 4; r++) {
      float lf = acc[m][r] + bge;
      float v1 = -1e30f, v2 = -1e30f, v3 = -1e30f;
      int i1 = 0, i2 = 0;
#pragma unroll
      for (int q = 0; q < EE; q++) {
        float v = __shfl(lf, (lane & 48) | q);
        if (v > v1) { v3 = v2; v2 = v1; i2 = i1; v1 = v; i1 = q; }
        else if (v > v2) { v3 = v2; v2 = v; i2 = q; }
        else if (v > v3) { v3 = v; }
      }
      if ((lane & 15) == 0) {
        int t2 = tok0 + wave * 32 + m * 16 + ((lane >> 4) << 2) + r;
        float p = expf(v2 - v1);
        float s = 1.0f / (1.0f + p);
        gate_e[t2 * 2] = i1;
        gate_e[t2 * 2 + 1] = i2;
        gate_w[t2 * 2] = s;
        gate_w[t2 * 2 + 1] = p * s;
        atomicAdd(&cnt_s[i1], 1);
        atomicAdd(&cnt_s[i2], 1);
        if (v2 - v3 < 0.02f) {
          int pos = atomicAdd(nretry, 1);
          if (pos < RETRYCAP) retry[pos] = t2;
        }
      }
    }
  }
  __syncthreads();
  if (tid < EE) atomicAdd(&counts[tid], cnt_s[tid]);
}

// ---------------- gatefix: exact f64 recompute for near-tie tokens ----------
__global__ __launch_bounds__(256) void gatefix_kernel(
    const float* __restrict__ x, const float* __restrict__ Wg,
    const float* __restrict__ bg, const int* __restrict__ nretry,
    const int* __restrict__ retry, int* __restrict__ gate_e,
    float* __restrict__ gate_w, int* __restrict__ counts) {
  __shared__ float lg[16][17];
  __shared__ int toks[16];
  int tid = threadIdx.x;
  int sl = tid >> 4, e = tid & 15;
  int s = blockIdx.x * 16 + sl;
  int n = *nretry; if (n > RETRYCAP) n = RETRYCAP;
  int active = (s < n);
  int tok = 0;
  if (active) tok = retry[s];
  if (active) {
    const float* xr = x + (size_t)tok * DD;
    double a0 = 0.0, a1 = 0.0, a2 = 0.0, a3 = 0.0;
    for (int i = 0; i < DD / 4; i++) {
      a0 += (double)xr[i * 4 + 0] * (double)Wg[(i * 4 + 0) * EE + e];
      a1 += (double)xr[i * 4 + 1] * (double)Wg[(i * 4 + 1) * EE + e];
      a2 += (double)xr[i * 4 + 2] * (double)Wg[(i * 4 + 2) * EE + e];
      a3 += (double)xr[i * 4 + 3] * (double)Wg[(i * 4 + 3) * EE + e];
    }
    double acc = (a0 + a1) + (a2 + a3);
    lg[sl][e] = (float)(acc + (double)bg[e]);
    toks[sl] = tok;
  }
  __syncthreads();
  if (active && e == 0) {
    float v1 = -1e30f, v2 = -1e30f;
    int i1 = 0, i2 = 0;
#pragma unroll
    for (int q = 0; q < EE; q++) {
      float v = lg[sl][q];
      if (v > v1) { v2 = v1; i2 = i1; v1 = v; i1 = q; }
      else if (v > v2) { v2 = v; i2 = q; }
    }
    int t2 = toks[sl];
    int o1 = gate_e[t2 * 2], o2 = gate_e[t2 * 2 + 1];
    float p = expf(v2 - v1);
    float sc = 1.0f / (1.0f + p);
    gate_e[t2 * 2] = i1;
    gate_e[t2 * 2 + 1] = i2;
    gate_w[t2 * 2] = sc;
    gate_w[t2 * 2 + 1] = p * sc;
    if (o1 != i1 || o2 != i2) {
      atomicSub(&counts[o1], 1);
      atomicSub(&counts[o2], 1);
      atomicAdd(&counts[i1], 1);
      atomicAdd(&counts[i2], 1);
    }
  }
}

// ---------------- scan: offsets + tile map (tiny) ----------------
__global__ void scan_kernel(const int* __restrict__ counts, int* __restrict__ offs,
                            int* __restrict__ tile_expert, int* __restrict__ ntiles,
                            int* __restrict__ fill) {
  if (threadIdx.x == 0) {
    int off = 0, nt = 0;
    for (int e = 0; e < EE; e++) {
      offs[e] = off;
      fill[e] = 0;
      int tiles = (counts[e] + BM - 1) / BM;
      for (int t = 0; t < tiles; t++) tile_expert[nt++] = e;
      off += tiles * BM;
    }
    offs[EE] = off;
    ntiles[0] = nt;
  }
}

// ---------------- scatter: parallel, global fill atomics ----------------
__global__ __launch_bounds__(256) void scatter_kernel(
    const int* __restrict__ gate_e, const float* __restrict__ gate_w,
    const int* __restrict__ offs, int* __restrict__ fill,
    int* __restrict__ slot_token, float* __restrict__ slot_w,
    int* __restrict__ slot_of) {
  int t = blockIdx.x * blockDim.x + threadIdx.x;
  if (t >= TT) return;
#pragma unroll
  for (int k = 0; k < 2; k++) {
    int e = gate_e[t * 2 + k];
    int pos = atomicAdd(&fill[e], 1);
    int slot = offs[e] + pos;
    slot_token[slot] = t;
    slot_w[slot] = gate_w[t * 2 + k];
    slot_of[t * 2 + k] = slot;
  }
}

// ---------------- GEMM1: 128x128 tile, BK=64 via 2 sub-buffers ----------------
// h = gelu(x[slot] @ W1[e] + b1[e]); grid (HH/128, MAXTILES)
// As[j] holds k-subchunk j (32 wide, 64B rows: conflict-free fragment reads).
__global__ __launch_bounds__(256) void gemm1_kernel(
    const unsigned short* __restrict__ xb, const unsigned short* __restrict__ w1t,
    const float* __restrict__ b1, const int* __restrict__ slot_token,
    const int* __restrict__ tile_expert, const int* __restrict__ ntiles,
    unsigned short* __restrict__ hb) {
  int mt = blockIdx.y;
  if (mt >= ntiles[0]) return;
  int e = tile_expert[mt];
  int row0 = mt * BM;
  int n0 = blockIdx.x * 128;
  __shared__ unsigned short As[2][128][32];  // 16 KB
  __shared__ unsigned short Bs[2][128][32];  // 16 KB
  int tid = threadIdx.x;
  int lane = tid & 63;
  int wave = tid >> 6;
  int wm = wave >> 1, wn = wave & 1;
  int ra = tid >> 2, c = tid & 3;
  int tok_a = slot_token[row0 + ra]; if (tok_a < 0) tok_a = 0;
  int tok_b = slot_token[row0 + ra + 64]; if (tok_b < 0) tok_b = 0;
  const unsigned short* wbase = w1t + ((size_t)e * HH * DD);
  const unsigned short* gA0 = xb + (size_t)tok_a * DD + c * 8;
  const unsigned short* gA1 = xb + (size_t)tok_b * DD + c * 8;
  const unsigned short* gB0 = wbase + (size_t)(n0 + ra) * DD + c * 8;
  const unsigned short* gB1 = wbase + (size_t)(n0 + ra + 64) * DD + c * 8;
  f32x4 acc[4][4];
#pragma unroll
  for (int m = 0; m < 4; m++)
#pragma unroll
    for (int n = 0; n < 4; n++) {
      f32x4 z = {0.f, 0.f, 0.f, 0.f};
      acc[m][n] = z;
    }
  for (int kk = 0; kk < DD / 64; kk++) {
    int k0 = kk * 64;
    __syncthreads();
#pragma unroll
    for (int j = 0; j < 2; j++) {
      int kj = k0 + j * 32;
      gload16(gA0 + kj, &As[j][ra][c * 8]);
      gload16(gA1 + kj, &As[j][ra + 64][c * 8]);
      gload16(gB0 + kj, &Bs[j][ra][c * 8]);
      gload16(gB1 + kj, &Bs[j][ra + 64][c * 8]);
    }
    __syncthreads();
#pragma unroll
    for (int ks = 0; ks < 2; ks++) {
      bf16x8 a[4], b[4];
#pragma unroll
      for (int m = 0; m < 4; m++)
        a[m] = *(const bf16x8*)(&As[ks][wm * 64 + m * 16 + (lane & 15)][(lane >> 4) * 8]);
#pragma unroll
      for (int n = 0; n < 4; n++)
        b[n] = *(const bf16x8*)(&Bs[ks][wn * 64 + n * 16 + (lane & 15)][(lane >> 4) * 8]);
#pragma unroll
      for (int m = 0; m < 4; m++)
#pragma unroll
        for (int n = 0; n < 4; n++)
          acc[m][n] = __builtin_amdgcn_mfma_f32_16x16x32_bf16(a[m], b[n], acc[m][n], 0, 0, 0);
    }
  }
  const float* b1e = b1 + (size_t)e * HH;
#pragma unroll
  for (int m = 0; m < 4; m++) {
#pragma unroll
    for (int r = 0; r < 4; r++) {
      int slot = row0 + wm * 64 + m * 16 + ((lane >> 4) << 2) + r;
      unsigned short* hrow = hb + (size_t)slot * HH;
#pragma unroll
      for (int n = 0; n < 4; n++) {
        int hc = n0 + wn * 64 + n * 16 + (lane & 15);
        float v = acc[m][n][r] + b1e[hc];
        hrow[hc] = f2bf(gelu_f(v));
      }
    }
  }
}

// ---------------- GEMM2: 128x128 tile, BK=64 via 2 sub-buffers ----------------
// yw[slot] = w*(h[slot] @ W2[e] + b2[e]); grid (DD/128, MAXTILES)
template <int USE_Y>
__global__ __launch_bounds__(256) void gemm2_kernel(
    const unsigned short* __restrict__ hb, const unsigned short* __restrict__ w2t,
    const float* __restrict__ b2, const int* __restrict__ slot_token,
    const float* __restrict__ slot_w, const int* __restrict__ tile_expert,
    const int* __restrict__ ntiles, unsigned short* __restrict__ yw,
    float* __restrict__ out) {
  int mt = blockIdx.y;
  if (mt >= ntiles[0]) return;
  int e = tile_expert[mt];
  int row0 = mt * BM;
  int n0 = blockIdx.x * 128;
  __shared__ unsigned short As[2][128][32];
  __shared__ unsigned short Bs[2][128][32];
  int tid = threadIdx.x;
  int lane = tid & 63;
  int wave = tid >> 6;
  int wm = wave >> 1, wn = wave & 1;
  int ra = tid >> 2, c = tid & 3;
  const unsigned short* wbase = w2t + ((size_t)e * DD * HH);
  const unsigned short* gA0 = hb + (size_t)(row0 + ra) * HH + c * 8;
  const unsigned short* gA1 = hb + (size_t)(row0 + ra + 64) * HH + c * 8;
  const unsigned short* gB0 = wbase + (size_t)(n0 + ra) * HH + c * 8;
  const unsigned short* gB1 = wbase + (size_t)(n0 + ra + 64) * HH + c * 8;
  f32x4 acc[4][4];
#pragma unroll
  for (int m = 0; m < 4; m++)
#pragma unroll
    for (int n = 0; n < 4; n++) {
      f32x4 z = {0.f, 0.f, 0.f, 0.f};
      acc[m][n] = z;
    }
  for (int kk = 0; kk < HH / 64; kk++) {
    int k0 = kk * 64;
    __syncthreads();
#pragma unroll
    for (int j = 0; j < 2; j++) {
      int kj = k0 + j * 32;
      gload16(gA0 + kj, &As[j][ra][c * 8]);
      gload16(gA1 + kj, &As[j][ra + 64][c * 8]);
      gload16(gB0 + kj, &Bs[j][ra][c * 8]);
      gload16(gB1 + kj, &Bs[j][ra + 64][c * 8]);
    }
    __syncthreads();
#pragma unroll
    for (int ks = 0; ks < 2; ks++) {
      bf16x8 a[4], b[4];
#pragma unroll
      for (int m = 0; m < 4; m++)
        a[m] = *(const bf16x8*)(&As[ks][wm * 64 + m * 16 + (lane & 15)][(lane >> 4) * 8]);
#pragma unroll
      for (int n = 0; n < 4; n++)
        b[n] = *(const bf16x8*)(&Bs[ks][wn * 64 + n * 16 + (lane & 15)][(lane >> 4) * 8]);
#pragma unroll
      for (int m = 0; m < 4; m++)
#pragma unroll
        for (int n = 0; n < 4; n++)
          acc[m][n] = __builtin_amdgcn_mfma_f32_16x16x32_bf16(a[m], b[n], acc[m][n], 0, 0, 0);
    }
  }
  const float* b2e = b2 + (size_t)e * DD;
#pragma unroll
  for (int m = 0; m < 4; m++) {
#pragma unroll
    for (int r = 0; r < 4; r++) {
      int slot = row0 + wm * 64 + m * 16 + ((lane >> 4) << 2) + r;
      if (USE_Y) {
        float w = slot_w[slot];
        unsigned short* yrow = yw + (size_t)slot * DD;
#pragma unroll
        for (int n = 0; n < 4; n++) {
          int dc = n0 + wn * 64 + n * 16 + (lane & 15);
          yrow[dc] = f2bf(w * (acc[m][n][r] + b2e[dc]));
        }
      } else {
        int tok = slot_token[slot];
        if (tok >= 0) {
          float w = slot_w[slot];
          float* orow = out + (size_t)tok * DD;
#pragma unroll
          for (int n = 0; n < 4; n++) {
            int dc = n0 + wn * 64 + n * 16 + (lane & 15);
            float v = acc[m][n][r] + b2e[dc];
            atomicAdd(&orow[dc], w * v);
          }
        }
      }
    }
  }
}

// ---------------- combine: out[t] = yw[s1] + yw[s2] ----------------
__global__ __launch_bounds__(256) void combine_kernel(
    const unsigned short* __restrict__ yw, const int* __restrict__ slot_of,
    float* __restrict__ out) {
  int gid = blockIdx.x * 256 + threadIdx.x;
  int t = gid >> 6;
  int d0 = (gid & 63) * 8;
  int s1 = slot_of[t * 2], s2 = slot_of[t * 2 + 1];
  const ushort4* p1 = (const ushort4*)(yw + (size_t)s1 * DD + d0);
  const ushort4* p2 = (const ushort4*)(yw + (size_t)s2 * DD + d0);
  ushort4 a0 = p1[0], a1 = p1[1];
  ushort4 b0 = p2[0], b1 = p2[1];
  float4 o0, o1;
  o0.x = bf2f(a0.x) + bf2f(b0.x);
  o0.y = bf2f(a0.y) + bf2f(b0.y);
  o0.z = bf2f(a0.z) + bf2f(b0.z);
  o0.w = bf2f(a0.w) + bf2f(b0.w);
  o1.x = bf2f(a1.x) + bf2f(b1.x);
  o1.y = bf2f(a1.y) + bf2f(b1.y);
  o1.z = bf2f(a1.z) + bf2f(b1.z);
  o1.w = bf2f(a1.w) + bf2f(b1.w);
  float* orow = out + (size_t)t * DD + d0;
  ((float4*)orow)[0] = o0;
  ((float4*)orow)[1] = o1;
}

extern "C" void kernel_launch(void* const* d_in, const int* in_sizes, int n_in,
                              void* d_out, int out_size, void* d_ws, size_t ws_size,
                              hipStream_t stream) {
  const float* x  = (const float*)d_in[0];
  const float* Wg = (const float*)d_in[1];
  const float* bg = (const float*)d_in[2];
  const float* W1 = (const float*)d_in[3];
  const float* b1 = (const float*)d_in[4];
  const float* W2 = (const float*)d_in[5];
  const float* b2 = (const float*)d_in[6];
  float* out = (float*)d_out;

  uint8_t* w = (uint8_t*)d_ws;
  size_t o = 0;
  unsigned short* xb  = (unsigned short*)(w + o); o += (size_t)TT * DD * 2;       // 8 MB
  unsigned short* w1t = (unsigned short*)(w + o); o += (size_t)EE * DD * HH * 2;  // 16 MB
  unsigned short* w2t = (unsigned short*)(w + o); o += (size_t)EE * DD * HH * 2;  // 16 MB
  unsigned short* hb  = (unsigned short*)(w + o); o += (size_t)NSLOT * HH * 2;    // 37.7 MB
  int*   slot_token = (int*)(w + o);   o += (size_t)NSLOT * 4;
  float* slot_w     = (float*)(w + o); o += (size_t)NSLOT * 4;
  int*   slot_of    = (int*)(w + o);   o += (size_t)TT * 2 * 4;
  int*   gate_e     = (int*)(w + o);   o += (size_t)TT * 2 * 4;
  float* gate_w     = (float*)(w + o); o += (size_t)TT * 2 * 4;
  int*   counts     = (int*)(w + o);   o += 64;   // counts[16]
  int*   nretry     = (int*)(w + o);   o += 64;   // adjacent: one 128B memset
  int*   tile_expert= (int*)(w + o);   o += 640;
  int*   ntiles     = (int*)(w + o);   o += 64;
  int*   offs       = (int*)(w + o);   o += 128;
  int*   fill       = (int*)(w + o);   o += 64;
  int*   retry      = (int*)(w + o);   o += RETRYCAP * 4;
  unsigned short* yw = (unsigned short*)(w + o);
  size_t need_y = o + (size_t)NSLOT * DD * 2;   // +18.9 MB
  int use_y = (ws_size >= need_y);

  hipMemsetAsync(counts, 0, 128, stream);  // counts + nretry
  hipMemsetAsync(slot_token, 0xFF, (size_t)NSLOT * 4, stream);
  if (!use_y) hipMemsetAsync(d_out, 0, (size_t)TT * DD * 4, stream);

  // W1 [E][512][1024] -> w1t [E][1024][512]
  {
    dim3 g(HH / 64, DD / 64, EE);
    transpose_cv_kernel<<<g, 256, 0, stream>>>(W1, w1t, DD, HH);
  }
  // W2 [E][1024][512] -> w2t [E][512][1024]
  {
    dim3 g(DD / 64, HH / 64, EE);
    transpose_cv_kernel<<<g, 256, 0, stream>>>(W2, w2t, HH, DD);
  }
  gate_mfma_kernel<<<TT / 128, 256, 0, stream>>>(x, Wg, bg, xb, gate_e, gate_w,
                                                 counts, nretry, retry);
  gatefix_kernel<<<RETRYCAP / 16, 256, 0, stream>>>(x, Wg, bg, nretry, retry,
                                                    gate_e, gate_w, counts);
  scan_kernel<<<1, 64, 0, stream>>>(counts, offs, tile_expert, ntiles, fill);
  scatter_kernel<<<TT / 256, 256, 0, stream>>>(gate_e, gate_w, offs, fill,
                                               slot_token, slot_w, slot_of);
  {
    dim3 g(HH / 128, MAXTILES);
    gemm1_kernel<<<g, 256, 0, stream>>>(xb, w1t, b1, slot_token, tile_expert, ntiles, hb);
  }
  {
    dim3 g(DD / 128, MAXTILES);
    if (use_y)
      gemm2_kernel<1><<<g, 256, 0, stream>>>(hb, w2t, b2, slot_token, slot_w,
                                             tile_expert, ntiles, yw, out);
    else
      gemm2_kernel<0><<<g, 256, 0, stream>>>(hb, w2t, b2, slot_token, slot_w,
                                             tile_expert, ntiles, yw, out);
  }
  if (use_y) {
    combine_kernel<<<TT * (DD / 8) / 256, 256, 0, stream>>>(yw, slot_of, out);
  }
}

// Round 12
// 223.051 us; speedup vs baseline: 1.0588x; 1.0588x over previous
//
#include <hip/hip_runtime.h>
#include <hip/hip_bf16.h>
#include <math.h>

#define TT 8192
#define DD 512
#define HH 1024
#define EE 16
#define NSLOT 18432   // 144 * 128 max padded slots
#define MAXTILES 144
#define BM 128
#define RETRYCAP 1024

typedef __attribute__((ext_vector_type(8))) short bf16x8;
typedef __attribute__((ext_vector_type(8))) unsigned short u16x8;
typedef __attribute__((ext_vector_type(4))) float f32x4;

__device__ __forceinline__ unsigned short f2bf(float f) {
  union { float f; unsigned u; } v; v.f = f;
  unsigned r = v.u + 0x7fffu + ((v.u >> 16) & 1u);
  return (unsigned short)(r >> 16);
}

__device__ __forceinline__ float bf2f(unsigned short u) {
  union { unsigned u; float f; } v; v.u = ((unsigned)u) << 16;
  return v.f;
}

__device__ __forceinline__ void gload16(const void* g, void* l) {
  __builtin_amdgcn_global_load_lds(
      (const __attribute__((address_space(1))) unsigned int*)g,
      (__attribute__((address_space(3))) unsigned int*)l, 16, 0, 0);
}

// Abramowitz-Stegun 7.1.26 erf approx (|err| <= 1.5e-7)
__device__ __forceinline__ float gelu_f(float v) {
  float s = fabsf(v) * 0.70710678118654752f;
  float t = 1.0f / (1.0f + 0.3275911f * s);
  float poly = t * (0.254829592f +
              t * (-0.284496736f +
              t * (1.421413741f +
              t * (-1.453152027f +
              t * 1.061405429f))));
  float erfa = 1.0f - poly * __expf(-s * s);
  float erfv = (v >= 0.f) ? erfa : -erfa;
  return 0.5f * v * (1.0f + erfv);
}

// ---------------- prep: W1-transpose | W2-transpose | MFMA-gate, one launch --
// LDS union is ~10.2 KB (unlike R7's 49.6 KB) -> no occupancy damage.
struct GateSm {
  unsigned short As[128][40];  // 10240 B
  int cnt[EE];
};
union __align__(16) PrepSm {
  unsigned short t[64][68];    // 8704 B
  GateSm g;
};

__device__ __forceinline__ void transpose_body(
    const float* __restrict__ src, unsigned short* __restrict__ dst,
    int R, int C, int c0, int r0, unsigned short (*t)[68], int tid) {
#pragma unroll
  for (int p = 0; p < 4; p++) {
    int r = tid >> 2;
    int c4 = (tid & 3) + p * 4;
    float4 v = *(const float4*)(src + (size_t)(r0 + r) * C + c0 + c4 * 4);
    t[c4 * 4 + 0][r] = f2bf(v.x);
    t[c4 * 4 + 1][r] = f2bf(v.y);
    t[c4 * 4 + 2][r] = f2bf(v.z);
    t[c4 * 4 + 3][r] = f2bf(v.w);
  }
  __syncthreads();
#pragma unroll
  for (int p = 0; p < 4; p++) {
    int oc = (tid >> 4) + p * 16;
    int ch = tid & 15;
    ushort4 v = *(ushort4*)(&t[oc][ch * 4]);
    *(ushort4*)(dst + (size_t)(c0 + oc) * R + r0 + ch * 4) = v;
  }
}

__global__ __launch_bounds__(256) void prep_kernel(
    const float* __restrict__ W1, const float* __restrict__ W2,
    unsigned short* __restrict__ w1t, unsigned short* __restrict__ w2t,
    const float* __restrict__ x, const float* __restrict__ Wg,
    const float* __restrict__ bg, unsigned short* __restrict__ xb,
    int* __restrict__ gate_e, float* __restrict__ gate_w,
    int* __restrict__ counts, int* __restrict__ nretry,
    int* __restrict__ retry) {
  __shared__ PrepSm sm;
  int bid = blockIdx.x;
  int tid = threadIdx.x;
  if (bid < 2048) {
    // W1 [E][512][1024] -> w1t [E][1024][512]
    int cx = bid & 15, ry = (bid >> 4) & 7, mat = bid >> 7;
    transpose_body(W1 + (size_t)mat * DD * HH, w1t + (size_t)mat * DD * HH,
                   DD, HH, cx * 64, ry * 64, sm.t, tid);
    return;
  }
  if (bid < 4096) {
    // W2 [E][1024][512] -> w2t [E][512][1024]
    int b = bid - 2048;
    int cx = b & 7, ry = (b >> 3) & 15, mat = b >> 7;
    transpose_body(W2 + (size_t)mat * DD * HH, w2t + (size_t)mat * DD * HH,
                   HH, DD, cx * 64, ry * 64, sm.t, tid);
    return;
  }
  // ---- MFMA gate (proven R8 body): 128 tokens/block ----
  unsigned short (*As)[40] = sm.g.As;
  int* cnt_s = sm.g.cnt;
  int lane = tid & 63;
  int wave = tid >> 6;
  int tok0 = (bid - 4096) * 128;
  if (tid < EE) cnt_s[tid] = 0;
  int e = lane & 15;
  int kb = (lane >> 4) * 8;
  bf16x8 bfrag[16];
#pragma unroll
  for (int ks = 0; ks < 16; ks++) {
    int kbase = ks * 32 + kb;
#pragma unroll
    for (int j = 0; j < 8; j++)
      bfrag[ks][j] = (short)f2bf(Wg[(kbase + j) * EE + e]);
  }
  float bge = bg[e];
  f32x4 acc[2];
  {
    f32x4 z = {0.f, 0.f, 0.f, 0.f};
    acc[0] = z; acc[1] = z;
  }
  int srow = tid >> 1;
  int sc0 = (tid & 1) * 16;
  const float* xrow = x + (size_t)(tok0 + srow) * DD + sc0;
  unsigned short* xbrow = xb + (size_t)(tok0 + srow) * DD + sc0;
  for (int ks = 0; ks < 16; ks++) {
    int k0 = ks * 32;
    __syncthreads();
    float4 v0 = *(const float4*)(xrow + k0);
    float4 v1 = *(const float4*)(xrow + k0 + 4);
    float4 v2 = *(const float4*)(xrow + k0 + 8);
    float4 v3 = *(const float4*)(xrow + k0 + 12);
    u16x8 w0, w1;
    w0[0] = f2bf(v0.x); w0[1] = f2bf(v0.y); w0[2] = f2bf(v0.z); w0[3] = f2bf(v0.w);
    w0[4] = f2bf(v1.x); w0[5] = f2bf(v1.y); w0[6] = f2bf(v1.z); w0[7] = f2bf(v1.w);
    w1[0] = f2bf(v2.x); w1[1] = f2bf(v2.y); w1[2] = f2bf(v2.z); w1[3] = f2bf(v2.w);
    w1[4] = f2bf(v3.x); w1[5] = f2bf(v3.y); w1[6] = f2bf(v3.z); w1[7] = f2bf(v3.w);
    *(u16x8*)(xbrow + k0) = w0;
    *(u16x8*)(xbrow + k0 + 8) = w1;
    *(u16x8*)(&As[srow][sc0]) = w0;
    *(u16x8*)(&As[srow][sc0 + 8]) = w1;
    __syncthreads();
    bf16x8 a0 = *(const bf16x8*)(&As[wave * 32 + (lane & 15)][kb]);
    bf16x8 a1 = *(const bf16x8*)(&As[wave * 32 + 16 + (lane & 15)][kb]);
    acc[0] = __builtin_amdgcn_mfma_f32_16x16x32_bf16(a0, bfrag[ks], acc[0], 0, 0, 0);
    acc[1] = __builtin_amdgcn_mfma_f32_16x16x32_bf16(a1, bfrag[ks], acc[1], 0, 0, 0);
  }
#pragma unroll
  for (int m = 0; m < 2; m++) {
#pragma unroll
    for (int r = 0; r < 4; r++) {
      float lf = acc[m][r] + bge;
      float v1 = -1e30f, v2 = -1e30f, v3 = -1e30f;
      int i1 = 0, i2 = 0;
#pragma unroll
      for (int q = 0; q < EE; q++) {
        float v = __shfl(lf, (lane & 48) | q);
        if (v > v1) { v3 = v2; v2 = v1; i2 = i1; v1 = v; i1 = q; }
        else if (v > v2) { v3 = v2; v2 = v; i2 = q; }
        else if (v > v3) { v3 = v; }
      }
      if ((lane & 15) == 0) {
        int t2 = tok0 + wave * 32 + m * 16 + ((lane >> 4) << 2) + r;
        float p = expf(v2 - v1);
        float s = 1.0f / (1.0f + p);
        gate_e[t2 * 2] = i1;
        gate_e[t2 * 2 + 1] = i2;
        gate_w[t2 * 2] = s;
        gate_w[t2 * 2 + 1] = p * s;
        atomicAdd(&cnt_s[i1], 1);
        atomicAdd(&cnt_s[i2], 1);
        if (v2 - v3 < 0.02f) {
          int pos = atomicAdd(nretry, 1);
          if (pos < RETRYCAP) retry[pos] = t2;
        }
      }
    }
  }
  __syncthreads();
  if (tid < EE) atomicAdd(&counts[tid], cnt_s[tid]);
}

// ---------------- gatefix: exact f64 recompute for near-tie tokens ----------
__global__ __launch_bounds__(256) void gatefix_kernel(
    const float* __restrict__ x, const float* __restrict__ Wg,
    const float* __restrict__ bg, const int* __restrict__ nretry,
    const int* __restrict__ retry, int* __restrict__ gate_e,
    float* __restrict__ gate_w, int* __restrict__ counts) {
  __shared__ float lg[16][17];
  __shared__ int toks[16];
  int tid = threadIdx.x;
  int sl = tid >> 4, e = tid & 15;
  int s = blockIdx.x * 16 + sl;
  int n = *nretry; if (n > RETRYCAP) n = RETRYCAP;
  int active = (s < n);
  int tok = 0;
  if (active) tok = retry[s];
  if (active) {
    const float* xr = x + (size_t)tok * DD;
    double a0 = 0.0, a1 = 0.0, a2 = 0.0, a3 = 0.0;
    for (int i = 0; i < DD / 4; i++) {
      a0 += (double)xr[i * 4 + 0] * (double)Wg[(i * 4 + 0) * EE + e];
      a1 += (double)xr[i * 4 + 1] * (double)Wg[(i * 4 + 1) * EE + e];
      a2 += (double)xr[i * 4 + 2] * (double)Wg[(i * 4 + 2) * EE + e];
      a3 += (double)xr[i * 4 + 3] * (double)Wg[(i * 4 + 3) * EE + e];
    }
    double acc = (a0 + a1) + (a2 + a3);
    lg[sl][e] = (float)(acc + (double)bg[e]);
    toks[sl] = tok;
  }
  __syncthreads();
  if (active && e == 0) {
    float v1 = -1e30f, v2 = -1e30f;
    int i1 = 0, i2 = 0;
#pragma unroll
    for (int q = 0; q < EE; q++) {
      float v = lg[sl][q];
      if (v > v1) { v2 = v1; i2 = i1; v1 = v; i1 = q; }
      else if (v > v2) { v2 = v; i2 = q; }
    }
    int t2 = toks[sl];
    int o1 = gate_e[t2 * 2], o2 = gate_e[t2 * 2 + 1];
    float p = expf(v2 - v1);
    float sc = 1.0f / (1.0f + p);
    gate_e[t2 * 2] = i1;
    gate_e[t2 * 2 + 1] = i2;
    gate_w[t2 * 2] = sc;
    gate_w[t2 * 2 + 1] = p * sc;
    if (o1 != i1 || o2 != i2) {
      atomicSub(&counts[o1], 1);
      atomicSub(&counts[o2], 1);
      atomicAdd(&counts[i1], 1);
      atomicAdd(&counts[i2], 1);
    }
  }
}

// ---------------- scan: offsets + tile map (tiny) ----------------
__global__ void scan_kernel(const int* __restrict__ counts, int* __restrict__ offs,
                            int* __restrict__ tile_expert, int* __restrict__ ntiles,
                            int* __restrict__ fill) {
  if (threadIdx.x == 0) {
    int off = 0, nt = 0;
    for (int e = 0; e < EE; e++) {
      offs[e] = off;
      fill[e] = 0;
      int tiles = (counts[e] + BM - 1) / BM;
      for (int t = 0; t < tiles; t++) tile_expert[nt++] = e;
      off += tiles * BM;
    }
    offs[EE] = off;
    ntiles[0] = nt;
  }
}

// ---------------- scatter: parallel, global fill atomics ----------------
__global__ __launch_bounds__(256) void scatter_kernel(
    const int* __restrict__ gate_e, const float* __restrict__ gate_w,
    const int* __restrict__ offs, int* __restrict__ fill,
    int* __restrict__ slot_token, float* __restrict__ slot_w,
    int* __restrict__ slot_of) {
  int t = blockIdx.x * blockDim.x + threadIdx.x;
  if (t >= TT) return;
#pragma unroll
  for (int k = 0; k < 2; k++) {
    int e = gate_e[t * 2 + k];
    int pos = atomicAdd(&fill[e], 1);
    int slot = offs[e] + pos;
    slot_token[slot] = t;
    slot_w[slot] = gate_w[t * 2 + k];
    slot_of[t * 2 + k] = slot;
  }
}

// ---------------- GEMM1: 128x128, BK=32, counted-vmcnt dbuf pipeline --------
// h = gelu(x[slot] @ W1[e] + b1[e]); grid (HH/128, MAXTILES)
__global__ __launch_bounds__(256) void gemm1_kernel(
    const unsigned short* __restrict__ xb, const unsigned short* __restrict__ w1t,
    const float* __restrict__ b1, const int* __restrict__ slot_token,
    const int* __restrict__ tile_expert, const int* __restrict__ ntiles,
    unsigned short* __restrict__ hb) {
  int mt = blockIdx.y;
  if (mt >= ntiles[0]) return;
  int e = tile_expert[mt];
  int row0 = mt * BM;
  int n0 = blockIdx.x * 128;
  __shared__ unsigned short As[2][128][32];  // 16 KB
  __shared__ unsigned short Bs[2][128][32];  // 16 KB
  int tid = threadIdx.x;
  int lane = tid & 63;
  int wave = tid >> 6;
  int wm = wave >> 1, wn = wave & 1;
  int ra = tid >> 2, c = tid & 3;
  int tok_a = slot_token[row0 + ra]; if (tok_a < 0) tok_a = 0;
  int tok_b = slot_token[row0 + ra + 64]; if (tok_b < 0) tok_b = 0;
  const unsigned short* wbase = w1t + ((size_t)e * HH * DD);
  const unsigned short* gA0 = xb + (size_t)tok_a * DD + c * 8;
  const unsigned short* gA1 = xb + (size_t)tok_b * DD + c * 8;
  const unsigned short* gB0 = wbase + (size_t)(n0 + ra) * DD + c * 8;
  const unsigned short* gB1 = wbase + (size_t)(n0 + ra + 64) * DD + c * 8;
  f32x4 acc[4][4];
#pragma unroll
  for (int m = 0; m < 4; m++)
#pragma unroll
    for (int n = 0; n < 4; n++) {
      f32x4 z = {0.f, 0.f, 0.f, 0.f};
      acc[m][n] = z;
    }
  // prologue: stage tile 0 into buf 0
  gload16(gA0, &As[0][ra][c * 8]);
  gload16(gA1, &As[0][ra + 64][c * 8]);
  gload16(gB0, &Bs[0][ra][c * 8]);
  gload16(gB1, &Bs[0][ra + 64][c * 8]);
  int cur = 0;
  for (int kk = 0; kk < DD / 32; kk++) {
    if (kk + 1 < DD / 32) {
      int k1 = (kk + 1) * 32;
      int nx = cur ^ 1;
      gload16(gA0 + k1, &As[nx][ra][c * 8]);
      gload16(gA1 + k1, &As[nx][ra + 64][c * 8]);
      gload16(gB0 + k1, &Bs[nx][ra][c * 8]);
      gload16(gB1 + k1, &Bs[nx][ra + 64][c * 8]);
      // wait only for CURRENT tile's 4 loads; next tile's 4 stay in flight
      asm volatile("s_waitcnt vmcnt(4)" ::: "memory");
    } else {
      asm volatile("s_waitcnt vmcnt(0)" ::: "memory");
    }
    __builtin_amdgcn_s_barrier();   // all waves' current-tile loads landed
    bf16x8 a[4], b[4];
#pragma unroll
    for (int m = 0; m < 4; m++)
      a[m] = *(const bf16x8*)(&As[cur][wm * 64 + m * 16 + (lane & 15)][(lane >> 4) * 8]);
#pragma unroll
    for (int n = 0; n < 4; n++)
      b[n] = *(const bf16x8*)(&Bs[cur][wn * 64 + n * 16 + (lane & 15)][(lane >> 4) * 8]);
#pragma unroll
    for (int m = 0; m < 4; m++)
#pragma unroll
      for (int n = 0; n < 4; n++)
        acc[m][n] = __builtin_amdgcn_mfma_f32_16x16x32_bf16(a[m], b[n], acc[m][n], 0, 0, 0);
    asm volatile("" ::: "memory");
    __builtin_amdgcn_s_barrier();   // buffer reads done before next overwrite
    cur ^= 1;
  }
  const float* b1e = b1 + (size_t)e * HH;
#pragma unroll
  for (int m = 0; m < 4; m++) {
#pragma unroll
    for (int r = 0; r < 4; r++) {
      int slot = row0 + wm * 64 + m * 16 + ((lane >> 4) << 2) + r;
      unsigned short* hrow = hb + (size_t)slot * HH;
#pragma unroll
      for (int n = 0; n < 4; n++) {
        int hc = n0 + wn * 64 + n * 16 + (lane & 15);
        float v = acc[m][n][r] + b1e[hc];
        hrow[hc] = f2bf(gelu_f(v));
      }
    }
  }
}

// ---------------- GEMM2: 128x128, BK=32, counted-vmcnt dbuf pipeline --------
// yw[slot] = w*(h[slot] @ W2[e] + b2[e]); grid (DD/128, MAXTILES)
template <int USE_Y>
__global__ __launch_bounds__(256) void gemm2_kernel(
    const unsigned short* __restrict__ hb, const unsigned short* __restrict__ w2t,
    const float* __restrict__ b2, const int* __restrict__ slot_token,
    const float* __restrict__ slot_w, const int* __restrict__ tile_expert,
    const int* __restrict__ ntiles, unsigned short* __restrict__ yw,
    float* __restrict__ out) {
  int mt = blockIdx.y;
  if (mt >= ntiles[0]) return;
  int e = tile_expert[mt];
  int row0 = mt * BM;
  int n0 = blockIdx.x * 128;
  __shared__ unsigned short As[2][128][32];
  __shared__ unsigned short Bs[2][128][32];
  int tid = threadIdx.x;
  int lane = tid & 63;
  int wave = tid >> 6;
  int wm = wave >> 1, wn = wave & 1;
  int ra = tid >> 2, c = tid & 3;
  const unsigned short* wbase = w2t + ((size_t)e * DD * HH);
  const unsigned short* gA0 = hb + (size_t)(row0 + ra) * HH + c * 8;
  const unsigned short* gA1 = hb + (size_t)(row0 + ra + 64) * HH + c * 8;
  const unsigned short* gB0 = wbase + (size_t)(n0 + ra) * HH + c * 8;
  const unsigned short* gB1 = wbase + (size_t)(n0 + ra + 64) * HH + c * 8;
  f32x4 acc[4][4];
#pragma unroll
  for (int m = 0; m < 4; m++)
#pragma unroll
    for (int n = 0; n < 4; n++) {
      f32x4 z = {0.f, 0.f, 0.f, 0.f};
      acc[m][n] = z;
    }
  gload16(gA0, &As[0][ra][c * 8]);
  gload16(gA1, &As[0][ra + 64][c * 8]);
  gload16(gB0, &Bs[0][ra][c * 8]);
  gload16(gB1, &Bs[0][ra + 64][c * 8]);
  int cur = 0;
  for (int kk = 0; kk < HH / 32; kk++) {
    if (kk + 1 < HH / 32) {
      int k1 = (kk + 1) * 32;
      int nx = cur ^ 1;
      gload16(gA0 + k1, &As[nx][ra][c * 8]);
      gload16(gA1 + k1, &As[nx][ra + 64][c * 8]);
      gload16(gB0 + k1, &Bs[nx][ra][c * 8]);
      gload16(gB1 + k1, &Bs[nx][ra + 64][c * 8]);
      asm volatile("s_waitcnt vmcnt(4)" ::: "memory");
    } else {
      asm volatile("s_waitcnt vmcnt(0)" ::: "memory");
    }
    __builtin_amdgcn_s_barrier();
    bf16x8 a[4], b[4];
#pragma unroll
    for (int m = 0; m < 4; m++)
      a[m] = *(const bf16x8*)(&As[cur][wm * 64 + m * 16 + (lane & 15)][(lane >> 4) * 8]);
#pragma unroll
    for (int n = 0; n < 4; n++)
      b[n] = *(const bf16x8*)(&Bs[cur][wn * 64 + n * 16 + (lane & 15)][(lane >> 4) * 8]);
#pragma unroll
    for (int m = 0; m < 4; m++)
#pragma unroll
      for (int n = 0; n < 4; n++)
        acc[m][n] = __builtin_amdgcn_mfma_f32_16x16x32_bf16(a[m], b[n], acc[m][n], 0, 0, 0);
    asm volatile("" ::: "memory");
    __builtin_amdgcn_s_barrier();
    cur ^= 1;
  }
  const float* b2e = b2 + (size_t)e * DD;
#pragma unroll
  for (int m = 0; m < 4; m++) {
#pragma unroll
    for (int r = 0; r < 4; r++) {
      int slot = row0 + wm * 64 + m * 16 + ((lane >> 4) << 2) + r;
      if (USE_Y) {
        float w = slot_w[slot];
        unsigned short* yrow = yw + (size_t)slot * DD;
#pragma unroll
        for (int n = 0; n < 4; n++) {
          int dc = n0 + wn * 64 + n * 16 + (lane & 15);
          yrow[dc] = f2bf(w * (acc[m][n][r] + b2e[dc]));
        }
      } else {
        int tok = slot_token[slot];
        if (tok >= 0) {
          float w = slot_w[slot];
          float* orow = out + (size_t)tok * DD;
#pragma unroll
          for (int n = 0; n < 4; n++) {
            int dc = n0 + wn * 64 + n * 16 + (lane & 15);
            float v = acc[m][n][r] + b2e[dc];
            atomicAdd(&orow[dc], w * v);
          }
        }
      }
    }
  }
}

// ---------------- combine: out[t] = yw[s1] + yw[s2] ----------------
__global__ __launch_bounds__(256) void combine_kernel(
    const unsigned short* __restrict__ yw, const int* __restrict__ slot_of,
    float* __restrict__ out) {
  int gid = blockIdx.x * 256 + threadIdx.x;
  int t = gid >> 6;
  int d0 = (gid & 63) * 8;
  int s1 = slot_of[t * 2], s2 = slot_of[t * 2 + 1];
  const ushort4* p1 = (const ushort4*)(yw + (size_t)s1 * DD + d0);
  const ushort4* p2 = (const ushort4*)(yw + (size_t)s2 * DD + d0);
  ushort4 a0 = p1[0], a1 = p1[1];
  ushort4 b0 = p2[0], b1 = p2[1];
  float4 o0, o1;
  o0.x = bf2f(a0.x) + bf2f(b0.x);
  o0.y = bf2f(a0.y) + bf2f(b0.y);
  o0.z = bf2f(a0.z) + bf2f(b0.z);
  o0.w = bf2f(a0.w) + bf2f(b0.w);
  o1.x = bf2f(a1.x) + bf2f(b1.x);
  o1.y = bf2f(a1.y) + bf2f(b1.y);
  o1.z = bf2f(a1.z) + bf2f(b1.z);
  o1.w = bf2f(a1.w) + bf2f(b1.w);
  float* orow = out + (size_t)t * DD + d0;
  ((float4*)orow)[0] = o0;
  ((float4*)orow)[1] = o1;
}

extern "C" void kernel_launch(void* const* d_in, const int* in_sizes, int n_in,
                              void* d_out, int out_size, void* d_ws, size_t ws_size,
                              hipStream_t stream) {
  const float* x  = (const float*)d_in[0];
  const float* Wg = (const float*)d_in[1];
  const float* bg = (const float*)d_in[2];
  const float* W1 = (const float*)d_in[3];
  const float* b1 = (const float*)d_in[4];
  const float* W2 = (const float*)d_in[5];
  const float* b2 = (const float*)d_in[6];
  float* out = (float*)d_out;

  uint8_t* w = (uint8_t*)d_ws;
  size_t o = 0;
  unsigned short* xb  = (unsigned short*)(w + o); o += (size_t)TT * DD * 2;       // 8 MB
  unsigned short* w1t = (unsigned short*)(w + o); o += (size_t)EE * DD * HH * 2;  // 16 MB
  unsigned short* w2t = (unsigned short*)(w + o); o += (size_t)EE * DD * HH * 2;  // 16 MB
  unsigned short* hb  = (unsigned short*)(w + o); o += (size_t)NSLOT * HH * 2;    // 37.7 MB
  int*   slot_token = (int*)(w + o);   o += (size_t)NSLOT * 4;
  float* slot_w     = (float*)(w + o); o += (size_t)NSLOT * 4;
  int*   slot_of    = (int*)(w + o);   o += (size_t)TT * 2 * 4;
  int*   gate_e     = (int*)(w + o);   o += (size_t)TT * 2 * 4;
  float* gate_w     = (float*)(w + o); o += (size_t)TT * 2 * 4;
  int*   counts     = (int*)(w + o);   o += 64;   // counts[16]
  int*   nretry     = (int*)(w + o);   o += 64;   // adjacent: one 128B memset
  int*   tile_expert= (int*)(w + o);   o += 640;
  int*   ntiles     = (int*)(w + o);   o += 64;
  int*   offs       = (int*)(w + o);   o += 128;
  int*   fill       = (int*)(w + o);   o += 64;
  int*   retry      = (int*)(w + o);   o += RETRYCAP * 4;
  unsigned short* yw = (unsigned short*)(w + o);
  size_t need_y = o + (size_t)NSLOT * DD * 2;   // +18.9 MB
  int use_y = (ws_size >= need_y);

  hipMemsetAsync(counts, 0, 128, stream);  // counts + nretry
  hipMemsetAsync(slot_token, 0xFF, (size_t)NSLOT * 4, stream);
  if (!use_y) hipMemsetAsync(d_out, 0, (size_t)TT * DD * 4, stream);

  // transposes + gate in one launch (independent work overlaps on the machine)
  prep_kernel<<<4096 + TT / 128, 256, 0, stream>>>(
      W1, W2, w1t, w2t, x, Wg, bg, xb, gate_e, gate_w, counts, nretry, retry);
  gatefix_kernel<<<RETRYCAP / 16, 256, 0, stream>>>(x, Wg, bg, nretry, retry,
                                                    gate_e, gate_w, counts);
  scan_kernel<<<1, 64, 0, stream>>>(counts, offs, tile_expert, ntiles, fill);
  scatter_kernel<<<TT / 256, 256, 0, stream>>>(gate_e, gate_w, offs, fill,
                                               slot_token, slot_w, slot_of);
  {
    dim3 g(HH / 128, MAXTILES);
    gemm1_kernel<<<g, 256, 0, stream>>>(xb, w1t, b1, slot_token, tile_expert, ntiles, hb);
  }
  {
    dim3 g(DD / 128, MAXTILES);
    if (use_y)
      gemm2_kernel<1><<<g, 256, 0, stream>>>(hb, w2t, b2, slot_token, slot_w,
                                             tile_expert, ntiles, yw, out);
    else
      gemm2_kernel<0><<<g, 256, 0, stream>>>(hb, w2t, b2, slot_token, slot_w,
                                             tile_expert, ntiles, yw, out);
  }
  if (use_y) {
    combine_kernel<<<TT * (DD / 8) / 256, 256, 0, stream>>>(yw, slot_of, out);
  }
}

// Round 13
// 218.840 us; speedup vs baseline: 1.0792x; 1.0192x over previous
//
#include <hip/hip_runtime.h>
#include <hip/hip_bf16.h>
#include <math.h>

#define TT 8192
#define DD 512
#define HH 1024
#define EE 16
#define NSLOT 18432   // 144 * 128 max padded slots
#define MAXTILES 144
#define BM 128
#define RETRYCAP 1024

typedef __attribute__((ext_vector_type(8))) short bf16x8;
typedef __attribute__((ext_vector_type(8))) unsigned short u16x8;
typedef __attribute__((ext_vector_type(4))) float f32x4;

__device__ __forceinline__ unsigned short f2bf(float f) {
  union { float f; unsigned u; } v; v.f = f;
  unsigned r = v.u + 0x7fffu + ((v.u >> 16) & 1u);
  return (unsigned short)(r >> 16);
}

__device__ __forceinline__ float bf2f(unsigned short u) {
  union { unsigned u; float f; } v; v.u = ((unsigned)u) << 16;
  return v.f;
}

__device__ __forceinline__ void gload16(const void* g, void* l) {
  __builtin_amdgcn_global_load_lds(
      (const __attribute__((address_space(1))) unsigned int*)g,
      (__attribute__((address_space(3))) unsigned int*)l, 16, 0, 0);
}

// Abramowitz-Stegun 7.1.26 erf approx (|err| <= 1.5e-7)
__device__ __forceinline__ float gelu_f(float v) {
  float s = fabsf(v) * 0.70710678118654752f;
  float t = 1.0f / (1.0f + 0.3275911f * s);
  float poly = t * (0.254829592f +
              t * (-0.284496736f +
              t * (1.421413741f +
              t * (-1.453152027f +
              t * 1.061405429f))));
  float erfa = 1.0f - poly * __expf(-s * s);
  float erfv = (v >= 0.f) ? erfa : -erfa;
  return 0.5f * v * (1.0f + erfv);
}

// ------- transpose+convert: in f32 [nmat][R][C] -> out bf16 [nmat][C][R] -------
__global__ __launch_bounds__(256) void transpose_cv_kernel(
    const float* __restrict__ in, unsigned short* __restrict__ out, int R, int C) {
  int mat = blockIdx.z;
  int c0 = blockIdx.x * 64;
  int r0 = blockIdx.y * 64;
  const float* src = in + (size_t)mat * R * C;
  unsigned short* dst = out + (size_t)mat * R * C;
  __shared__ unsigned short t[64][68];
  int tid = threadIdx.x;
#pragma unroll
  for (int p = 0; p < 4; p++) {
    int r = tid >> 2;
    int c4 = (tid & 3) + p * 4;
    float4 v = *(const float4*)(src + (size_t)(r0 + r) * C + c0 + c4 * 4);
    t[c4 * 4 + 0][r] = f2bf(v.x);
    t[c4 * 4 + 1][r] = f2bf(v.y);
    t[c4 * 4 + 2][r] = f2bf(v.z);
    t[c4 * 4 + 3][r] = f2bf(v.w);
  }
  __syncthreads();
#pragma unroll
  for (int p = 0; p < 4; p++) {
    int oc = (tid >> 4) + p * 16;
    int ch = tid & 15;
    ushort4 v = *(ushort4*)(&t[oc][ch * 4]);
    *(ushort4*)(dst + (size_t)(c0 + oc) * R + r0 + ch * 4) = v;
  }
}

// ---------------- gate via MFMA: 128 blocks x 64 tokens ----------------
// Same proven R8 body, scaled: 1 MFMA chain per wave (16 tokens), As[64][40].
__global__ __launch_bounds__(256) void gate_mfma_kernel(
    const float* __restrict__ x, const float* __restrict__ Wg,
    const float* __restrict__ bg, unsigned short* __restrict__ xb,
    int* __restrict__ gate_e, float* __restrict__ gate_w,
    int* __restrict__ counts, int* __restrict__ nretry,
    int* __restrict__ retry) {
  __shared__ __align__(16) unsigned short As[64][40];  // 5 KB
  __shared__ int cnt_s[EE];
  int tid = threadIdx.x;
  int lane = tid & 63;
  int wave = tid >> 6;
  int tok0 = blockIdx.x * 64;
  if (tid < EE) cnt_s[tid] = 0;
  int e = lane & 15;
  int kb = (lane >> 4) * 8;
  bf16x8 bfrag[16];
#pragma unroll
  for (int ks = 0; ks < 16; ks++) {
    int kbase = ks * 32 + kb;
#pragma unroll
    for (int j = 0; j < 8; j++)
      bfrag[ks][j] = (short)f2bf(Wg[(kbase + j) * EE + e]);
  }
  float bge = bg[e];
  f32x4 acc = {0.f, 0.f, 0.f, 0.f};
  int srow = tid >> 2;           // 0..63
  int sc0 = (tid & 3) * 8;       // float offset 0,8,16,24
  const float* xrow = x + (size_t)(tok0 + srow) * DD + sc0;
  unsigned short* xbrow = xb + (size_t)(tok0 + srow) * DD + sc0;
  for (int ks = 0; ks < 16; ks++) {
    int k0 = ks * 32;
    __syncthreads();
    float4 v0 = *(const float4*)(xrow + k0);
    float4 v1 = *(const float4*)(xrow + k0 + 4);
    u16x8 w0;
    w0[0] = f2bf(v0.x); w0[1] = f2bf(v0.y); w0[2] = f2bf(v0.z); w0[3] = f2bf(v0.w);
    w0[4] = f2bf(v1.x); w0[5] = f2bf(v1.y); w0[6] = f2bf(v1.z); w0[7] = f2bf(v1.w);
    *(u16x8*)(xbrow + k0) = w0;
    *(u16x8*)(&As[srow][sc0]) = w0;
    __syncthreads();
    bf16x8 a0 = *(const bf16x8*)(&As[wave * 16 + (lane & 15)][kb]);
    acc = __builtin_amdgcn_mfma_f32_16x16x32_bf16(a0, bfrag[ks], acc, 0, 0, 0);
  }
#pragma unroll
  for (int r = 0; r < 4; r++) {
    float lf = acc[r] + bge;
    float v1 = -1e30f, v2 = -1e30f, v3 = -1e30f;
    int i1 = 0, i2 = 0;
#pragma unroll
    for (int q = 0; q < EE; q++) {
      float v = __shfl(lf, (lane & 48) | q);
      if (v > v1) { v3 = v2; v2 = v1; i2 = i1; v1 = v; i1 = q; }
      else if (v > v2) { v3 = v2; v2 = v; i2 = q; }
      else if (v > v3) { v3 = v; }
    }
    if ((lane & 15) == 0) {
      int t2 = tok0 + wave * 16 + ((lane >> 4) << 2) + r;
      float p = expf(v2 - v1);
      float s = 1.0f / (1.0f + p);
      gate_e[t2 * 2] = i1;
      gate_e[t2 * 2 + 1] = i2;
      gate_w[t2 * 2] = s;
      gate_w[t2 * 2 + 1] = p * s;
      atomicAdd(&cnt_s[i1], 1);
      atomicAdd(&cnt_s[i2], 1);
      if (v2 - v3 < 0.02f) {
        int pos = atomicAdd(nretry, 1);
        if (pos < RETRYCAP) retry[pos] = t2;
      }
    }
  }
  __syncthreads();
  if (tid < EE) atomicAdd(&counts[tid], cnt_s[tid]);
}

// ---------------- gatefix: exact f64 recompute for near-tie tokens ----------
__global__ __launch_bounds__(256) void gatefix_kernel(
    const float* __restrict__ x, const float* __restrict__ Wg,
    const float* __restrict__ bg, const int* __restrict__ nretry,
    const int* __restrict__ retry, int* __restrict__ gate_e,
    float* __restrict__ gate_w, int* __restrict__ counts) {
  __shared__ float lg[16][17];
  __shared__ int toks[16];
  int tid = threadIdx.x;
  int sl = tid >> 4, e = tid & 15;
  int s = blockIdx.x * 16 + sl;
  int n = *nretry; if (n > RETRYCAP) n = RETRYCAP;
  int active = (s < n);
  int tok = 0;
  if (active) tok = retry[s];
  if (active) {
    const float* xr = x + (size_t)tok * DD;
    double a0 = 0.0, a1 = 0.0, a2 = 0.0, a3 = 0.0;
    for (int i = 0; i < DD / 4; i++) {
      a0 += (double)xr[i * 4 + 0] * (double)Wg[(i * 4 + 0) * EE + e];
      a1 += (double)xr[i * 4 + 1] * (double)Wg[(i * 4 + 1) * EE + e];
      a2 += (double)xr[i * 4 + 2] * (double)Wg[(i * 4 + 2) * EE + e];
      a3 += (double)xr[i * 4 + 3] * (double)Wg[(i * 4 + 3) * EE + e];
    }
    double acc = (a0 + a1) + (a2 + a3);
    lg[sl][e] = (float)(acc + (double)bg[e]);
    toks[sl] = tok;
  }
  __syncthreads();
  if (active && e == 0) {
    float v1 = -1e30f, v2 = -1e30f;
    int i1 = 0, i2 = 0;
#pragma unroll
    for (int q = 0; q < EE; q++) {
      float v = lg[sl][q];
      if (v > v1) { v2 = v1; i2 = i1; v1 = v; i1 = q; }
      else if (v > v2) { v2 = v; i2 = q; }
    }
    int t2 = toks[sl];
    int o1 = gate_e[t2 * 2], o2 = gate_e[t2 * 2 + 1];
    float p = expf(v2 - v1);
    float sc = 1.0f / (1.0f + p);
    gate_e[t2 * 2] = i1;
    gate_e[t2 * 2 + 1] = i2;
    gate_w[t2 * 2] = sc;
    gate_w[t2 * 2 + 1] = p * sc;
    if (o1 != i1 || o2 != i2) {
      atomicSub(&counts[o1], 1);
      atomicSub(&counts[o2], 1);
      atomicAdd(&counts[i1], 1);
      atomicAdd(&counts[i2], 1);
    }
  }
}

// ---------------- scan: offsets + tile map (tiny) ----------------
__global__ void scan_kernel(const int* __restrict__ counts, int* __restrict__ offs,
                            int* __restrict__ tile_expert, int* __restrict__ ntiles,
                            int* __restrict__ fill) {
  if (threadIdx.x == 0) {
    int off = 0, nt = 0;
    for (int e = 0; e < EE; e++) {
      offs[e] = off;
      fill[e] = 0;
      int tiles = (counts[e] + BM - 1) / BM;
      for (int t = 0; t < tiles; t++) tile_expert[nt++] = e;
      off += tiles * BM;
    }
    offs[EE] = off;
    ntiles[0] = nt;
  }
}

// ---------------- scatter: parallel, global fill atomics ----------------
__global__ __launch_bounds__(256) void scatter_kernel(
    const int* __restrict__ gate_e, const float* __restrict__ gate_w,
    const int* __restrict__ offs, int* __restrict__ fill,
    int* __restrict__ slot_token, float* __restrict__ slot_w,
    int* __restrict__ slot_of) {
  int t = blockIdx.x * blockDim.x + threadIdx.x;
  if (t >= TT) return;
#pragma unroll
  for (int k = 0; k < 2; k++) {
    int e = gate_e[t * 2 + k];
    int pos = atomicAdd(&fill[e], 1);
    int slot = offs[e] + pos;
    slot_token[slot] = t;
    slot_w[slot] = gate_w[t * 2 + k];
    slot_of[t * 2 + k] = slot;
  }
}

// ---------------- GEMM1: 128x128, BK=32, counted-vmcnt dbuf pipeline --------
// h = gelu(x[slot] @ W1[e] + b1[e]); grid (HH/128, MAXTILES)
__global__ __launch_bounds__(256) void gemm1_kernel(
    const unsigned short* __restrict__ xb, const unsigned short* __restrict__ w1t,
    const float* __restrict__ b1, const int* __restrict__ slot_token,
    const int* __restrict__ tile_expert, const int* __restrict__ ntiles,
    unsigned short* __restrict__ hb) {
  int mt = blockIdx.y;
  if (mt >= ntiles[0]) return;
  int e = tile_expert[mt];
  int row0 = mt * BM;
  int n0 = blockIdx.x * 128;
  __shared__ unsigned short As[2][128][32];  // 16 KB
  __shared__ unsigned short Bs[2][128][32];  // 16 KB
  int tid = threadIdx.x;
  int lane = tid & 63;
  int wave = tid >> 6;
  int wm = wave >> 1, wn = wave & 1;
  int ra = tid >> 2, c = tid & 3;
  int tok_a = slot_token[row0 + ra]; if (tok_a < 0) tok_a = 0;
  int tok_b = slot_token[row0 + ra + 64]; if (tok_b < 0) tok_b = 0;
  const unsigned short* wbase = w1t + ((size_t)e * HH * DD);
  const unsigned short* gA0 = xb + (size_t)tok_a * DD + c * 8;
  const unsigned short* gA1 = xb + (size_t)tok_b * DD + c * 8;
  const unsigned short* gB0 = wbase + (size_t)(n0 + ra) * DD + c * 8;
  const unsigned short* gB1 = wbase + (size_t)(n0 + ra + 64) * DD + c * 8;
  f32x4 acc[4][4];
#pragma unroll
  for (int m = 0; m < 4; m++)
#pragma unroll
    for (int n = 0; n < 4; n++) {
      f32x4 z = {0.f, 0.f, 0.f, 0.f};
      acc[m][n] = z;
    }
  gload16(gA0, &As[0][ra][c * 8]);
  gload16(gA1, &As[0][ra + 64][c * 8]);
  gload16(gB0, &Bs[0][ra][c * 8]);
  gload16(gB1, &Bs[0][ra + 64][c * 8]);
  int cur = 0;
  for (int kk = 0; kk < DD / 32; kk++) {
    if (kk + 1 < DD / 32) {
      int k1 = (kk + 1) * 32;
      int nx = cur ^ 1;
      gload16(gA0 + k1, &As[nx][ra][c * 8]);
      gload16(gA1 + k1, &As[nx][ra + 64][c * 8]);
      gload16(gB0 + k1, &Bs[nx][ra][c * 8]);
      gload16(gB1 + k1, &Bs[nx][ra + 64][c * 8]);
      asm volatile("s_waitcnt vmcnt(4)" ::: "memory");
    } else {
      asm volatile("s_waitcnt vmcnt(0)" ::: "memory");
    }
    __builtin_amdgcn_s_barrier();
    bf16x8 a[4], b[4];
#pragma unroll
    for (int m = 0; m < 4; m++)
      a[m] = *(const bf16x8*)(&As[cur][wm * 64 + m * 16 + (lane & 15)][(lane >> 4) * 8]);
#pragma unroll
    for (int n = 0; n < 4; n++)
      b[n] = *(const bf16x8*)(&Bs[cur][wn * 64 + n * 16 + (lane & 15)][(lane >> 4) * 8]);
#pragma unroll
    for (int m = 0; m < 4; m++)
#pragma unroll
      for (int n = 0; n < 4; n++)
        acc[m][n] = __builtin_amdgcn_mfma_f32_16x16x32_bf16(a[m], b[n], acc[m][n], 0, 0, 0);
    asm volatile("" ::: "memory");
    __builtin_amdgcn_s_barrier();
    cur ^= 1;
  }
  const float* b1e = b1 + (size_t)e * HH;
#pragma unroll
  for (int m = 0; m < 4; m++) {
#pragma unroll
    for (int r = 0; r < 4; r++) {
      int slot = row0 + wm * 64 + m * 16 + ((lane >> 4) << 2) + r;
      unsigned short* hrow = hb + (size_t)slot * HH;
#pragma unroll
      for (int n = 0; n < 4; n++) {
        int hc = n0 + wn * 64 + n * 16 + (lane & 15);
        float v = acc[m][n][r] + b1e[hc];
        hrow[hc] = f2bf(gelu_f(v));
      }
    }
  }
}

// ---------------- GEMM2: 128x128, BK=32, counted-vmcnt dbuf pipeline --------
// yw[slot] = w*(h[slot] @ W2[e] + b2[e]); grid (DD/128, MAXTILES)
template <int USE_Y>
__global__ __launch_bounds__(256) void gemm2_kernel(
    const unsigned short* __restrict__ hb, const unsigned short* __restrict__ w2t,
    const float* __restrict__ b2, const int* __restrict__ slot_token,
    const float* __restrict__ slot_w, const int* __restrict__ tile_expert,
    const int* __restrict__ ntiles, unsigned short* __restrict__ yw,
    float* __restrict__ out) {
  int mt = blockIdx.y;
  if (mt >= ntiles[0]) return;
  int e = tile_expert[mt];
  int row0 = mt * BM;
  int n0 = blockIdx.x * 128;
  __shared__ unsigned short As[2][128][32];
  __shared__ unsigned short Bs[2][128][32];
  int tid = threadIdx.x;
  int lane = tid & 63;
  int wave = tid >> 6;
  int wm = wave >> 1, wn = wave & 1;
  int ra = tid >> 2, c = tid & 3;
  const unsigned short* wbase = w2t + ((size_t)e * DD * HH);
  const unsigned short* gA0 = hb + (size_t)(row0 + ra) * HH + c * 8;
  const unsigned short* gA1 = hb + (size_t)(row0 + ra + 64) * HH + c * 8;
  const unsigned short* gB0 = wbase + (size_t)(n0 + ra) * HH + c * 8;
  const unsigned short* gB1 = wbase + (size_t)(n0 + ra + 64) * HH + c * 8;
  f32x4 acc[4][4];
#pragma unroll
  for (int m = 0; m < 4; m++)
#pragma unroll
    for (int n = 0; n < 4; n++) {
      f32x4 z = {0.f, 0.f, 0.f, 0.f};
      acc[m][n] = z;
    }
  gload16(gA0, &As[0][ra][c * 8]);
  gload16(gA1, &As[0][ra + 64][c * 8]);
  gload16(gB0, &Bs[0][ra][c * 8]);
  gload16(gB1, &Bs[0][ra + 64][c * 8]);
  int cur = 0;
  for (int kk = 0; kk < HH / 32; kk++) {
    if (kk + 1 < HH / 32) {
      int k1 = (kk + 1) * 32;
      int nx = cur ^ 1;
      gload16(gA0 + k1, &As[nx][ra][c * 8]);
      gload16(gA1 + k1, &As[nx][ra + 64][c * 8]);
      gload16(gB0 + k1, &Bs[nx][ra][c * 8]);
      gload16(gB1 + k1, &Bs[nx][ra + 64][c * 8]);
      asm volatile("s_waitcnt vmcnt(4)" ::: "memory");
    } else {
      asm volatile("s_waitcnt vmcnt(0)" ::: "memory");
    }
    __builtin_amdgcn_s_barrier();
    bf16x8 a[4], b[4];
#pragma unroll
    for (int m = 0; m < 4; m++)
      a[m] = *(const bf16x8*)(&As[cur][wm * 64 + m * 16 + (lane & 15)][(lane >> 4) * 8]);
#pragma unroll
    for (int n = 0; n < 4; n++)
      b[n] = *(const bf16x8*)(&Bs[cur][wn * 64 + n * 16 + (lane & 15)][(lane >> 4) * 8]);
#pragma unroll
    for (int m = 0; m < 4; m++)
#pragma unroll
      for (int n = 0; n < 4; n++)
        acc[m][n] = __builtin_amdgcn_mfma_f32_16x16x32_bf16(a[m], b[n], acc[m][n], 0, 0, 0);
    asm volatile("" ::: "memory");
    __builtin_amdgcn_s_barrier();
    cur ^= 1;
  }
  const float* b2e = b2 + (size_t)e * DD;
#pragma unroll
  for (int m = 0; m < 4; m++) {
#pragma unroll
    for (int r = 0; r < 4; r++) {
      int slot = row0 + wm * 64 + m * 16 + ((lane >> 4) << 2) + r;
      if (USE_Y) {
        float w = slot_w[slot];
        unsigned short* yrow = yw + (size_t)slot * DD;
#pragma unroll
        for (int n = 0; n < 4; n++) {
          int dc = n0 + wn * 64 + n * 16 + (lane & 15);
          yrow[dc] = f2bf(w * (acc[m][n][r] + b2e[dc]));
        }
      } else {
        int tok = slot_token[slot];
        if (tok >= 0) {
          float w = slot_w[slot];
          float* orow = out + (size_t)tok * DD;
#pragma unroll
          for (int n = 0; n < 4; n++) {
            int dc = n0 + wn * 64 + n * 16 + (lane & 15);
            float v = acc[m][n][r] + b2e[dc];
            atomicAdd(&orow[dc], w * v);
          }
        }
      }
    }
  }
}

// ---------------- combine: out[t] = yw[s1] + yw[s2] ----------------
__global__ __launch_bounds__(256) void combine_kernel(
    const unsigned short* __restrict__ yw, const int* __restrict__ slot_of,
    float* __restrict__ out) {
  int gid = blockIdx.x * 256 + threadIdx.x;
  int t = gid >> 6;
  int d0 = (gid & 63) * 8;
  int s1 = slot_of[t * 2], s2 = slot_of[t * 2 + 1];
  const ushort4* p1 = (const ushort4*)(yw + (size_t)s1 * DD + d0);
  const ushort4* p2 = (const ushort4*)(yw + (size_t)s2 * DD + d0);
  ushort4 a0 = p1[0], a1 = p1[1];
  ushort4 b0 = p2[0], b1 = p2[1];
  float4 o0, o1;
  o0.x = bf2f(a0.x) + bf2f(b0.x);
  o0.y = bf2f(a0.y) + bf2f(b0.y);
  o0.z = bf2f(a0.z) + bf2f(b0.z);
  o0.w = bf2f(a0.w) + bf2f(b0.w);
  o1.x = bf2f(a1.x) + bf2f(b1.x);
  o1.y = bf2f(a1.y) + bf2f(b1.y);
  o1.z = bf2f(a1.z) + bf2f(b1.z);
  o1.w = bf2f(a1.w) + bf2f(b1.w);
  float* orow = out + (size_t)t * DD + d0;
  ((float4*)orow)[0] = o0;
  ((float4*)orow)[1] = o1;
}

extern "C" void kernel_launch(void* const* d_in, const int* in_sizes, int n_in,
                              void* d_out, int out_size, void* d_ws, size_t ws_size,
                              hipStream_t stream) {
  const float* x  = (const float*)d_in[0];
  const float* Wg = (const float*)d_in[1];
  const float* bg = (const float*)d_in[2];
  const float* W1 = (const float*)d_in[3];
  const float* b1 = (const float*)d_in[4];
  const float* W2 = (const float*)d_in[5];
  const float* b2 = (const float*)d_in[6];
  float* out = (float*)d_out;

  uint8_t* w = (uint8_t*)d_ws;
  size_t o = 0;
  unsigned short* xb  = (unsigned short*)(w + o); o += (size_t)TT * DD * 2;       // 8 MB
  unsigned short* w1t = (unsigned short*)(w + o); o += (size_t)EE * DD * HH * 2;  // 16 MB
  unsigned short* w2t = (unsigned short*)(w + o); o += (size_t)EE * DD * HH * 2;  // 16 MB
  unsigned short* hb  = (unsigned short*)(w + o); o += (size_t)NSLOT * HH * 2;    // 37.7 MB
  int*   slot_token = (int*)(w + o);   o += (size_t)NSLOT * 4;
  float* slot_w     = (float*)(w + o); o += (size_t)NSLOT * 4;
  int*   slot_of    = (int*)(w + o);   o += (size_t)TT * 2 * 4;
  int*   gate_e     = (int*)(w + o);   o += (size_t)TT * 2 * 4;
  float* gate_w     = (float*)(w + o); o += (size_t)TT * 2 * 4;
  int*   counts     = (int*)(w + o);   o += 64;   // counts[16]
  int*   nretry     = (int*)(w + o);   o += 64;   // adjacent: one 128B memset
  int*   tile_expert= (int*)(w + o);   o += 640;
  int*   ntiles     = (int*)(w + o);   o += 64;
  int*   offs       = (int*)(w + o);   o += 128;
  int*   fill       = (int*)(w + o);   o += 64;
  int*   retry      = (int*)(w + o);   o += RETRYCAP * 4;
  unsigned short* yw = (unsigned short*)(w + o);
  size_t need_y = o + (size_t)NSLOT * DD * 2;   // +18.9 MB
  int use_y = (ws_size >= need_y);

  hipMemsetAsync(counts, 0, 128, stream);  // counts + nretry
  hipMemsetAsync(slot_token, 0xFF, (size_t)NSLOT * 4, stream);
  if (!use_y) hipMemsetAsync(d_out, 0, (size_t)TT * DD * 4, stream);

  // W1 [E][512][1024] -> w1t [E][1024][512]
  {
    dim3 g(HH / 64, DD / 64, EE);
    transpose_cv_kernel<<<g, 256, 0, stream>>>(W1, w1t, DD, HH);
  }
  // W2 [E][1024][512] -> w2t [E][512][1024]
  {
    dim3 g(DD / 64, HH / 64, EE);
    transpose_cv_kernel<<<g, 256, 0, stream>>>(W2, w2t, HH, DD);
  }
  gate_mfma_kernel<<<TT / 64, 256, 0, stream>>>(x, Wg, bg, xb, gate_e, gate_w,
                                                counts, nretry, retry);
  gatefix_kernel<<<RETRYCAP / 16, 256, 0, stream>>>(x, Wg, bg, nretry, retry,
                                                    gate_e, gate_w, counts);
  scan_kernel<<<1, 64, 0, stream>>>(counts, offs, tile_expert, ntiles, fill);
  scatter_kernel<<<TT / 256, 256, 0, stream>>>(gate_e, gate_w, offs, fill,
                                               slot_token, slot_w, slot_of);
  {
    dim3 g(HH / 128, MAXTILES);
    gemm1_kernel<<<g, 256, 0, stream>>>(xb, w1t, b1, slot_token, tile_expert, ntiles, hb);
  }
  {
    dim3 g(DD / 128, MAXTILES);
    if (use_y)
      gemm2_kernel<1><<<g, 256, 0, stream>>>(hb, w2t, b2, slot_token, slot_w,
                                             tile_expert, ntiles, yw, out);
    else
      gemm2_kernel<0><<<g, 256, 0, stream>>>(hb, w2t, b2, slot_token, slot_w,
                                             tile_expert, ntiles, yw, out);
  }
  if (use_y) {
    combine_kernel<<<TT * (DD / 8) / 256, 256, 0, stream>>>(yw, slot_of, out);
  }
}

// Round 14
// 181.691 us; speedup vs baseline: 1.2999x; 1.2045x over previous
//
#include <hip/hip_runtime.h>
#include <hip/hip_bf16.h>
#include <math.h>

#define TT 8192
#define DD 512
#define HH 1024
#define EE 16
#define NSLOT 18432   // 144 * 128 max padded slots
#define MAXTILES 144
#define BM 128
#define RETRYCAP 1024

typedef __attribute__((ext_vector_type(8))) short bf16x8;
typedef __attribute__((ext_vector_type(8))) unsigned short u16x8;
typedef __attribute__((ext_vector_type(4))) float f32x4;

__device__ __forceinline__ unsigned short f2bf(float f) {
  union { float f; unsigned u; } v; v.f = f;
  unsigned r = v.u + 0x7fffu + ((v.u >> 16) & 1u);
  return (unsigned short)(r >> 16);
}

__device__ __forceinline__ float bf2f(unsigned short u) {
  union { unsigned u; float f; } v; v.u = ((unsigned)u) << 16;
  return v.f;
}

__device__ __forceinline__ void gload16(const void* g, void* l) {
  __builtin_amdgcn_global_load_lds(
      (const __attribute__((address_space(1))) unsigned int*)g,
      (__attribute__((address_space(3))) unsigned int*)l, 16, 0, 0);
}

// Abramowitz-Stegun 7.1.26 erf approx (|err| <= 1.5e-7)
__device__ __forceinline__ float gelu_f(float v) {
  float s = fabsf(v) * 0.70710678118654752f;
  float t = 1.0f / (1.0f + 0.3275911f * s);
  float poly = t * (0.254829592f +
              t * (-0.284496736f +
              t * (1.421413741f +
              t * (-1.453152027f +
              t * 1.061405429f))));
  float erfa = 1.0f - poly * __expf(-s * s);
  float erfv = (v >= 0.f) ? erfa : -erfa;
  return 0.5f * v * (1.0f + erfv);
}

// ------- transpose+convert: in f32 [nmat][R][C] -> out bf16 [nmat][C][R] -------
__global__ __launch_bounds__(256) void transpose_cv_kernel(
    const float* __restrict__ in, unsigned short* __restrict__ out, int R, int C) {
  int mat = blockIdx.z;
  int c0 = blockIdx.x * 64;
  int r0 = blockIdx.y * 64;
  const float* src = in + (size_t)mat * R * C;
  unsigned short* dst = out + (size_t)mat * R * C;
  __shared__ unsigned short t[64][68];
  int tid = threadIdx.x;
#pragma unroll
  for (int p = 0; p < 4; p++) {
    int r = tid >> 2;
    int c4 = (tid & 3) + p * 4;
    float4 v = *(const float4*)(src + (size_t)(r0 + r) * C + c0 + c4 * 4);
    t[c4 * 4 + 0][r] = f2bf(v.x);
    t[c4 * 4 + 1][r] = f2bf(v.y);
    t[c4 * 4 + 2][r] = f2bf(v.z);
    t[c4 * 4 + 3][r] = f2bf(v.w);
  }
  __syncthreads();
#pragma unroll
  for (int p = 0; p < 4; p++) {
    int oc = (tid >> 4) + p * 16;
    int ch = tid & 15;
    ushort4 v = *(ushort4*)(&t[oc][ch * 4]);
    *(ushort4*)(dst + (size_t)(c0 + oc) * R + r0 + ch * 4) = v;
  }
}

// ---------------- gate via MFMA (proven R8: 64 blocks x 128 tokens) ----------
__global__ __launch_bounds__(256) void gate_mfma_kernel(
    const float* __restrict__ x, const float* __restrict__ Wg,
    const float* __restrict__ bg, unsigned short* __restrict__ xb,
    int* __restrict__ gate_e, float* __restrict__ gate_w,
    int* __restrict__ counts, int* __restrict__ nretry,
    int* __restrict__ retry) {
  __shared__ __align__(16) unsigned short As[128][40];
  __shared__ int cnt_s[EE];
  int tid = threadIdx.x;
  int lane = tid & 63;
  int wave = tid >> 6;
  int tok0 = blockIdx.x * 128;
  if (tid < EE) cnt_s[tid] = 0;
  int e = lane & 15;
  int kb = (lane >> 4) * 8;
  bf16x8 bfrag[16];
#pragma unroll
  for (int ks = 0; ks < 16; ks++) {
    int kbase = ks * 32 + kb;
#pragma unroll
    for (int j = 0; j < 8; j++)
      bfrag[ks][j] = (short)f2bf(Wg[(kbase + j) * EE + e]);
  }
  float bge = bg[e];
  f32x4 acc[2];
  {
    f32x4 z = {0.f, 0.f, 0.f, 0.f};
    acc[0] = z; acc[1] = z;
  }
  int srow = tid >> 1;
  int sc0 = (tid & 1) * 16;
  const float* xrow = x + (size_t)(tok0 + srow) * DD + sc0;
  unsigned short* xbrow = xb + (size_t)(tok0 + srow) * DD + sc0;
  for (int ks = 0; ks < 16; ks++) {
    int k0 = ks * 32;
    __syncthreads();
    float4 v0 = *(const float4*)(xrow + k0);
    float4 v1 = *(const float4*)(xrow + k0 + 4);
    float4 v2 = *(const float4*)(xrow + k0 + 8);
    float4 v3 = *(const float4*)(xrow + k0 + 12);
    u16x8 w0, w1;
    w0[0] = f2bf(v0.x); w0[1] = f2bf(v0.y); w0[2] = f2bf(v0.z); w0[3] = f2bf(v0.w);
    w0[4] = f2bf(v1.x); w0[5] = f2bf(v1.y); w0[6] = f2bf(v1.z); w0[7] = f2bf(v1.w);
    w1[0] = f2bf(v2.x); w1[1] = f2bf(v2.y); w1[2] = f2bf(v2.z); w1[3] = f2bf(v2.w);
    w1[4] = f2bf(v3.x); w1[5] = f2bf(v3.y); w1[6] = f2bf(v3.z); w1[7] = f2bf(v3.w);
    *(u16x8*)(xbrow + k0) = w0;
    *(u16x8*)(xbrow + k0 + 8) = w1;
    *(u16x8*)(&As[srow][sc0]) = w0;
    *(u16x8*)(&As[srow][sc0 + 8]) = w1;
    __syncthreads();
    bf16x8 a0 = *(const bf16x8*)(&As[wave * 32 + (lane & 15)][kb]);
    bf16x8 a1 = *(const bf16x8*)(&As[wave * 32 + 16 + (lane & 15)][kb]);
    acc[0] = __builtin_amdgcn_mfma_f32_16x16x32_bf16(a0, bfrag[ks], acc[0], 0, 0, 0);
    acc[1] = __builtin_amdgcn_mfma_f32_16x16x32_bf16(a1, bfrag[ks], acc[1], 0, 0, 0);
  }
#pragma unroll
  for (int m = 0; m < 2; m++) {
#pragma unroll
    for (int r = 0; r < 4; r++) {
      float lf = acc[m][r] + bge;
      float v1 = -1e30f, v2 = -1e30f, v3 = -1e30f;
      int i1 = 0, i2 = 0;
#pragma unroll
      for (int q = 0; q < EE; q++) {
        float v = __shfl(lf, (lane & 48) | q);
        if (v > v1) { v3 = v2; v2 = v1; i2 = i1; v1 = v; i1 = q; }
        else if (v > v2) { v3 = v2; v2 = v; i2 = q; }
        else if (v > v3) { v3 = v; }
      }
      if ((lane & 15) == 0) {
        int t2 = tok0 + wave * 32 + m * 16 + ((lane >> 4) << 2) + r;
        float p = expf(v2 - v1);
        float s = 1.0f / (1.0f + p);
        gate_e[t2 * 2] = i1;
        gate_e[t2 * 2 + 1] = i2;
        gate_w[t2 * 2] = s;
        gate_w[t2 * 2 + 1] = p * s;
        atomicAdd(&cnt_s[i1], 1);
        atomicAdd(&cnt_s[i2], 1);
        if (v2 - v3 < 0.02f) {
          int pos = atomicAdd(nretry, 1);
          if (pos < RETRYCAP) retry[pos] = t2;
        }
      }
    }
  }
  __syncthreads();
  if (tid < EE) atomicAdd(&counts[tid], cnt_s[tid]);
}

// ---------------- gatefix: exact f64 recompute for near-tie tokens ----------
__global__ __launch_bounds__(256) void gatefix_kernel(
    const float* __restrict__ x, const float* __restrict__ Wg,
    const float* __restrict__ bg, const int* __restrict__ nretry,
    const int* __restrict__ retry, int* __restrict__ gate_e,
    float* __restrict__ gate_w, int* __restrict__ counts) {
  __shared__ float lg[16][17];
  __shared__ int toks[16];
  int tid = threadIdx.x;
  int sl = tid >> 4, e = tid & 15;
  int s = blockIdx.x * 16 + sl;
  int n = *nretry; if (n > RETRYCAP) n = RETRYCAP;
  int active = (s < n);
  int tok = 0;
  if (active) tok = retry[s];
  if (active) {
    const float* xr = x + (size_t)tok * DD;
    double a0 = 0.0, a1 = 0.0, a2 = 0.0, a3 = 0.0;
    for (int i = 0; i < DD / 4; i++) {
      a0 += (double)xr[i * 4 + 0] * (double)Wg[(i * 4 + 0) * EE + e];
      a1 += (double)xr[i * 4 + 1] * (double)Wg[(i * 4 + 1) * EE + e];
      a2 += (double)xr[i * 4 + 2] * (double)Wg[(i * 4 + 2) * EE + e];
      a3 += (double)xr[i * 4 + 3] * (double)Wg[(i * 4 + 3) * EE + e];
    }
    double acc = (a0 + a1) + (a2 + a3);
    lg[sl][e] = (float)(acc + (double)bg[e]);
    toks[sl] = tok;
  }
  __syncthreads();
  if (active && e == 0) {
    float v1 = -1e30f, v2 = -1e30f;
    int i1 = 0, i2 = 0;
#pragma unroll
    for (int q = 0; q < EE; q++) {
      float v = lg[sl][q];
      if (v > v1) { v2 = v1; i2 = i1; v1 = v; i1 = q; }
      else if (v > v2) { v2 = v; i2 = q; }
    }
    int t2 = toks[sl];
    int o1 = gate_e[t2 * 2], o2 = gate_e[t2 * 2 + 1];
    float p = expf(v2 - v1);
    float sc = 1.0f / (1.0f + p);
    gate_e[t2 * 2] = i1;
    gate_e[t2 * 2 + 1] = i2;
    gate_w[t2 * 2] = sc;
    gate_w[t2 * 2 + 1] = p * sc;
    if (o1 != i1 || o2 != i2) {
      atomicSub(&counts[o1], 1);
      atomicSub(&counts[o2], 1);
      atomicAdd(&counts[i1], 1);
      atomicAdd(&counts[i2], 1);
    }
  }
}

// ---------------- scan: offsets + tile map (tiny) ----------------
__global__ void scan_kernel(const int* __restrict__ counts, int* __restrict__ offs,
                            int* __restrict__ tile_expert, int* __restrict__ ntiles,
                            int* __restrict__ fill) {
  if (threadIdx.x == 0) {
    int off = 0, nt = 0;
    for (int e = 0; e < EE; e++) {
      offs[e] = off;
      fill[e] = 0;
      int tiles = (counts[e] + BM - 1) / BM;
      for (int t = 0; t < tiles; t++) tile_expert[nt++] = e;
      off += tiles * BM;
    }
    offs[EE] = off;
    ntiles[0] = nt;
  }
}

// ---------------- scatter: hierarchical (LDS count -> 16 global atomics/blk) --
__global__ __launch_bounds__(256) void scatter_kernel(
    const int* __restrict__ gate_e, const float* __restrict__ gate_w,
    const int* __restrict__ offs, int* __restrict__ fill,
    int* __restrict__ slot_token, float* __restrict__ slot_w,
    int* __restrict__ slot_of) {
  __shared__ int lcnt[EE];
  __shared__ int lbase[EE];
  int tid = threadIdx.x;
  int t = blockIdx.x * 256 + tid;
  if (tid < EE) lcnt[tid] = 0;
  __syncthreads();
  int e0 = gate_e[t * 2], e1 = gate_e[t * 2 + 1];
  int p0 = atomicAdd(&lcnt[e0], 1);
  int p1 = atomicAdd(&lcnt[e1], 1);
  __syncthreads();
  if (tid < EE) lbase[tid] = atomicAdd(&fill[tid], lcnt[tid]);
  __syncthreads();
  int s0 = offs[e0] + lbase[e0] + p0;
  int s1 = offs[e1] + lbase[e1] + p1;
  slot_token[s0] = t;
  slot_w[s0] = gate_w[t * 2];
  slot_of[t * 2] = s0;
  slot_token[s1] = t;
  slot_w[s1] = gate_w[t * 2 + 1];
  slot_of[t * 2 + 1] = s1;
}

// ---------------- GEMM1: 128x128, BK=32, counted-vmcnt dbuf pipeline --------
// h = gelu(x[slot] @ W1[e] + b1[e]); grid (HH/128, MAXTILES)
__global__ __launch_bounds__(256) void gemm1_kernel(
    const unsigned short* __restrict__ xb, const unsigned short* __restrict__ w1t,
    const float* __restrict__ b1, const int* __restrict__ slot_token,
    const int* __restrict__ tile_expert, const int* __restrict__ ntiles,
    unsigned short* __restrict__ hb) {
  int mt = blockIdx.y;
  if (mt >= ntiles[0]) return;
  int e = tile_expert[mt];
  int row0 = mt * BM;
  int n0 = blockIdx.x * 128;
  __shared__ unsigned short As[2][128][32];  // 16 KB
  __shared__ unsigned short Bs[2][128][32];  // 16 KB
  int tid = threadIdx.x;
  int lane = tid & 63;
  int wave = tid >> 6;
  int wm = wave >> 1, wn = wave & 1;
  int ra = tid >> 2, c = tid & 3;
  int tok_a = slot_token[row0 + ra]; if (tok_a < 0) tok_a = 0;
  int tok_b = slot_token[row0 + ra + 64]; if (tok_b < 0) tok_b = 0;
  const unsigned short* wbase = w1t + ((size_t)e * HH * DD);
  const unsigned short* gA0 = xb + (size_t)tok_a * DD + c * 8;
  const unsigned short* gA1 = xb + (size_t)tok_b * DD + c * 8;
  const unsigned short* gB0 = wbase + (size_t)(n0 + ra) * DD + c * 8;
  const unsigned short* gB1 = wbase + (size_t)(n0 + ra + 64) * DD + c * 8;
  f32x4 acc[4][4];
#pragma unroll
  for (int m = 0; m < 4; m++)
#pragma unroll
    for (int n = 0; n < 4; n++) {
      f32x4 z = {0.f, 0.f, 0.f, 0.f};
      acc[m][n] = z;
    }
  gload16(gA0, &As[0][ra][c * 8]);
  gload16(gA1, &As[0][ra + 64][c * 8]);
  gload16(gB0, &Bs[0][ra][c * 8]);
  gload16(gB1, &Bs[0][ra + 64][c * 8]);
  int cur = 0;
  for (int kk = 0; kk < DD / 32; kk++) {
    if (kk + 1 < DD / 32) {
      int k1 = (kk + 1) * 32;
      int nx = cur ^ 1;
      gload16(gA0 + k1, &As[nx][ra][c * 8]);
      gload16(gA1 + k1, &As[nx][ra + 64][c * 8]);
      gload16(gB0 + k1, &Bs[nx][ra][c * 8]);
      gload16(gB1 + k1, &Bs[nx][ra + 64][c * 8]);
      asm volatile("s_waitcnt vmcnt(4)" ::: "memory");
    } else {
      asm volatile("s_waitcnt vmcnt(0)" ::: "memory");
    }
    __builtin_amdgcn_s_barrier();
    bf16x8 a[4], b[4];
#pragma unroll
    for (int m = 0; m < 4; m++)
      a[m] = *(const bf16x8*)(&As[cur][wm * 64 + m * 16 + (lane & 15)][(lane >> 4) * 8]);
#pragma unroll
    for (int n = 0; n < 4; n++)
      b[n] = *(const bf16x8*)(&Bs[cur][wn * 64 + n * 16 + (lane & 15)][(lane >> 4) * 8]);
#pragma unroll
    for (int m = 0; m < 4; m++)
#pragma unroll
      for (int n = 0; n < 4; n++)
        acc[m][n] = __builtin_amdgcn_mfma_f32_16x16x32_bf16(a[m], b[n], acc[m][n], 0, 0, 0);
    asm volatile("" ::: "memory");
    __builtin_amdgcn_s_barrier();
    cur ^= 1;
  }
  const float* b1e = b1 + (size_t)e * HH;
#pragma unroll
  for (int m = 0; m < 4; m++) {
#pragma unroll
    for (int r = 0; r < 4; r++) {
      int slot = row0 + wm * 64 + m * 16 + ((lane >> 4) << 2) + r;
      unsigned short* hrow = hb + (size_t)slot * HH;
#pragma unroll
      for (int n = 0; n < 4; n++) {
        int hc = n0 + wn * 64 + n * 16 + (lane & 15);
        float v = acc[m][n][r] + b1e[hc];
        hrow[hc] = f2bf(gelu_f(v));
      }
    }
  }
}

// ---------------- GEMM2: 128x128, BK=32, counted-vmcnt dbuf pipeline --------
// yw[slot] = w*(h[slot] @ W2[e] + b2[e]); grid (DD/128, MAXTILES)
template <int USE_Y>
__global__ __launch_bounds__(256) void gemm2_kernel(
    const unsigned short* __restrict__ hb, const unsigned short* __restrict__ w2t,
    const float* __restrict__ b2, const int* __restrict__ slot_token,
    const float* __restrict__ slot_w, const int* __restrict__ tile_expert,
    const int* __restrict__ ntiles, unsigned short* __restrict__ yw,
    float* __restrict__ out) {
  int mt = blockIdx.y;
  if (mt >= ntiles[0]) return;
  int e = tile_expert[mt];
  int row0 = mt * BM;
  int n0 = blockIdx.x * 128;
  __shared__ unsigned short As[2][128][32];
  __shared__ unsigned short Bs[2][128][32];
  int tid = threadIdx.x;
  int lane = tid & 63;
  int wave = tid >> 6;
  int wm = wave >> 1, wn = wave & 1;
  int ra = tid >> 2, c = tid & 3;
  const unsigned short* wbase = w2t + ((size_t)e * DD * HH);
  const unsigned short* gA0 = hb + (size_t)(row0 + ra) * HH + c * 8;
  const unsigned short* gA1 = hb + (size_t)(row0 + ra + 64) * HH + c * 8;
  const unsigned short* gB0 = wbase + (size_t)(n0 + ra) * HH + c * 8;
  const unsigned short* gB1 = wbase + (size_t)(n0 + ra + 64) * HH + c * 8;
  f32x4 acc[4][4];
#pragma unroll
  for (int m = 0; m < 4; m++)
#pragma unroll
    for (int n = 0; n < 4; n++) {
      f32x4 z = {0.f, 0.f, 0.f, 0.f};
      acc[m][n] = z;
    }
  gload16(gA0, &As[0][ra][c * 8]);
  gload16(gA1, &As[0][ra + 64][c * 8]);
  gload16(gB0, &Bs[0][ra][c * 8]);
  gload16(gB1, &Bs[0][ra + 64][c * 8]);
  int cur = 0;
  for (int kk = 0; kk < HH / 32; kk++) {
    if (kk + 1 < HH / 32) {
      int k1 = (kk + 1) * 32;
      int nx = cur ^ 1;
      gload16(gA0 + k1, &As[nx][ra][c * 8]);
      gload16(gA1 + k1, &As[nx][ra + 64][c * 8]);
      gload16(gB0 + k1, &Bs[nx][ra][c * 8]);
      gload16(gB1 + k1, &Bs[nx][ra + 64][c * 8]);
      asm volatile("s_waitcnt vmcnt(4)" ::: "memory");
    } else {
      asm volatile("s_waitcnt vmcnt(0)" ::: "memory");
    }
    __builtin_amdgcn_s_barrier();
    bf16x8 a[4], b[4];
#pragma unroll
    for (int m = 0; m < 4; m++)
      a[m] = *(const bf16x8*)(&As[cur][wm * 64 + m * 16 + (lane & 15)][(lane >> 4) * 8]);
#pragma unroll
    for (int n = 0; n < 4; n++)
      b[n] = *(const bf16x8*)(&Bs[cur][wn * 64 + n * 16 + (lane & 15)][(lane >> 4) * 8]);
#pragma unroll
    for (int m = 0; m < 4; m++)
#pragma unroll
      for (int n = 0; n < 4; n++)
        acc[m][n] = __builtin_amdgcn_mfma_f32_16x16x32_bf16(a[m], b[n], acc[m][n], 0, 0, 0);
    asm volatile("" ::: "memory");
    __builtin_amdgcn_s_barrier();
    cur ^= 1;
  }
  const float* b2e = b2 + (size_t)e * DD;
#pragma unroll
  for (int m = 0; m < 4; m++) {
#pragma unroll
    for (int r = 0; r < 4; r++) {
      int slot = row0 + wm * 64 + m * 16 + ((lane >> 4) << 2) + r;
      if (USE_Y) {
        float w = slot_w[slot];
        unsigned short* yrow = yw + (size_t)slot * DD;
#pragma unroll
        for (int n = 0; n < 4; n++) {
          int dc = n0 + wn * 64 + n * 16 + (lane & 15);
          yrow[dc] = f2bf(w * (acc[m][n][r] + b2e[dc]));
        }
      } else {
        int tok = slot_token[slot];
        if (tok >= 0) {
          float w = slot_w[slot];
          float* orow = out + (size_t)tok * DD;
#pragma unroll
          for (int n = 0; n < 4; n++) {
            int dc = n0 + wn * 64 + n * 16 + (lane & 15);
            float v = acc[m][n][r] + b2e[dc];
            atomicAdd(&orow[dc], w * v);
          }
        }
      }
    }
  }
}

// ---------------- combine: out[t] = yw[s1] + yw[s2] ----------------
__global__ __launch_bounds__(256) void combine_kernel(
    const unsigned short* __restrict__ yw, const int* __restrict__ slot_of,
    float* __restrict__ out) {
  int gid = blockIdx.x * 256 + threadIdx.x;
  int t = gid >> 6;
  int d0 = (gid & 63) * 8;
  int s1 = slot_of[t * 2], s2 = slot_of[t * 2 + 1];
  const ushort4* p1 = (const ushort4*)(yw + (size_t)s1 * DD + d0);
  const ushort4* p2 = (const ushort4*)(yw + (size_t)s2 * DD + d0);
  ushort4 a0 = p1[0], a1 = p1[1];
  ushort4 b0 = p2[0], b1 = p2[1];
  float4 o0, o1;
  o0.x = bf2f(a0.x) + bf2f(b0.x);
  o0.y = bf2f(a0.y) + bf2f(b0.y);
  o0.z = bf2f(a0.z) + bf2f(b0.z);
  o0.w = bf2f(a0.w) + bf2f(b0.w);
  o1.x = bf2f(a1.x) + bf2f(b1.x);
  o1.y = bf2f(a1.y) + bf2f(b1.y);
  o1.z = bf2f(a1.z) + bf2f(b1.z);
  o1.w = bf2f(a1.w) + bf2f(b1.w);
  float* orow = out + (size_t)t * DD + d0;
  ((float4*)orow)[0] = o0;
  ((float4*)orow)[1] = o1;
}

extern "C" void kernel_launch(void* const* d_in, const int* in_sizes, int n_in,
                              void* d_out, int out_size, void* d_ws, size_t ws_size,
                              hipStream_t stream) {
  const float* x  = (const float*)d_in[0];
  const float* Wg = (const float*)d_in[1];
  const float* bg = (const float*)d_in[2];
  const float* W1 = (const float*)d_in[3];
  const float* b1 = (const float*)d_in[4];
  const float* W2 = (const float*)d_in[5];
  const float* b2 = (const float*)d_in[6];
  float* out = (float*)d_out;

  uint8_t* w = (uint8_t*)d_ws;
  size_t o = 0;
  unsigned short* xb  = (unsigned short*)(w + o); o += (size_t)TT * DD * 2;       // 8 MB
  unsigned short* w1t = (unsigned short*)(w + o); o += (size_t)EE * DD * HH * 2;  // 16 MB
  unsigned short* w2t = (unsigned short*)(w + o); o += (size_t)EE * DD * HH * 2;  // 16 MB
  unsigned short* hb  = (unsigned short*)(w + o); o += (size_t)NSLOT * HH * 2;    // 37.7 MB
  int*   slot_token = (int*)(w + o);   o += (size_t)NSLOT * 4;
  float* slot_w     = (float*)(w + o); o += (size_t)NSLOT * 4;
  int*   slot_of    = (int*)(w + o);   o += (size_t)TT * 2 * 4;
  int*   gate_e     = (int*)(w + o);   o += (size_t)TT * 2 * 4;
  float* gate_w     = (float*)(w + o); o += (size_t)TT * 2 * 4;
  int*   counts     = (int*)(w + o);   o += 64;   // counts[16]
  int*   nretry     = (int*)(w + o);   o += 64;   // adjacent: one 128B memset
  int*   tile_expert= (int*)(w + o);   o += 640;
  int*   ntiles     = (int*)(w + o);   o += 64;
  int*   offs       = (int*)(w + o);   o += 128;
  int*   fill       = (int*)(w + o);   o += 64;
  int*   retry      = (int*)(w + o);   o += RETRYCAP * 4;
  unsigned short* yw = (unsigned short*)(w + o);
  size_t need_y = o + (size_t)NSLOT * DD * 2;   // +18.9 MB
  int use_y = (ws_size >= need_y);

  hipMemsetAsync(counts, 0, 128, stream);  // counts + nretry
  hipMemsetAsync(slot_token, 0xFF, (size_t)NSLOT * 4, stream);
  if (!use_y) hipMemsetAsync(d_out, 0, (size_t)TT * DD * 4, stream);

  // W1 [E][512][1024] -> w1t [E][1024][512]
  {
    dim3 g(HH / 64, DD / 64, EE);
    transpose_cv_kernel<<<g, 256, 0, stream>>>(W1, w1t, DD, HH);
  }
  // W2 [E][1024][512] -> w2t [E][512][1024]
  {
    dim3 g(DD / 64, HH / 64, EE);
    transpose_cv_kernel<<<g, 256, 0, stream>>>(W2, w2t, HH, DD);
  }
  gate_mfma_kernel<<<TT / 128, 256, 0, stream>>>(x, Wg, bg, xb, gate_e, gate_w,
                                                 counts, nretry, retry);
  gatefix_kernel<<<RETRYCAP / 16, 256, 0, stream>>>(x, Wg, bg, nretry, retry,
                                                    gate_e, gate_w, counts);
  scan_kernel<<<1, 64, 0, stream>>>(counts, offs, tile_expert, ntiles, fill);
  scatter_kernel<<<TT / 256, 256, 0, stream>>>(gate_e, gate_w, offs, fill,
                                               slot_token, slot_w, slot_of);
  {
    dim3 g(HH / 128, MAXTILES);
    gemm1_kernel<<<g, 256, 0, stream>>>(xb, w1t, b1, slot_token, tile_expert, ntiles, hb);
  }
  {
    dim3 g(DD / 128, MAXTILES);
    if (use_y)
      gemm2_kernel<1><<<g, 256, 0, stream>>>(hb, w2t, b2, slot_token, slot_w,
                                             tile_expert, ntiles, yw, out);
    else
      gemm2_kernel<0><<<g, 256, 0, stream>>>(hb, w2t, b2, slot_token, slot_w,
                                             tile_expert, ntiles, yw, out);
  }
  if (use_y) {
    combine_kernel<<<TT * (DD / 8) / 256, 256, 0, stream>>>(yw, slot_of, out);
  }
}

// Round 15
// 177.361 us; speedup vs baseline: 1.3316x; 1.0244x over previous
//
#include <hip/hip_runtime.h>
#include <hip/hip_bf16.h>
#include <math.h>

#define TT 8192
#define DD 512
#define HH 1024
#define EE 16
#define NSLOT 18432   // 144 * 128 max padded slots
#define MAXTILES 144
#define BM 128
#define RETRYCAP 1024

typedef __attribute__((ext_vector_type(8))) short bf16x8;
typedef __attribute__((ext_vector_type(8))) unsigned short u16x8;
typedef __attribute__((ext_vector_type(4))) float f32x4;

__device__ __forceinline__ unsigned short f2bf(float f) {
  union { float f; unsigned u; } v; v.f = f;
  unsigned r = v.u + 0x7fffu + ((v.u >> 16) & 1u);
  return (unsigned short)(r >> 16);
}

__device__ __forceinline__ float bf2f(unsigned short u) {
  union { unsigned u; float f; } v; v.u = ((unsigned)u) << 16;
  return v.f;
}

__device__ __forceinline__ void gload16(const void* g, void* l) {
  __builtin_amdgcn_global_load_lds(
      (const __attribute__((address_space(1))) unsigned int*)g,
      (__attribute__((address_space(3))) unsigned int*)l, 16, 0, 0);
}

// Abramowitz-Stegun 7.1.26 erf approx (|err| <= 1.5e-7)
__device__ __forceinline__ float gelu_f(float v) {
  float s = fabsf(v) * 0.70710678118654752f;
  float t = 1.0f / (1.0f + 0.3275911f * s);
  float poly = t * (0.254829592f +
              t * (-0.284496736f +
              t * (1.421413741f +
              t * (-1.453152027f +
              t * 1.061405429f))));
  float erfa = 1.0f - poly * __expf(-s * s);
  float erfv = (v >= 0.f) ? erfa : -erfa;
  return 0.5f * v * (1.0f + erfv);
}

// expert/row0 from counts: tile mt -> (expert, row0, valid)
__device__ __forceinline__ int tile_decode(const int* __restrict__ counts,
                                           int mt, int* e_out, int* row0_out) {
  int off = 0, rem = mt;
#pragma unroll
  for (int q = 0; q < EE; q++) {
    int tl = (counts[q] + BM - 1) / BM;
    if (rem < tl) { *e_out = q; *row0_out = off + rem * BM; return 1; }
    rem -= tl;
    off += tl * BM;
  }
  return 0;
}

// ------- transposes merged: bid<2048 W1 [E][512][1024]->[E][1024][512];
//         else W2 [E][1024][512]->[E][512][1024] -------
__global__ __launch_bounds__(256) void transpose_cv_kernel(
    const float* __restrict__ W1, const float* __restrict__ W2,
    unsigned short* __restrict__ w1t, unsigned short* __restrict__ w2t) {
  __shared__ unsigned short t[64][68];
  int bid = blockIdx.x;
  int tid = threadIdx.x;
  const float* src;
  unsigned short* dst;
  int R, C, c0, r0;
  if (bid < 2048) {
    int cx = bid & 15, ry = (bid >> 4) & 7, mat = bid >> 7;
    src = W1 + (size_t)mat * DD * HH; dst = w1t + (size_t)mat * DD * HH;
    R = DD; C = HH; c0 = cx * 64; r0 = ry * 64;
  } else {
    int b = bid - 2048;
    int cx = b & 7, ry = (b >> 3) & 15, mat = b >> 7;
    src = W2 + (size_t)mat * DD * HH; dst = w2t + (size_t)mat * DD * HH;
    R = HH; C = DD; c0 = cx * 64; r0 = ry * 64;
  }
#pragma unroll
  for (int p = 0; p < 4; p++) {
    int r = tid >> 2;
    int c4 = (tid & 3) + p * 4;
    float4 v = *(const float4*)(src + (size_t)(r0 + r) * C + c0 + c4 * 4);
    t[c4 * 4 + 0][r] = f2bf(v.x);
    t[c4 * 4 + 1][r] = f2bf(v.y);
    t[c4 * 4 + 2][r] = f2bf(v.z);
    t[c4 * 4 + 3][r] = f2bf(v.w);
  }
  __syncthreads();
#pragma unroll
  for (int p = 0; p < 4; p++) {
    int oc = (tid >> 4) + p * 16;
    int ch = tid & 15;
    ushort4 v = *(ushort4*)(&t[oc][ch * 4]);
    *(ushort4*)(dst + (size_t)(c0 + oc) * R + r0 + ch * 4) = v;
  }
}

// ---------------- gate via MFMA (proven R8: 64 blocks x 128 tokens) ----------
__global__ __launch_bounds__(256) void gate_mfma_kernel(
    const float* __restrict__ x, const float* __restrict__ Wg,
    const float* __restrict__ bg, unsigned short* __restrict__ xb,
    int* __restrict__ gate_e, float* __restrict__ gate_w,
    int* __restrict__ counts, int* __restrict__ nretry,
    int* __restrict__ retry) {
  __shared__ __align__(16) unsigned short As[128][40];
  __shared__ int cnt_s[EE];
  int tid = threadIdx.x;
  int lane = tid & 63;
  int wave = tid >> 6;
  int tok0 = blockIdx.x * 128;
  if (tid < EE) cnt_s[tid] = 0;
  int e = lane & 15;
  int kb = (lane >> 4) * 8;
  bf16x8 bfrag[16];
#pragma unroll
  for (int ks = 0; ks < 16; ks++) {
    int kbase = ks * 32 + kb;
#pragma unroll
    for (int j = 0; j < 8; j++)
      bfrag[ks][j] = (short)f2bf(Wg[(kbase + j) * EE + e]);
  }
  float bge = bg[e];
  f32x4 acc[2];
  {
    f32x4 z = {0.f, 0.f, 0.f, 0.f};
    acc[0] = z; acc[1] = z;
  }
  int srow = tid >> 1;
  int sc0 = (tid & 1) * 16;
  const float* xrow = x + (size_t)(tok0 + srow) * DD + sc0;
  unsigned short* xbrow = xb + (size_t)(tok0 + srow) * DD + sc0;
  for (int ks = 0; ks < 16; ks++) {
    int k0 = ks * 32;
    __syncthreads();
    float4 v0 = *(const float4*)(xrow + k0);
    float4 v1 = *(const float4*)(xrow + k0 + 4);
    float4 v2 = *(const float4*)(xrow + k0 + 8);
    float4 v3 = *(const float4*)(xrow + k0 + 12);
    u16x8 w0, w1;
    w0[0] = f2bf(v0.x); w0[1] = f2bf(v0.y); w0[2] = f2bf(v0.z); w0[3] = f2bf(v0.w);
    w0[4] = f2bf(v1.x); w0[5] = f2bf(v1.y); w0[6] = f2bf(v1.z); w0[7] = f2bf(v1.w);
    w1[0] = f2bf(v2.x); w1[1] = f2bf(v2.y); w1[2] = f2bf(v2.z); w1[3] = f2bf(v2.w);
    w1[4] = f2bf(v3.x); w1[5] = f2bf(v3.y); w1[6] = f2bf(v3.z); w1[7] = f2bf(v3.w);
    *(u16x8*)(xbrow + k0) = w0;
    *(u16x8*)(xbrow + k0 + 8) = w1;
    *(u16x8*)(&As[srow][sc0]) = w0;
    *(u16x8*)(&As[srow][sc0 + 8]) = w1;
    __syncthreads();
    bf16x8 a0 = *(const bf16x8*)(&As[wave * 32 + (lane & 15)][kb]);
    bf16x8 a1 = *(const bf16x8*)(&As[wave * 32 + 16 + (lane & 15)][kb]);
    acc[0] = __builtin_amdgcn_mfma_f32_16x16x32_bf16(a0, bfrag[ks], acc[0], 0, 0, 0);
    acc[1] = __builtin_amdgcn_mfma_f32_16x16x32_bf16(a1, bfrag[ks], acc[1], 0, 0, 0);
  }
#pragma unroll
  for (int m = 0; m < 2; m++) {
#pragma unroll
    for (int r = 0; r < 4; r++) {
      float lf = acc[m][r] + bge;
      float v1 = -1e30f, v2 = -1e30f, v3 = -1e30f;
      int i1 = 0, i2 = 0;
#pragma unroll
      for (int q = 0; q < EE; q++) {
        float v = __shfl(lf, (lane & 48) | q);
        if (v > v1) { v3 = v2; v2 = v1; i2 = i1; v1 = v; i1 = q; }
        else if (v > v2) { v3 = v2; v2 = v; i2 = q; }
        else if (v > v3) { v3 = v; }
      }
      if ((lane & 15) == 0) {
        int t2 = tok0 + wave * 32 + m * 16 + ((lane >> 4) << 2) + r;
        float p = expf(v2 - v1);
        float s = 1.0f / (1.0f + p);
        gate_e[t2 * 2] = i1;
        gate_e[t2 * 2 + 1] = i2;
        gate_w[t2 * 2] = s;
        gate_w[t2 * 2 + 1] = p * s;
        atomicAdd(&cnt_s[i1], 1);
        atomicAdd(&cnt_s[i2], 1);
        if (v2 - v3 < 0.02f) {
          int pos = atomicAdd(nretry, 1);
          if (pos < RETRYCAP) retry[pos] = t2;
        }
      }
    }
  }
  __syncthreads();
  if (tid < EE) atomicAdd(&counts[tid], cnt_s[tid]);
}

// ---------------- gatefix: exact f64 recompute for near-tie tokens ----------
__global__ __launch_bounds__(256) void gatefix_kernel(
    const float* __restrict__ x, const float* __restrict__ Wg,
    const float* __restrict__ bg, const int* __restrict__ nretry,
    const int* __restrict__ retry, int* __restrict__ gate_e,
    float* __restrict__ gate_w, int* __restrict__ counts) {
  __shared__ float lg[16][17];
  __shared__ int toks[16];
  int tid = threadIdx.x;
  int sl = tid >> 4, e = tid & 15;
  int s = blockIdx.x * 16 + sl;
  int n = *nretry; if (n > RETRYCAP) n = RETRYCAP;
  int active = (s < n);
  int tok = 0;
  if (active) tok = retry[s];
  if (active) {
    const float* xr = x + (size_t)tok * DD;
    double a0 = 0.0, a1 = 0.0, a2 = 0.0, a3 = 0.0;
    for (int i = 0; i < DD / 4; i++) {
      a0 += (double)xr[i * 4 + 0] * (double)Wg[(i * 4 + 0) * EE + e];
      a1 += (double)xr[i * 4 + 1] * (double)Wg[(i * 4 + 1) * EE + e];
      a2 += (double)xr[i * 4 + 2] * (double)Wg[(i * 4 + 2) * EE + e];
      a3 += (double)xr[i * 4 + 3] * (double)Wg[(i * 4 + 3) * EE + e];
    }
    double acc = (a0 + a1) + (a2 + a3);
    lg[sl][e] = (float)(acc + (double)bg[e]);
    toks[sl] = tok;
  }
  __syncthreads();
  if (active && e == 0) {
    float v1 = -1e30f, v2 = -1e30f;
    int i1 = 0, i2 = 0;
#pragma unroll
    for (int q = 0; q < EE; q++) {
      float v = lg[sl][q];
      if (v > v1) { v2 = v1; i2 = i1; v1 = v; i1 = q; }
      else if (v > v2) { v2 = v; i2 = q; }
    }
    int t2 = toks[sl];
    int o1 = gate_e[t2 * 2], o2 = gate_e[t2 * 2 + 1];
    float p = expf(v2 - v1);
    float sc = 1.0f / (1.0f + p);
    gate_e[t2 * 2] = i1;
    gate_e[t2 * 2 + 1] = i2;
    gate_w[t2 * 2] = sc;
    gate_w[t2 * 2 + 1] = p * sc;
    if (o1 != i1 || o2 != i2) {
      atomicSub(&counts[o1], 1);
      atomicSub(&counts[o2], 1);
      atomicAdd(&counts[i1], 1);
      atomicAdd(&counts[i2], 1);
    }
  }
}

// ---------------- scatter: hierarchical; offs computed locally from counts --
__global__ __launch_bounds__(256) void scatter_kernel(
    const int* __restrict__ gate_e, const float* __restrict__ gate_w,
    const int* __restrict__ counts, int* __restrict__ fill,
    int* __restrict__ slot_token, float* __restrict__ slot_w,
    int* __restrict__ slot_of) {
  __shared__ int lcnt[EE];
  __shared__ int lbase[EE];
  __shared__ int offs_s[EE];
  int tid = threadIdx.x;
  int t = blockIdx.x * 256 + tid;
  if (tid < EE) lcnt[tid] = 0;
  if (tid == 0) {
    int off = 0;
    for (int q = 0; q < EE; q++) {
      offs_s[q] = off;
      off += ((counts[q] + BM - 1) / BM) * BM;
    }
  }
  __syncthreads();
  int e0 = gate_e[t * 2], e1 = gate_e[t * 2 + 1];
  int p0 = atomicAdd(&lcnt[e0], 1);
  int p1 = atomicAdd(&lcnt[e1], 1);
  __syncthreads();
  if (tid < EE) lbase[tid] = atomicAdd(&fill[tid], lcnt[tid]);
  __syncthreads();
  int s0 = offs_s[e0] + lbase[e0] + p0;
  int s1 = offs_s[e1] + lbase[e1] + p1;
  slot_token[s0] = t;
  slot_w[s0] = gate_w[t * 2];
  slot_of[t * 2] = s0;
  slot_token[s1] = t;
  slot_w[s1] = gate_w[t * 2 + 1];
  slot_of[t * 2 + 1] = s1;
}

// ---------------- GEMM1: 128x128, BK=32, depth-2 counted-vmcnt pipeline -----
// h = gelu(x[slot] @ W1[e] + b1[e]); grid (HH/128, MAXTILES)
__global__ __launch_bounds__(256) void gemm1_kernel(
    const unsigned short* __restrict__ xb, const unsigned short* __restrict__ w1t,
    const float* __restrict__ b1, const int* __restrict__ slot_token,
    const int* __restrict__ counts, unsigned short* __restrict__ hb) {
  int e, row0;
  if (!tile_decode(counts, blockIdx.y, &e, &row0)) return;
  int n0 = blockIdx.x * 128;
  __shared__ unsigned short As[3][128][32];  // 24 KB
  __shared__ unsigned short Bs[3][128][32];  // 24 KB
  int tid = threadIdx.x;
  int lane = tid & 63;
  int wave = tid >> 6;
  int wm = wave >> 1, wn = wave & 1;
  int ra = tid >> 2, c = tid & 3;
  int tok_a = slot_token[row0 + ra]; if (tok_a < 0) tok_a = 0;
  int tok_b = slot_token[row0 + ra + 64]; if (tok_b < 0) tok_b = 0;
  const unsigned short* wbase = w1t + ((size_t)e * HH * DD);
  const unsigned short* gA0 = xb + (size_t)tok_a * DD + c * 8;
  const unsigned short* gA1 = xb + (size_t)tok_b * DD + c * 8;
  const unsigned short* gB0 = wbase + (size_t)(n0 + ra) * DD + c * 8;
  const unsigned short* gB1 = wbase + (size_t)(n0 + ra + 64) * DD + c * 8;
  f32x4 acc[4][4];
#pragma unroll
  for (int m = 0; m < 4; m++)
#pragma unroll
    for (int n = 0; n < 4; n++) {
      f32x4 z = {0.f, 0.f, 0.f, 0.f};
      acc[m][n] = z;
    }
  const int NK = DD / 32;
#pragma unroll
  for (int p = 0; p < 2; p++) {   // stage tiles 0,1 into bufs 0,1
    int kj = p * 32;
    gload16(gA0 + kj, &As[p][ra][c * 8]);
    gload16(gA1 + kj, &As[p][ra + 64][c * 8]);
    gload16(gB0 + kj, &Bs[p][ra][c * 8]);
    gload16(gB1 + kj, &Bs[p][ra + 64][c * 8]);
  }
  for (int kk = 0; kk < NK; kk++) {
    int cur = kk % 3;
    if (kk + 2 < NK) {
      int k2 = (kk + 2) * 32;
      int nx = (kk + 2) % 3;
      gload16(gA0 + k2, &As[nx][ra][c * 8]);
      gload16(gA1 + k2, &As[nx][ra + 64][c * 8]);
      gload16(gB0 + k2, &Bs[nx][ra][c * 8]);
      gload16(gB1 + k2, &Bs[nx][ra + 64][c * 8]);
      asm volatile("s_waitcnt vmcnt(8)" ::: "memory");
    } else if (kk + 1 < NK) {
      asm volatile("s_waitcnt vmcnt(4)" ::: "memory");
    } else {
      asm volatile("s_waitcnt vmcnt(0)" ::: "memory");
    }
    __builtin_amdgcn_s_barrier();
    bf16x8 a[4], b[4];
#pragma unroll
    for (int m = 0; m < 4; m++)
      a[m] = *(const bf16x8*)(&As[cur][wm * 64 + m * 16 + (lane & 15)][(lane >> 4) * 8]);
#pragma unroll
    for (int n = 0; n < 4; n++)
      b[n] = *(const bf16x8*)(&Bs[cur][wn * 64 + n * 16 + (lane & 15)][(lane >> 4) * 8]);
#pragma unroll
    for (int m = 0; m < 4; m++)
#pragma unroll
      for (int n = 0; n < 4; n++)
        acc[m][n] = __builtin_amdgcn_mfma_f32_16x16x32_bf16(a[m], b[n], acc[m][n], 0, 0, 0);
    asm volatile("" ::: "memory");
    __builtin_amdgcn_s_barrier();
  }
  const float* b1e = b1 + (size_t)e * HH;
#pragma unroll
  for (int m = 0; m < 4; m++) {
#pragma unroll
    for (int r = 0; r < 4; r++) {
      int slot = row0 + wm * 64 + m * 16 + ((lane >> 4) << 2) + r;
      unsigned short* hrow = hb + (size_t)slot * HH;
#pragma unroll
      for (int n = 0; n < 4; n++) {
        int hc = n0 + wn * 64 + n * 16 + (lane & 15);
        float v = acc[m][n][r] + b1e[hc];
        hrow[hc] = f2bf(gelu_f(v));
      }
    }
  }
}

// ---------------- GEMM2: 128x128, BK=32, depth-2 counted-vmcnt pipeline -----
// yw[slot] = w*(h[slot] @ W2[e] + b2[e]); grid (DD/128, MAXTILES)
template <int USE_Y>
__global__ __launch_bounds__(256) void gemm2_kernel(
    const unsigned short* __restrict__ hb, const unsigned short* __restrict__ w2t,
    const float* __restrict__ b2, const int* __restrict__ slot_token,
    const float* __restrict__ slot_w, const int* __restrict__ counts,
    unsigned short* __restrict__ yw, float* __restrict__ out) {
  int e, row0;
  if (!tile_decode(counts, blockIdx.y, &e, &row0)) return;
  int n0 = blockIdx.x * 128;
  __shared__ unsigned short As[3][128][32];
  __shared__ unsigned short Bs[3][128][32];
  int tid = threadIdx.x;
  int lane = tid & 63;
  int wave = tid >> 6;
  int wm = wave >> 1, wn = wave & 1;
  int ra = tid >> 2, c = tid & 3;
  const unsigned short* wbase = w2t + ((size_t)e * DD * HH);
  const unsigned short* gA0 = hb + (size_t)(row0 + ra) * HH + c * 8;
  const unsigned short* gA1 = hb + (size_t)(row0 + ra + 64) * HH + c * 8;
  const unsigned short* gB0 = wbase + (size_t)(n0 + ra) * HH + c * 8;
  const unsigned short* gB1 = wbase + (size_t)(n0 + ra + 64) * HH + c * 8;
  f32x4 acc[4][4];
#pragma unroll
  for (int m = 0; m < 4; m++)
#pragma unroll
    for (int n = 0; n < 4; n++) {
      f32x4 z = {0.f, 0.f, 0.f, 0.f};
      acc[m][n] = z;
    }
  const int NK = HH / 32;
#pragma unroll
  for (int p = 0; p < 2; p++) {
    int kj = p * 32;
    gload16(gA0 + kj, &As[p][ra][c * 8]);
    gload16(gA1 + kj, &As[p][ra + 64][c * 8]);
    gload16(gB0 + kj, &Bs[p][ra][c * 8]);
    gload16(gB1 + kj, &Bs[p][ra + 64][c * 8]);
  }
  for (int kk = 0; kk < NK; kk++) {
    int cur = kk % 3;
    if (kk + 2 < NK) {
      int k2 = (kk + 2) * 32;
      int nx = (kk + 2) % 3;
      gload16(gA0 + k2, &As[nx][ra][c * 8]);
      gload16(gA1 + k2, &As[nx][ra + 64][c * 8]);
      gload16(gB0 + k2, &Bs[nx][ra][c * 8]);
      gload16(gB1 + k2, &Bs[nx][ra + 64][c * 8]);
      asm volatile("s_waitcnt vmcnt(8)" ::: "memory");
    } else if (kk + 1 < NK) {
      asm volatile("s_waitcnt vmcnt(4)" ::: "memory");
    } else {
      asm volatile("s_waitcnt vmcnt(0)" ::: "memory");
    }
    __builtin_amdgcn_s_barrier();
    bf16x8 a[4], b[4];
#pragma unroll
    for (int m = 0; m < 4; m++)
      a[m] = *(const bf16x8*)(&As[cur][wm * 64 + m * 16 + (lane & 15)][(lane >> 4) * 8]);
#pragma unroll
    for (int n = 0; n < 4; n++)
      b[n] = *(const bf16x8*)(&Bs[cur][wn * 64 + n * 16 + (lane & 15)][(lane >> 4) * 8]);
#pragma unroll
    for (int m = 0; m < 4; m++)
#pragma unroll
      for (int n = 0; n < 4; n++)
        acc[m][n] = __builtin_amdgcn_mfma_f32_16x16x32_bf16(a[m], b[n], acc[m][n], 0, 0, 0);
    asm volatile("" ::: "memory");
    __builtin_amdgcn_s_barrier();
  }
  const float* b2e = b2 + (size_t)e * DD;
#pragma unroll
  for (int m = 0; m < 4; m++) {
#pragma unroll
    for (int r = 0; r < 4; r++) {
      int slot = row0 + wm * 64 + m * 16 + ((lane >> 4) << 2) + r;
      if (USE_Y) {
        float w = slot_w[slot];
        unsigned short* yrow = yw + (size_t)slot * DD;
#pragma unroll
        for (int n = 0; n < 4; n++) {
          int dc = n0 + wn * 64 + n * 16 + (lane & 15);
          yrow[dc] = f2bf(w * (acc[m][n][r] + b2e[dc]));
        }
      } else {
        int tok = slot_token[slot];
        if (tok >= 0) {
          float w = slot_w[slot];
          float* orow = out + (size_t)tok * DD;
#pragma unroll
          for (int n = 0; n < 4; n++) {
            int dc = n0 + wn * 64 + n * 16 + (lane & 15);
            float v = acc[m][n][r] + b2e[dc];
            atomicAdd(&orow[dc], w * v);
          }
        }
      }
    }
  }
}

// ---------------- combine: out[t] = yw[s1] + yw[s2] ----------------
__global__ __launch_bounds__(256) void combine_kernel(
    const unsigned short* __restrict__ yw, const int* __restrict__ slot_of,
    float* __restrict__ out) {
  int gid = blockIdx.x * 256 + threadIdx.x;
  int t = gid >> 6;
  int d0 = (gid & 63) * 8;
  int s1 = slot_of[t * 2], s2 = slot_of[t * 2 + 1];
  const ushort4* p1 = (const ushort4*)(yw + (size_t)s1 * DD + d0);
  const ushort4* p2 = (const ushort4*)(yw + (size_t)s2 * DD + d0);
  ushort4 a0 = p1[0], a1 = p1[1];
  ushort4 b0 = p2[0], b1 = p2[1];
  float4 o0, o1;
  o0.x = bf2f(a0.x) + bf2f(b0.x);
  o0.y = bf2f(a0.y) + bf2f(b0.y);
  o0.z = bf2f(a0.z) + bf2f(b0.z);
  o0.w = bf2f(a0.w) + bf2f(b0.w);
  o1.x = bf2f(a1.x) + bf2f(b1.x);
  o1.y = bf2f(a1.y) + bf2f(b1.y);
  o1.z = bf2f(a1.z) + bf2f(b1.z);
  o1.w = bf2f(a1.w) + bf2f(b1.w);
  float* orow = out + (size_t)t * DD + d0;
  ((float4*)orow)[0] = o0;
  ((float4*)orow)[1] = o1;
}

extern "C" void kernel_launch(void* const* d_in, const int* in_sizes, int n_in,
                              void* d_out, int out_size, void* d_ws, size_t ws_size,
                              hipStream_t stream) {
  const float* x  = (const float*)d_in[0];
  const float* Wg = (const float*)d_in[1];
  const float* bg = (const float*)d_in[2];
  const float* W1 = (const float*)d_in[3];
  const float* b1 = (const float*)d_in[4];
  const float* W2 = (const float*)d_in[5];
  const float* b2 = (const float*)d_in[6];
  float* out = (float*)d_out;

  uint8_t* w = (uint8_t*)d_ws;
  size_t o = 0;
  unsigned short* xb  = (unsigned short*)(w + o); o += (size_t)TT * DD * 2;       // 8 MB
  unsigned short* w1t = (unsigned short*)(w + o); o += (size_t)EE * DD * HH * 2;  // 16 MB
  unsigned short* w2t = (unsigned short*)(w + o); o += (size_t)EE * DD * HH * 2;  // 16 MB
  unsigned short* hb  = (unsigned short*)(w + o); o += (size_t)NSLOT * HH * 2;    // 37.7 MB
  int*   slot_token = (int*)(w + o);   o += (size_t)NSLOT * 4;
  float* slot_w     = (float*)(w + o); o += (size_t)NSLOT * 4;
  int*   slot_of    = (int*)(w + o);   o += (size_t)TT * 2 * 4;
  int*   gate_e     = (int*)(w + o);   o += (size_t)TT * 2 * 4;
  float* gate_w     = (float*)(w + o); o += (size_t)TT * 2 * 4;
  int*   counts     = (int*)(w + o);   o += 64;   // counts[16]
  int*   nretry     = (int*)(w + o);   o += 64;
  int*   fill       = (int*)(w + o);   o += 64;   // one 192B memset covers all 3
  int*   retry      = (int*)(w + o);   o += RETRYCAP * 4;
  unsigned short* yw = (unsigned short*)(w + o);
  size_t need_y = o + (size_t)NSLOT * DD * 2;   // +18.9 MB
  int use_y = (ws_size >= need_y);

  hipMemsetAsync(counts, 0, 192, stream);  // counts + nretry + fill
  hipMemsetAsync(slot_token, 0xFF, (size_t)NSLOT * 4, stream);
  if (!use_y) hipMemsetAsync(d_out, 0, (size_t)TT * DD * 4, stream);

  transpose_cv_kernel<<<4096, 256, 0, stream>>>(W1, W2, w1t, w2t);
  gate_mfma_kernel<<<TT / 128, 256, 0, stream>>>(x, Wg, bg, xb, gate_e, gate_w,
                                                 counts, nretry, retry);
  gatefix_kernel<<<RETRYCAP / 16, 256, 0, stream>>>(x, Wg, bg, nretry, retry,
                                                    gate_e, gate_w, counts);
  scatter_kernel<<<TT / 256, 256, 0, stream>>>(gate_e, gate_w, counts, fill,
                                               slot_token, slot_w, slot_of);
  {
    dim3 g(HH / 128, MAXTILES);
    gemm1_kernel<<<g, 256, 0, stream>>>(xb, w1t, b1, slot_token, counts, hb);
  }
  {
    dim3 g(DD / 128, MAXTILES);
    if (use_y)
      gemm2_kernel<1><<<g, 256, 0, stream>>>(hb, w2t, b2, slot_token, slot_w,
                                             counts, yw, out);
    else
      gemm2_kernel<0><<<g, 256, 0, stream>>>(hb, w2t, b2, slot_token, slot_w,
                                             counts, yw, out);
  }
  if (use_y) {
    combine_kernel<<<TT * (DD / 8) / 256, 256, 0, stream>>>(yw, slot_of, out);
  }
}

// Round 16
// 172.484 us; speedup vs baseline: 1.3693x; 1.0283x over previous
//
#include <hip/hip_runtime.h>
#include <hip/hip_bf16.h>
#include <math.h>

#define TT 8192
#define DD 512
#define HH 1024
#define EE 16
#define NSLOT 18432   // 144 * 128 max padded slots
#define MAXTILES 144
#define BM 128
#define RETRYCAP 1024

typedef __attribute__((ext_vector_type(8))) short bf16x8;
typedef __attribute__((ext_vector_type(8))) unsigned short u16x8;
typedef __attribute__((ext_vector_type(4))) float f32x4;

__device__ __forceinline__ unsigned short f2bf(float f) {
  union { float f; unsigned u; } v; v.f = f;
  unsigned r = v.u + 0x7fffu + ((v.u >> 16) & 1u);
  return (unsigned short)(r >> 16);
}

__device__ __forceinline__ float bf2f(unsigned short u) {
  union { unsigned u; float f; } v; v.u = ((unsigned)u) << 16;
  return v.f;
}

__device__ __forceinline__ void gload16(const void* g, void* l) {
  __builtin_amdgcn_global_load_lds(
      (const __attribute__((address_space(1))) unsigned int*)g,
      (__attribute__((address_space(3))) unsigned int*)l, 16, 0, 0);
}

// Abramowitz-Stegun 7.1.26 erf approx (|err| <= 1.5e-7)
__device__ __forceinline__ float gelu_f(float v) {
  float s = fabsf(v) * 0.70710678118654752f;
  float t = 1.0f / (1.0f + 0.3275911f * s);
  float poly = t * (0.254829592f +
              t * (-0.284496736f +
              t * (1.421413741f +
              t * (-1.453152027f +
              t * 1.061405429f))));
  float erfa = 1.0f - poly * __expf(-s * s);
  float erfv = (v >= 0.f) ? erfa : -erfa;
  return 0.5f * v * (1.0f + erfv);
}

// expert/row0 from counts: tile mt -> (expert, row0, valid)
__device__ __forceinline__ int tile_decode(const int* __restrict__ counts,
                                           int mt, int* e_out, int* row0_out) {
  int off = 0, rem = mt;
#pragma unroll
  for (int q = 0; q < EE; q++) {
    int tl = (counts[q] + BM - 1) / BM;
    if (rem < tl) { *e_out = q; *row0_out = off + rem * BM; return 1; }
    rem -= tl;
    off += tl * BM;
  }
  return 0;
}

// ------- transposes merged: bid<2048 W1 [E][512][1024]->[E][1024][512];
//         else W2 [E][1024][512]->[E][512][1024] -------
__global__ __launch_bounds__(256) void transpose_cv_kernel(
    const float* __restrict__ W1, const float* __restrict__ W2,
    unsigned short* __restrict__ w1t, unsigned short* __restrict__ w2t) {
  __shared__ unsigned short t[64][68];
  int bid = blockIdx.x;
  int tid = threadIdx.x;
  const float* src;
  unsigned short* dst;
  int R, C, c0, r0;
  if (bid < 2048) {
    int cx = bid & 15, ry = (bid >> 4) & 7, mat = bid >> 7;
    src = W1 + (size_t)mat * DD * HH; dst = w1t + (size_t)mat * DD * HH;
    R = DD; C = HH; c0 = cx * 64; r0 = ry * 64;
  } else {
    int b = bid - 2048;
    int cx = b & 7, ry = (b >> 3) & 15, mat = b >> 7;
    src = W2 + (size_t)mat * DD * HH; dst = w2t + (size_t)mat * DD * HH;
    R = HH; C = DD; c0 = cx * 64; r0 = ry * 64;
  }
#pragma unroll
  for (int p = 0; p < 4; p++) {
    int r = tid >> 2;
    int c4 = (tid & 3) + p * 4;
    float4 v = *(const float4*)(src + (size_t)(r0 + r) * C + c0 + c4 * 4);
    t[c4 * 4 + 0][r] = f2bf(v.x);
    t[c4 * 4 + 1][r] = f2bf(v.y);
    t[c4 * 4 + 2][r] = f2bf(v.z);
    t[c4 * 4 + 3][r] = f2bf(v.w);
  }
  __syncthreads();
#pragma unroll
  for (int p = 0; p < 4; p++) {
    int oc = (tid >> 4) + p * 16;
    int ch = tid & 15;
    ushort4 v = *(ushort4*)(&t[oc][ch * 4]);
    *(ushort4*)(dst + (size_t)(c0 + oc) * R + r0 + ch * 4) = v;
  }
}

// ---------------- gate via MFMA: barrier-free, register fragments -----------
// 256 blocks x 2 waves x 16 tokens. Each lane loads its A-fragment directly
// from x (row = tok0+(lane&15), k = ks*32+(lane>>4)*8), converts in-register
// (the same u16x8 is the xb write-back), and feeds the MFMA. No LDS staging,
// no inner barriers -> loads pipeline across MFMAs.
__global__ __launch_bounds__(128) void gate_mfma_kernel(
    const float* __restrict__ x, const float* __restrict__ Wg,
    const float* __restrict__ bg, unsigned short* __restrict__ xb,
    int* __restrict__ gate_e, float* __restrict__ gate_w,
    int* __restrict__ counts, int* __restrict__ nretry,
    int* __restrict__ retry) {
  __shared__ int cnt_s[EE];
  int tid = threadIdx.x;
  int lane = tid & 63;
  int wave = tid >> 6;                    // 0..1
  int tok0 = blockIdx.x * 32 + wave * 16; // 16 tokens per wave
  if (tid < EE) cnt_s[tid] = 0;
  __syncthreads();
  int e = lane & 15;
  int kb = (lane >> 4) * 8;
  bf16x8 bfrag[16];
#pragma unroll
  for (int ks = 0; ks < 16; ks++) {
    int kbase = ks * 32 + kb;
#pragma unroll
    for (int j = 0; j < 8; j++)
      bfrag[ks][j] = (short)f2bf(Wg[(kbase + j) * EE + e]);
  }
  float bge = bg[e];
  f32x4 acc = {0.f, 0.f, 0.f, 0.f};
  const float* xrow = x + (size_t)(tok0 + (lane & 15)) * DD + kb;
  unsigned short* xbrow = xb + (size_t)(tok0 + (lane & 15)) * DD + kb;
#pragma unroll 4
  for (int ks = 0; ks < 16; ks++) {
    int k0 = ks * 32;
    float4 v0 = *(const float4*)(xrow + k0);
    float4 v1 = *(const float4*)(xrow + k0 + 4);
    u16x8 w0;
    w0[0] = f2bf(v0.x); w0[1] = f2bf(v0.y); w0[2] = f2bf(v0.z); w0[3] = f2bf(v0.w);
    w0[4] = f2bf(v1.x); w0[5] = f2bf(v1.y); w0[6] = f2bf(v1.z); w0[7] = f2bf(v1.w);
    *(u16x8*)(xbrow + k0) = w0;
    union { u16x8 u; bf16x8 b; } cv; cv.u = w0;
    acc = __builtin_amdgcn_mfma_f32_16x16x32_bf16(cv.b, bfrag[ks], acc, 0, 0, 0);
  }
#pragma unroll
  for (int r = 0; r < 4; r++) {
    float lf = acc[r] + bge;
    float v1 = -1e30f, v2 = -1e30f, v3 = -1e30f;
    int i1 = 0, i2 = 0;
#pragma unroll
    for (int q = 0; q < EE; q++) {
      float v = __shfl(lf, (lane & 48) | q);
      if (v > v1) { v3 = v2; v2 = v1; i2 = i1; v1 = v; i1 = q; }
      else if (v > v2) { v3 = v2; v2 = v; i2 = q; }
      else if (v > v3) { v3 = v; }
    }
    if ((lane & 15) == 0) {
      int t2 = tok0 + ((lane >> 4) << 2) + r;
      float p = expf(v2 - v1);
      float s = 1.0f / (1.0f + p);
      gate_e[t2 * 2] = i1;
      gate_e[t2 * 2 + 1] = i2;
      gate_w[t2 * 2] = s;
      gate_w[t2 * 2 + 1] = p * s;
      atomicAdd(&cnt_s[i1], 1);
      atomicAdd(&cnt_s[i2], 1);
      if (v2 - v3 < 0.02f) {
        int pos = atomicAdd(nretry, 1);
        if (pos < RETRYCAP) retry[pos] = t2;
      }
    }
  }
  __syncthreads();
  if (tid < EE) atomicAdd(&counts[tid], cnt_s[tid]);
}

// ---------------- gatefix: exact f64 recompute for near-tie tokens ----------
__global__ __launch_bounds__(256) void gatefix_kernel(
    const float* __restrict__ x, const float* __restrict__ Wg,
    const float* __restrict__ bg, const int* __restrict__ nretry,
    const int* __restrict__ retry, int* __restrict__ gate_e,
    float* __restrict__ gate_w, int* __restrict__ counts) {
  __shared__ float lg[16][17];
  __shared__ int toks[16];
  int tid = threadIdx.x;
  int sl = tid >> 4, e = tid & 15;
  int s = blockIdx.x * 16 + sl;
  int n = *nretry; if (n > RETRYCAP) n = RETRYCAP;
  int active = (s < n);
  int tok = 0;
  if (active) tok = retry[s];
  if (active) {
    const float* xr = x + (size_t)tok * DD;
    double a0 = 0.0, a1 = 0.0, a2 = 0.0, a3 = 0.0;
    for (int i = 0; i < DD / 4; i++) {
      a0 += (double)xr[i * 4 + 0] * (double)Wg[(i * 4 + 0) * EE + e];
      a1 += (double)xr[i * 4 + 1] * (double)Wg[(i * 4 + 1) * EE + e];
      a2 += (double)xr[i * 4 + 2] * (double)Wg[(i * 4 + 2) * EE + e];
      a3 += (double)xr[i * 4 + 3] * (double)Wg[(i * 4 + 3) * EE + e];
    }
    double acc = (a0 + a1) + (a2 + a3);
    lg[sl][e] = (float)(acc + (double)bg[e]);
    toks[sl] = tok;
  }
  __syncthreads();
  if (active && e == 0) {
    float v1 = -1e30f, v2 = -1e30f;
    int i1 = 0, i2 = 0;
#pragma unroll
    for (int q = 0; q < EE; q++) {
      float v = lg[sl][q];
      if (v > v1) { v2 = v1; i2 = i1; v1 = v; i1 = q; }
      else if (v > v2) { v2 = v; i2 = q; }
    }
    int t2 = toks[sl];
    int o1 = gate_e[t2 * 2], o2 = gate_e[t2 * 2 + 1];
    float p = expf(v2 - v1);
    float sc = 1.0f / (1.0f + p);
    gate_e[t2 * 2] = i1;
    gate_e[t2 * 2 + 1] = i2;
    gate_w[t2 * 2] = sc;
    gate_w[t2 * 2 + 1] = p * sc;
    if (o1 != i1 || o2 != i2) {
      atomicSub(&counts[o1], 1);
      atomicSub(&counts[o2], 1);
      atomicAdd(&counts[i1], 1);
      atomicAdd(&counts[i2], 1);
    }
  }
}

// ---------------- scatter: hierarchical; block 0 also writes pad slots ------
__global__ __launch_bounds__(256) void scatter_kernel(
    const int* __restrict__ gate_e, const float* __restrict__ gate_w,
    const int* __restrict__ counts, int* __restrict__ fill,
    int* __restrict__ slot_token, float* __restrict__ slot_w,
    int* __restrict__ slot_of) {
  __shared__ int lcnt[EE];
  __shared__ int lbase[EE];
  __shared__ int offs_s[EE];
  int tid = threadIdx.x;
  int t = blockIdx.x * 256 + tid;
  if (tid < EE) lcnt[tid] = 0;
  if (tid == 0) {
    int off = 0;
    for (int q = 0; q < EE; q++) {
      offs_s[q] = off;
      off += ((counts[q] + BM - 1) / BM) * BM;
    }
  }
  __syncthreads();
  if (blockIdx.x == 0) {
    // pad slots [offs+counts[e], offs+tiles*BM) get token -1 (disjoint from
    // the filled region; gemm1 clamps, gemm2 yw rows never combined)
#pragma unroll
    for (int q = 0; q < EE; q++) {
      int cnt = counts[q];
      int lim = ((cnt + BM - 1) / BM) * BM;
      for (int p = cnt + tid; p < lim; p += 256)
        slot_token[offs_s[q] + p] = -1;
    }
  }
  int e0 = gate_e[t * 2], e1 = gate_e[t * 2 + 1];
  int p0 = atomicAdd(&lcnt[e0], 1);
  int p1 = atomicAdd(&lcnt[e1], 1);
  __syncthreads();
  if (tid < EE) lbase[tid] = atomicAdd(&fill[tid], lcnt[tid]);
  __syncthreads();
  int s0 = offs_s[e0] + lbase[e0] + p0;
  int s1 = offs_s[e1] + lbase[e1] + p1;
  slot_token[s0] = t;
  slot_w[s0] = gate_w[t * 2];
  slot_of[t * 2] = s0;
  slot_token[s1] = t;
  slot_w[s1] = gate_w[t * 2 + 1];
  slot_of[t * 2 + 1] = s1;
}

// ---------------- GEMM1: 128x128, BK=32, depth-2 counted-vmcnt pipeline -----
// h = gelu(x[slot] @ W1[e] + b1[e]); grid (HH/128, MAXTILES)
__global__ __launch_bounds__(256) void gemm1_kernel(
    const unsigned short* __restrict__ xb, const unsigned short* __restrict__ w1t,
    const float* __restrict__ b1, const int* __restrict__ slot_token,
    const int* __restrict__ counts, unsigned short* __restrict__ hb) {
  int e, row0;
  if (!tile_decode(counts, blockIdx.y, &e, &row0)) return;
  int n0 = blockIdx.x * 128;
  __shared__ unsigned short As[3][128][32];  // 24 KB
  __shared__ unsigned short Bs[3][128][32];  // 24 KB
  int tid = threadIdx.x;
  int lane = tid & 63;
  int wave = tid >> 6;
  int wm = wave >> 1, wn = wave & 1;
  int ra = tid >> 2, c = tid & 3;
  int tok_a = slot_token[row0 + ra]; if (tok_a < 0) tok_a = 0;
  int tok_b = slot_token[row0 + ra + 64]; if (tok_b < 0) tok_b = 0;
  const unsigned short* wbase = w1t + ((size_t)e * HH * DD);
  const unsigned short* gA0 = xb + (size_t)tok_a * DD + c * 8;
  const unsigned short* gA1 = xb + (size_t)tok_b * DD + c * 8;
  const unsigned short* gB0 = wbase + (size_t)(n0 + ra) * DD + c * 8;
  const unsigned short* gB1 = wbase + (size_t)(n0 + ra + 64) * DD + c * 8;
  f32x4 acc[4][4];
#pragma unroll
  for (int m = 0; m < 4; m++)
#pragma unroll
    for (int n = 0; n < 4; n++) {
      f32x4 z = {0.f, 0.f, 0.f, 0.f};
      acc[m][n] = z;
    }
  const int NK = DD / 32;
#pragma unroll
  for (int p = 0; p < 2; p++) {   // stage tiles 0,1 into bufs 0,1
    int kj = p * 32;
    gload16(gA0 + kj, &As[p][ra][c * 8]);
    gload16(gA1 + kj, &As[p][ra + 64][c * 8]);
    gload16(gB0 + kj, &Bs[p][ra][c * 8]);
    gload16(gB1 + kj, &Bs[p][ra + 64][c * 8]);
  }
  for (int kk = 0; kk < NK; kk++) {
    int cur = kk % 3;
    if (kk + 2 < NK) {
      int k2 = (kk + 2) * 32;
      int nx = (kk + 2) % 3;
      gload16(gA0 + k2, &As[nx][ra][c * 8]);
      gload16(gA1 + k2, &As[nx][ra + 64][c * 8]);
      gload16(gB0 + k2, &Bs[nx][ra][c * 8]);
      gload16(gB1 + k2, &Bs[nx][ra + 64][c * 8]);
      asm volatile("s_waitcnt vmcnt(8)" ::: "memory");
    } else if (kk + 1 < NK) {
      asm volatile("s_waitcnt vmcnt(4)" ::: "memory");
    } else {
      asm volatile("s_waitcnt vmcnt(0)" ::: "memory");
    }
    __builtin_amdgcn_s_barrier();
    bf16x8 a[4], b[4];
#pragma unroll
    for (int m = 0; m < 4; m++)
      a[m] = *(const bf16x8*)(&As[cur][wm * 64 + m * 16 + (lane & 15)][(lane >> 4) * 8]);
#pragma unroll
    for (int n = 0; n < 4; n++)
      b[n] = *(const bf16x8*)(&Bs[cur][wn * 64 + n * 16 + (lane & 15)][(lane >> 4) * 8]);
#pragma unroll
    for (int m = 0; m < 4; m++)
#pragma unroll
      for (int n = 0; n < 4; n++)
        acc[m][n] = __builtin_amdgcn_mfma_f32_16x16x32_bf16(a[m], b[n], acc[m][n], 0, 0, 0);
    asm volatile("" ::: "memory");
    __builtin_amdgcn_s_barrier();
  }
  const float* b1e = b1 + (size_t)e * HH;
#pragma unroll
  for (int m = 0; m < 4; m++) {
#pragma unroll
    for (int r = 0; r < 4; r++) {
      int slot = row0 + wm * 64 + m * 16 + ((lane >> 4) << 2) + r;
      unsigned short* hrow = hb + (size_t)slot * HH;
#pragma unroll
      for (int n = 0; n < 4; n++) {
        int hc = n0 + wn * 64 + n * 16 + (lane & 15);
        float v = acc[m][n][r] + b1e[hc];
        hrow[hc] = f2bf(gelu_f(v));
      }
    }
  }
}

// ---------------- GEMM2: 128x128, BK=32, depth-2 counted-vmcnt pipeline -----
// yw[slot] = w*(h[slot] @ W2[e] + b2[e]); grid (DD/128, MAXTILES)
template <int USE_Y>
__global__ __launch_bounds__(256) void gemm2_kernel(
    const unsigned short* __restrict__ hb, const unsigned short* __restrict__ w2t,
    const float* __restrict__ b2, const int* __restrict__ slot_token,
    const float* __restrict__ slot_w, const int* __restrict__ counts,
    unsigned short* __restrict__ yw, float* __restrict__ out) {
  int e, row0;
  if (!tile_decode(counts, blockIdx.y, &e, &row0)) return;
  int n0 = blockIdx.x * 128;
  __shared__ unsigned short As[3][128][32];
  __shared__ unsigned short Bs[3][128][32];
  int tid = threadIdx.x;
  int lane = tid & 63;
  int wave = tid >> 6;
  int wm = wave >> 1, wn = wave & 1;
  int ra = tid >> 2, c = tid & 3;
  const unsigned short* wbase = w2t + ((size_t)e * DD * HH);
  const unsigned short* gA0 = hb + (size_t)(row0 + ra) * HH + c * 8;
  const unsigned short* gA1 = hb + (size_t)(row0 + ra + 64) * HH + c * 8;
  const unsigned short* gB0 = wbase + (size_t)(n0 + ra) * HH + c * 8;
  const unsigned short* gB1 = wbase + (size_t)(n0 + ra + 64) * HH + c * 8;
  f32x4 acc[4][4];
#pragma unroll
  for (int m = 0; m < 4; m++)
#pragma unroll
    for (int n = 0; n < 4; n++) {
      f32x4 z = {0.f, 0.f, 0.f, 0.f};
      acc[m][n] = z;
    }
  const int NK = HH / 32;
#pragma unroll
  for (int p = 0; p < 2; p++) {
    int kj = p * 32;
    gload16(gA0 + kj, &As[p][ra][c * 8]);
    gload16(gA1 + kj, &As[p][ra + 64][c * 8]);
    gload16(gB0 + kj, &Bs[p][ra][c * 8]);
    gload16(gB1 + kj, &Bs[p][ra + 64][c * 8]);
  }
  for (int kk = 0; kk < NK; kk++) {
    int cur = kk % 3;
    if (kk + 2 < NK) {
      int k2 = (kk + 2) * 32;
      int nx = (kk + 2) % 3;
      gload16(gA0 + k2, &As[nx][ra][c * 8]);
      gload16(gA1 + k2, &As[nx][ra + 64][c * 8]);
      gload16(gB0 + k2, &Bs[nx][ra][c * 8]);
      gload16(gB1 + k2, &Bs[nx][ra + 64][c * 8]);
      asm volatile("s_waitcnt vmcnt(8)" ::: "memory");
    } else if (kk + 1 < NK) {
      asm volatile("s_waitcnt vmcnt(4)" ::: "memory");
    } else {
      asm volatile("s_waitcnt vmcnt(0)" ::: "memory");
    }
    __builtin_amdgcn_s_barrier();
    bf16x8 a[4], b[4];
#pragma unroll
    for (int m = 0; m < 4; m++)
      a[m] = *(const bf16x8*)(&As[cur][wm * 64 + m * 16 + (lane & 15)][(lane >> 4) * 8]);
#pragma unroll
    for (int n = 0; n < 4; n++)
      b[n] = *(const bf16x8*)(&Bs[cur][wn * 64 + n * 16 + (lane & 15)][(lane >> 4) * 8]);
#pragma unroll
    for (int m = 0; m < 4; m++)
#pragma unroll
      for (int n = 0; n < 4; n++)
        acc[m][n] = __builtin_amdgcn_mfma_f32_16x16x32_bf16(a[m], b[n], acc[m][n], 0, 0, 0);
    asm volatile("" ::: "memory");
    __builtin_amdgcn_s_barrier();
  }
  const float* b2e = b2 + (size_t)e * DD;
#pragma unroll
  for (int m = 0; m < 4; m++) {
#pragma unroll
    for (int r = 0; r < 4; r++) {
      int slot = row0 + wm * 64 + m * 16 + ((lane >> 4) << 2) + r;
      if (USE_Y) {
        float w = slot_w[slot];
        unsigned short* yrow = yw + (size_t)slot * DD;
#pragma unroll
        for (int n = 0; n < 4; n++) {
          int dc = n0 + wn * 64 + n * 16 + (lane & 15);
          yrow[dc] = f2bf(w * (acc[m][n][r] + b2e[dc]));
        }
      } else {
        int tok = slot_token[slot];
        if (tok >= 0) {
          float w = slot_w[slot];
          float* orow = out + (size_t)tok * DD;
#pragma unroll
          for (int n = 0; n < 4; n++) {
            int dc = n0 + wn * 64 + n * 16 + (lane & 15);
            float v = acc[m][n][r] + b2e[dc];
            atomicAdd(&orow[dc], w * v);
          }
        }
      }
    }
  }
}

// ---------------- combine: out[t] = yw[s1] + yw[s2] ----------------
__global__ __launch_bounds__(256) void combine_kernel(
    const unsigned short* __restrict__ yw, const int* __restrict__ slot_of,
    float* __restrict__ out) {
  int gid = blockIdx.x * 256 + threadIdx.x;
  int t = gid >> 6;
  int d0 = (gid & 63) * 8;
  int s1 = slot_of[t * 2], s2 = slot_of[t * 2 + 1];
  const ushort4* p1 = (const ushort4*)(yw + (size_t)s1 * DD + d0);
  const ushort4* p2 = (const ushort4*)(yw + (size_t)s2 * DD + d0);
  ushort4 a0 = p1[0], a1 = p1[1];
  ushort4 b0 = p2[0], b1 = p2[1];
  float4 o0, o1;
  o0.x = bf2f(a0.x) + bf2f(b0.x);
  o0.y = bf2f(a0.y) + bf2f(b0.y);
  o0.z = bf2f(a0.z) + bf2f(b0.z);
  o0.w = bf2f(a0.w) + bf2f(b0.w);
  o1.x = bf2f(a1.x) + bf2f(b1.x);
  o1.y = bf2f(a1.y) + bf2f(b1.y);
  o1.z = bf2f(a1.z) + bf2f(b1.z);
  o1.w = bf2f(a1.w) + bf2f(b1.w);
  float* orow = out + (size_t)t * DD + d0;
  ((float4*)orow)[0] = o0;
  ((float4*)orow)[1] = o1;
}

extern "C" void kernel_launch(void* const* d_in, const int* in_sizes, int n_in,
                              void* d_out, int out_size, void* d_ws, size_t ws_size,
                              hipStream_t stream) {
  const float* x  = (const float*)d_in[0];
  const float* Wg = (const float*)d_in[1];
  const float* bg = (const float*)d_in[2];
  const float* W1 = (const float*)d_in[3];
  const float* b1 = (const float*)d_in[4];
  const float* W2 = (const float*)d_in[5];
  const float* b2 = (const float*)d_in[6];
  float* out = (float*)d_out;

  uint8_t* w = (uint8_t*)d_ws;
  size_t o = 0;
  unsigned short* xb  = (unsigned short*)(w + o); o += (size_t)TT * DD * 2;       // 8 MB
  unsigned short* w1t = (unsigned short*)(w + o); o += (size_t)EE * DD * HH * 2;  // 16 MB
  unsigned short* w2t = (unsigned short*)(w + o); o += (size_t)EE * DD * HH * 2;  // 16 MB
  unsigned short* hb  = (unsigned short*)(w + o); o += (size_t)NSLOT * HH * 2;    // 37.7 MB
  int*   slot_token = (int*)(w + o);   o += (size_t)NSLOT * 4;
  float* slot_w     = (float*)(w + o); o += (size_t)NSLOT * 4;
  int*   slot_of    = (int*)(w + o);   o += (size_t)TT * 2 * 4;
  int*   gate_e     = (int*)(w + o);   o += (size_t)TT * 2 * 4;
  float* gate_w     = (float*)(w + o); o += (size_t)TT * 2 * 4;
  int*   counts     = (int*)(w + o);   o += 64;   // counts[16]
  int*   nretry     = (int*)(w + o);   o += 64;
  int*   fill       = (int*)(w + o);   o += 64;   // one 192B memset covers all 3
  int*   retry      = (int*)(w + o);   o += RETRYCAP * 4;
  unsigned short* yw = (unsigned short*)(w + o);
  size_t need_y = o + (size_t)NSLOT * DD * 2;   // +18.9 MB
  int use_y = (ws_size >= need_y);

  hipMemsetAsync(counts, 0, 192, stream);  // counts + nretry + fill
  if (!use_y) {
    hipMemsetAsync(slot_token, 0xFF, (size_t)NSLOT * 4, stream);
    hipMemsetAsync(d_out, 0, (size_t)TT * DD * 4, stream);
  }

  transpose_cv_kernel<<<4096, 256, 0, stream>>>(W1, W2, w1t, w2t);
  gate_mfma_kernel<<<TT / 32, 128, 0, stream>>>(x, Wg, bg, xb, gate_e, gate_w,
                                                counts, nretry, retry);
  gatefix_kernel<<<RETRYCAP / 16, 256, 0, stream>>>(x, Wg, bg, nretry, retry,
                                                    gate_e, gate_w, counts);
  scatter_kernel<<<TT / 256, 256, 0, stream>>>(gate_e, gate_w, counts, fill,
                                               slot_token, slot_w, slot_of);
  {
    dim3 g(HH / 128, MAXTILES);
    gemm1_kernel<<<g, 256, 0, stream>>>(xb, w1t, b1, slot_token, counts, hb);
  }
  {
    dim3 g(DD / 128, MAXTILES);
    if (use_y)
      gemm2_kernel<1><<<g, 256, 0, stream>>>(hb, w2t, b2, slot_token, slot_w,
                                             counts, yw, out);
    else
      gemm2_kernel<0><<<g, 256, 0, stream>>>(hb, w2t, b2, slot_token, slot_w,
                                             counts, yw, out);
  }
  if (use_y) {
    combine_kernel<<<TT * (DD / 8) / 256, 256, 0, stream>>>(yw, slot_of, out);
  }
}

// Round 17
// 167.915 us; speedup vs baseline: 1.4065x; 1.0272x over previous
//
#include <hip/hip_runtime.h>
#include <hip/hip_bf16.h>
#include <math.h>

#define TT 8192
#define DD 512
#define HH 1024
#define EE 16
#define NSLOT 18432   // 144 * 128 max padded slots
#define MAXTILES 144
#define BM 128
#define RETRYCAP 1024

typedef __attribute__((ext_vector_type(8))) short bf16x8;
typedef __attribute__((ext_vector_type(8))) unsigned short u16x8;
typedef __attribute__((ext_vector_type(4))) float f32x4;

__device__ __forceinline__ unsigned short f2bf(float f) {
  union { float f; unsigned u; } v; v.f = f;
  unsigned r = v.u + 0x7fffu + ((v.u >> 16) & 1u);
  return (unsigned short)(r >> 16);
}

__device__ __forceinline__ float bf2f(unsigned short u) {
  union { unsigned u; float f; } v; v.u = ((unsigned)u) << 16;
  return v.f;
}

__device__ __forceinline__ void gload16(const void* g, void* l) {
  __builtin_amdgcn_global_load_lds(
      (const __attribute__((address_space(1))) unsigned int*)g,
      (__attribute__((address_space(3))) unsigned int*)l, 16, 0, 0);
}

// Abramowitz-Stegun 7.1.26 erf approx (|err| <= 1.5e-7)
__device__ __forceinline__ float gelu_f(float v) {
  float s = fabsf(v) * 0.70710678118654752f;
  float t = 1.0f / (1.0f + 0.3275911f * s);
  float poly = t * (0.254829592f +
              t * (-0.284496736f +
              t * (1.421413741f +
              t * (-1.453152027f +
              t * 1.061405429f))));
  float erfa = 1.0f - poly * __expf(-s * s);
  float erfv = (v >= 0.f) ? erfa : -erfa;
  return 0.5f * v * (1.0f + erfv);
}

// expert/row0 from counts: tile mt -> (expert, row0, valid)
__device__ __forceinline__ int tile_decode(const int* __restrict__ counts,
                                           int mt, int* e_out, int* row0_out) {
  int off = 0, rem = mt;
#pragma unroll
  for (int q = 0; q < EE; q++) {
    int tl = (counts[q] + BM - 1) / BM;
    if (rem < tl) { *e_out = q; *row0_out = off + rem * BM; return 1; }
    rem -= tl;
    off += tl * BM;
  }
  return 0;
}

// ---------------- prep: GATE blocks first (bid<128), then transposes --------
// Gate: 4 waves x 16 tokens, barrier-free register-fragment MFMA (R16 body).
// Transposes: bid-128 < 2048 -> W1; else W2. LDS union ~8.7 KB.
__global__ __launch_bounds__(256) void prep_kernel(
    const float* __restrict__ W1, const float* __restrict__ W2,
    unsigned short* __restrict__ w1t, unsigned short* __restrict__ w2t,
    const float* __restrict__ x, const float* __restrict__ Wg,
    const float* __restrict__ bg, unsigned short* __restrict__ xb,
    int* __restrict__ gate_e, float* __restrict__ gate_w,
    int* __restrict__ counts, int* __restrict__ nretry,
    int* __restrict__ retry) {
  __shared__ union { unsigned short t[64][68]; int cnt[EE]; } sm;
  int bid = blockIdx.x;
  int tid = threadIdx.x;
  if (bid < 128) {
    // ---- gate: 64 tokens/block ----
    int lane = tid & 63;
    int wave = tid >> 6;                  // 0..3
    int tok0 = bid * 64 + wave * 16;
    if (tid < EE) sm.cnt[tid] = 0;
    __syncthreads();
    int e = lane & 15;
    int kb = (lane >> 4) * 8;
    bf16x8 bfrag[16];
#pragma unroll
    for (int ks = 0; ks < 16; ks++) {
      int kbase = ks * 32 + kb;
#pragma unroll
      for (int j = 0; j < 8; j++)
        bfrag[ks][j] = (short)f2bf(Wg[(kbase + j) * EE + e]);
    }
    float bge = bg[e];
    f32x4 acc = {0.f, 0.f, 0.f, 0.f};
    const float* xrow = x + (size_t)(tok0 + (lane & 15)) * DD + kb;
    unsigned short* xbrow = xb + (size_t)(tok0 + (lane & 15)) * DD + kb;
#pragma unroll 4
    for (int ks = 0; ks < 16; ks++) {
      int k0 = ks * 32;
      float4 v0 = *(const float4*)(xrow + k0);
      float4 v1 = *(const float4*)(xrow + k0 + 4);
      u16x8 w0;
      w0[0] = f2bf(v0.x); w0[1] = f2bf(v0.y); w0[2] = f2bf(v0.z); w0[3] = f2bf(v0.w);
      w0[4] = f2bf(v1.x); w0[5] = f2bf(v1.y); w0[6] = f2bf(v1.z); w0[7] = f2bf(v1.w);
      *(u16x8*)(xbrow + k0) = w0;
      union { u16x8 u; bf16x8 b; } cv; cv.u = w0;
      acc = __builtin_amdgcn_mfma_f32_16x16x32_bf16(cv.b, bfrag[ks], acc, 0, 0, 0);
    }
#pragma unroll
    for (int r = 0; r < 4; r++) {
      float lf = acc[r] + bge;
      float v1 = -1e30f, v2 = -1e30f, v3 = -1e30f;
      int i1 = 0, i2 = 0;
#pragma unroll
      for (int q = 0; q < EE; q++) {
        float v = __shfl(lf, (lane & 48) | q);
        if (v > v1) { v3 = v2; v2 = v1; i2 = i1; v1 = v; i1 = q; }
        else if (v > v2) { v3 = v2; v2 = v; i2 = q; }
        else if (v > v3) { v3 = v; }
      }
      if ((lane & 15) == 0) {
        int t2 = tok0 + ((lane >> 4) << 2) + r;
        float p = expf(v2 - v1);
        float s = 1.0f / (1.0f + p);
        gate_e[t2 * 2] = i1;
        gate_e[t2 * 2 + 1] = i2;
        gate_w[t2 * 2] = s;
        gate_w[t2 * 2 + 1] = p * s;
        atomicAdd(&sm.cnt[i1], 1);
        atomicAdd(&sm.cnt[i2], 1);
        if (v2 - v3 < 0.02f) {
          int pos = atomicAdd(nretry, 1);
          if (pos < RETRYCAP) retry[pos] = t2;
        }
      }
    }
    __syncthreads();
    if (tid < EE) atomicAdd(&counts[tid], sm.cnt[tid]);
    return;
  }
  // ---- transposes ----
  const float* src;
  unsigned short* dst;
  int R, C, c0, r0;
  int b = bid - 128;
  if (b < 2048) {
    int cx = b & 15, ry = (b >> 4) & 7, mat = b >> 7;
    src = W1 + (size_t)mat * DD * HH; dst = w1t + (size_t)mat * DD * HH;
    R = DD; C = HH; c0 = cx * 64; r0 = ry * 64;
  } else {
    b -= 2048;
    int cx = b & 7, ry = (b >> 3) & 15, mat = b >> 7;
    src = W2 + (size_t)mat * DD * HH; dst = w2t + (size_t)mat * DD * HH;
    R = HH; C = DD; c0 = cx * 64; r0 = ry * 64;
  }
#pragma unroll
  for (int p = 0; p < 4; p++) {
    int r = tid >> 2;
    int c4 = (tid & 3) + p * 4;
    float4 v = *(const float4*)(src + (size_t)(r0 + r) * C + c0 + c4 * 4);
    sm.t[c4 * 4 + 0][r] = f2bf(v.x);
    sm.t[c4 * 4 + 1][r] = f2bf(v.y);
    sm.t[c4 * 4 + 2][r] = f2bf(v.z);
    sm.t[c4 * 4 + 3][r] = f2bf(v.w);
  }
  __syncthreads();
#pragma unroll
  for (int p = 0; p < 4; p++) {
    int oc = (tid >> 4) + p * 16;
    int ch = tid & 15;
    ushort4 v = *(ushort4*)(&sm.t[oc][ch * 4]);
    *(ushort4*)(dst + (size_t)(c0 + oc) * R + r0 + ch * 4) = v;
  }
}

// ---------------- gatefix: exact f64 recompute for near-tie tokens ----------
__global__ __launch_bounds__(256) void gatefix_kernel(
    const float* __restrict__ x, const float* __restrict__ Wg,
    const float* __restrict__ bg, const int* __restrict__ nretry,
    const int* __restrict__ retry, int* __restrict__ gate_e,
    float* __restrict__ gate_w, int* __restrict__ counts) {
  __shared__ float lg[16][17];
  __shared__ int toks[16];
  int tid = threadIdx.x;
  int sl = tid >> 4, e = tid & 15;
  int s = blockIdx.x * 16 + sl;
  int n = *nretry; if (n > RETRYCAP) n = RETRYCAP;
  int active = (s < n);
  int tok = 0;
  if (active) tok = retry[s];
  if (active) {
    const float* xr = x + (size_t)tok * DD;
    double a0 = 0.0, a1 = 0.0, a2 = 0.0, a3 = 0.0;
    for (int i = 0; i < DD / 4; i++) {
      a0 += (double)xr[i * 4 + 0] * (double)Wg[(i * 4 + 0) * EE + e];
      a1 += (double)xr[i * 4 + 1] * (double)Wg[(i * 4 + 1) * EE + e];
      a2 += (double)xr[i * 4 + 2] * (double)Wg[(i * 4 + 2) * EE + e];
      a3 += (double)xr[i * 4 + 3] * (double)Wg[(i * 4 + 3) * EE + e];
    }
    double acc = (a0 + a1) + (a2 + a3);
    lg[sl][e] = (float)(acc + (double)bg[e]);
    toks[sl] = tok;
  }
  __syncthreads();
  if (active && e == 0) {
    float v1 = -1e30f, v2 = -1e30f;
    int i1 = 0, i2 = 0;
#pragma unroll
    for (int q = 0; q < EE; q++) {
      float v = lg[sl][q];
      if (v > v1) { v2 = v1; i2 = i1; v1 = v; i1 = q; }
      else if (v > v2) { v2 = v; i2 = q; }
    }
    int t2 = toks[sl];
    int o1 = gate_e[t2 * 2], o2 = gate_e[t2 * 2 + 1];
    float p = expf(v2 - v1);
    float sc = 1.0f / (1.0f + p);
    gate_e[t2 * 2] = i1;
    gate_e[t2 * 2 + 1] = i2;
    gate_w[t2 * 2] = sc;
    gate_w[t2 * 2 + 1] = p * sc;
    if (o1 != i1 || o2 != i2) {
      atomicSub(&counts[o1], 1);
      atomicSub(&counts[o2], 1);
      atomicAdd(&counts[i1], 1);
      atomicAdd(&counts[i2], 1);
    }
  }
}

// ---------------- scatter: hierarchical; block 0 also writes pad slots ------
__global__ __launch_bounds__(256) void scatter_kernel(
    const int* __restrict__ gate_e, const float* __restrict__ gate_w,
    const int* __restrict__ counts, int* __restrict__ fill,
    int* __restrict__ slot_token, float* __restrict__ slot_w,
    int* __restrict__ slot_of) {
  __shared__ int lcnt[EE];
  __shared__ int lbase[EE];
  __shared__ int offs_s[EE];
  int tid = threadIdx.x;
  int t = blockIdx.x * 256 + tid;
  if (tid < EE) lcnt[tid] = 0;
  if (tid == 0) {
    int off = 0;
    for (int q = 0; q < EE; q++) {
      offs_s[q] = off;
      off += ((counts[q] + BM - 1) / BM) * BM;
    }
  }
  __syncthreads();
  if (blockIdx.x == 0) {
#pragma unroll
    for (int q = 0; q < EE; q++) {
      int cnt = counts[q];
      int lim = ((cnt + BM - 1) / BM) * BM;
      for (int p = cnt + tid; p < lim; p += 256)
        slot_token[offs_s[q] + p] = -1;
    }
  }
  int e0 = gate_e[t * 2], e1 = gate_e[t * 2 + 1];
  int p0 = atomicAdd(&lcnt[e0], 1);
  int p1 = atomicAdd(&lcnt[e1], 1);
  __syncthreads();
  if (tid < EE) lbase[tid] = atomicAdd(&fill[tid], lcnt[tid]);
  __syncthreads();
  int s0 = offs_s[e0] + lbase[e0] + p0;
  int s1 = offs_s[e1] + lbase[e1] + p1;
  slot_token[s0] = t;
  slot_w[s0] = gate_w[t * 2];
  slot_of[t * 2] = s0;
  slot_token[s1] = t;
  slot_w[s1] = gate_w[t * 2 + 1];
  slot_of[t * 2 + 1] = s1;
}

// ---------------- GEMM1: 128x128, BK=32, depth-2 counted-vmcnt pipeline -----
__global__ __launch_bounds__(256) void gemm1_kernel(
    const unsigned short* __restrict__ xb, const unsigned short* __restrict__ w1t,
    const float* __restrict__ b1, const int* __restrict__ slot_token,
    const int* __restrict__ counts, unsigned short* __restrict__ hb) {
  int e, row0;
  if (!tile_decode(counts, blockIdx.y, &e, &row0)) return;
  int n0 = blockIdx.x * 128;
  __shared__ unsigned short As[3][128][32];  // 24 KB
  __shared__ unsigned short Bs[3][128][32];  // 24 KB
  int tid = threadIdx.x;
  int lane = tid & 63;
  int wave = tid >> 6;
  int wm = wave >> 1, wn = wave & 1;
  int ra = tid >> 2, c = tid & 3;
  int tok_a = slot_token[row0 + ra]; if (tok_a < 0) tok_a = 0;
  int tok_b = slot_token[row0 + ra + 64]; if (tok_b < 0) tok_b = 0;
  const unsigned short* wbase = w1t + ((size_t)e * HH * DD);
  const unsigned short* gA0 = xb + (size_t)tok_a * DD + c * 8;
  const unsigned short* gA1 = xb + (size_t)tok_b * DD + c * 8;
  const unsigned short* gB0 = wbase + (size_t)(n0 + ra) * DD + c * 8;
  const unsigned short* gB1 = wbase + (size_t)(n0 + ra + 64) * DD + c * 8;
  f32x4 acc[4][4];
#pragma unroll
  for (int m = 0; m < 4; m++)
#pragma unroll
    for (int n = 0; n < 4; n++) {
      f32x4 z = {0.f, 0.f, 0.f, 0.f};
      acc[m][n] = z;
    }
  const int NK = DD / 32;
#pragma unroll
  for (int p = 0; p < 2; p++) {
    int kj = p * 32;
    gload16(gA0 + kj, &As[p][ra][c * 8]);
    gload16(gA1 + kj, &As[p][ra + 64][c * 8]);
    gload16(gB0 + kj, &Bs[p][ra][c * 8]);
    gload16(gB1 + kj, &Bs[p][ra + 64][c * 8]);
  }
  for (int kk = 0; kk < NK; kk++) {
    int cur = kk % 3;
    if (kk + 2 < NK) {
      int k2 = (kk + 2) * 32;
      int nx = (kk + 2) % 3;
      gload16(gA0 + k2, &As[nx][ra][c * 8]);
      gload16(gA1 + k2, &As[nx][ra + 64][c * 8]);
      gload16(gB0 + k2, &Bs[nx][ra][c * 8]);
      gload16(gB1 + k2, &Bs[nx][ra + 64][c * 8]);
      asm volatile("s_waitcnt vmcnt(8)" ::: "memory");
    } else if (kk + 1 < NK) {
      asm volatile("s_waitcnt vmcnt(4)" ::: "memory");
    } else {
      asm volatile("s_waitcnt vmcnt(0)" ::: "memory");
    }
    __builtin_amdgcn_s_barrier();
    bf16x8 a[4], b[4];
#pragma unroll
    for (int m = 0; m < 4; m++)
      a[m] = *(const bf16x8*)(&As[cur][wm * 64 + m * 16 + (lane & 15)][(lane >> 4) * 8]);
#pragma unroll
    for (int n = 0; n < 4; n++)
      b[n] = *(const bf16x8*)(&Bs[cur][wn * 64 + n * 16 + (lane & 15)][(lane >> 4) * 8]);
#pragma unroll
    for (int m = 0; m < 4; m++)
#pragma unroll
      for (int n = 0; n < 4; n++)
        acc[m][n] = __builtin_amdgcn_mfma_f32_16x16x32_bf16(a[m], b[n], acc[m][n], 0, 0, 0);
    asm volatile("" ::: "memory");
    __builtin_amdgcn_s_barrier();
  }
  const float* b1e = b1 + (size_t)e * HH;
#pragma unroll
  for (int m = 0; m < 4; m++) {
#pragma unroll
    for (int r = 0; r < 4; r++) {
      int slot = row0 + wm * 64 + m * 16 + ((lane >> 4) << 2) + r;
      unsigned short* hrow = hb + (size_t)slot * HH;
#pragma unroll
      for (int n = 0; n < 4; n++) {
        int hc = n0 + wn * 64 + n * 16 + (lane & 15);
        float v = acc[m][n][r] + b1e[hc];
        hrow[hc] = f2bf(gelu_f(v));
      }
    }
  }
}

// ---------------- GEMM2: 128x128, BK=32, depth-2 counted-vmcnt pipeline -----
template <int USE_Y>
__global__ __launch_bounds__(256) void gemm2_kernel(
    const unsigned short* __restrict__ hb, const unsigned short* __restrict__ w2t,
    const float* __restrict__ b2, const int* __restrict__ slot_token,
    const float* __restrict__ slot_w, const int* __restrict__ counts,
    unsigned short* __restrict__ yw, float* __restrict__ out) {
  int e, row0;
  if (!tile_decode(counts, blockIdx.y, &e, &row0)) return;
  int n0 = blockIdx.x * 128;
  __shared__ unsigned short As[3][128][32];
  __shared__ unsigned short Bs[3][128][32];
  int tid = threadIdx.x;
  int lane = tid & 63;
  int wave = tid >> 6;
  int wm = wave >> 1, wn = wave & 1;
  int ra = tid >> 2, c = tid & 3;
  const unsigned short* wbase = w2t + ((size_t)e * DD * HH);
  const unsigned short* gA0 = hb + (size_t)(row0 + ra) * HH + c * 8;
  const unsigned short* gA1 = hb + (size_t)(row0 + ra + 64) * HH + c * 8;
  const unsigned short* gB0 = wbase + (size_t)(n0 + ra) * HH + c * 8;
  const unsigned short* gB1 = wbase + (size_t)(n0 + ra + 64) * HH + c * 8;
  f32x4 acc[4][4];
#pragma unroll
  for (int m = 0; m < 4; m++)
#pragma unroll
    for (int n = 0; n < 4; n++) {
      f32x4 z = {0.f, 0.f, 0.f, 0.f};
      acc[m][n] = z;
    }
  const int NK = HH / 32;
#pragma unroll
  for (int p = 0; p < 2; p++) {
    int kj = p * 32;
    gload16(gA0 + kj, &As[p][ra][c * 8]);
    gload16(gA1 + kj, &As[p][ra + 64][c * 8]);
    gload16(gB0 + kj, &Bs[p][ra][c * 8]);
    gload16(gB1 + kj, &Bs[p][ra + 64][c * 8]);
  }
  for (int kk = 0; kk < NK; kk++) {
    int cur = kk % 3;
    if (kk + 2 < NK) {
      int k2 = (kk + 2) * 32;
      int nx = (kk + 2) % 3;
      gload16(gA0 + k2, &As[nx][ra][c * 8]);
      gload16(gA1 + k2, &As[nx][ra + 64][c * 8]);
      gload16(gB0 + k2, &Bs[nx][ra][c * 8]);
      gload16(gB1 + k2, &Bs[nx][ra + 64][c * 8]);
      asm volatile("s_waitcnt vmcnt(8)" ::: "memory");
    } else if (kk + 1 < NK) {
      asm volatile("s_waitcnt vmcnt(4)" ::: "memory");
    } else {
      asm volatile("s_waitcnt vmcnt(0)" ::: "memory");
    }
    __builtin_amdgcn_s_barrier();
    bf16x8 a[4], b[4];
#pragma unroll
    for (int m = 0; m < 4; m++)
      a[m] = *(const bf16x8*)(&As[cur][wm * 64 + m * 16 + (lane & 15)][(lane >> 4) * 8]);
#pragma unroll
    for (int n = 0; n < 4; n++)
      b[n] = *(const bf16x8*)(&Bs[cur][wn * 64 + n * 16 + (lane & 15)][(lane >> 4) * 8]);
#pragma unroll
    for (int m = 0; m < 4; m++)
#pragma unroll
      for (int n = 0; n < 4; n++)
        acc[m][n] = __builtin_amdgcn_mfma_f32_16x16x32_bf16(a[m], b[n], acc[m][n], 0, 0, 0);
    asm volatile("" ::: "memory");
    __builtin_amdgcn_s_barrier();
  }
  const float* b2e = b2 + (size_t)e * DD;
#pragma unroll
  for (int m = 0; m < 4; m++) {
#pragma unroll
    for (int r = 0; r < 4; r++) {
      int slot = row0 + wm * 64 + m * 16 + ((lane >> 4) << 2) + r;
      if (USE_Y) {
        float w = slot_w[slot];
        unsigned short* yrow = yw + (size_t)slot * DD;
#pragma unroll
        for (int n = 0; n < 4; n++) {
          int dc = n0 + wn * 64 + n * 16 + (lane & 15);
          yrow[dc] = f2bf(w * (acc[m][n][r] + b2e[dc]));
        }
      } else {
        int tok = slot_token[slot];
        if (tok >= 0) {
          float w = slot_w[slot];
          float* orow = out + (size_t)tok * DD;
#pragma unroll
          for (int n = 0; n < 4; n++) {
            int dc = n0 + wn * 64 + n * 16 + (lane & 15);
            float v = acc[m][n][r] + b2e[dc];
            atomicAdd(&orow[dc], w * v);
          }
        }
      }
    }
  }
}

// ---------------- combine: out[t] = yw[s1] + yw[s2] ----------------
__global__ __launch_bounds__(256) void combine_kernel(
    const unsigned short* __restrict__ yw, const int* __restrict__ slot_of,
    float* __restrict__ out) {
  int gid = blockIdx.x * 256 + threadIdx.x;
  int t = gid >> 6;
  int d0 = (gid & 63) * 8;
  int s1 = slot_of[t * 2], s2 = slot_of[t * 2 + 1];
  const ushort4* p1 = (const ushort4*)(yw + (size_t)s1 * DD + d0);
  const ushort4* p2 = (const ushort4*)(yw + (size_t)s2 * DD + d0);
  ushort4 a0 = p1[0], a1 = p1[1];
  ushort4 b0 = p2[0], b1 = p2[1];
  float4 o0, o1;
  o0.x = bf2f(a0.x) + bf2f(b0.x);
  o0.y = bf2f(a0.y) + bf2f(b0.y);
  o0.z = bf2f(a0.z) + bf2f(b0.z);
  o0.w = bf2f(a0.w) + bf2f(b0.w);
  o1.x = bf2f(a1.x) + bf2f(b1.x);
  o1.y = bf2f(a1.y) + bf2f(b1.y);
  o1.z = bf2f(a1.z) + bf2f(b1.z);
  o1.w = bf2f(a1.w) + bf2f(b1.w);
  float* orow = out + (size_t)t * DD + d0;
  ((float4*)orow)[0] = o0;
  ((float4*)orow)[1] = o1;
}

extern "C" void kernel_launch(void* const* d_in, const int* in_sizes, int n_in,
                              void* d_out, int out_size, void* d_ws, size_t ws_size,
                              hipStream_t stream) {
  const float* x  = (const float*)d_in[0];
  const float* Wg = (const float*)d_in[1];
  const float* bg = (const float*)d_in[2];
  const float* W1 = (const float*)d_in[3];
  const float* b1 = (const float*)d_in[4];
  const float* W2 = (const float*)d_in[5];
  const float* b2 = (const float*)d_in[6];
  float* out = (float*)d_out;

  uint8_t* w = (uint8_t*)d_ws;
  size_t o = 0;
  unsigned short* xb  = (unsigned short*)(w + o); o += (size_t)TT * DD * 2;       // 8 MB
  unsigned short* w1t = (unsigned short*)(w + o); o += (size_t)EE * DD * HH * 2;  // 16 MB
  unsigned short* w2t = (unsigned short*)(w + o); o += (size_t)EE * DD * HH * 2;  // 16 MB
  unsigned short* hb  = (unsigned short*)(w + o); o += (size_t)NSLOT * HH * 2;    // 37.7 MB
  int*   slot_token = (int*)(w + o);   o += (size_t)NSLOT * 4;
  float* slot_w     = (float*)(w + o); o += (size_t)NSLOT * 4;
  int*   slot_of    = (int*)(w + o);   o += (size_t)TT * 2 * 4;
  int*   gate_e     = (int*)(w + o);   o += (size_t)TT * 2 * 4;
  float* gate_w     = (float*)(w + o); o += (size_t)TT * 2 * 4;
  int*   counts     = (int*)(w + o);   o += 64;   // counts[16]
  int*   nretry     = (int*)(w + o);   o += 64;
  int*   fill       = (int*)(w + o);   o += 64;   // one 192B memset covers all 3
  int*   retry      = (int*)(w + o);   o += RETRYCAP * 4;
  unsigned short* yw = (unsigned short*)(w + o);
  size_t need_y = o + (size_t)NSLOT * DD * 2;   // +18.9 MB
  int use_y = (ws_size >= need_y);

  hipMemsetAsync(counts, 0, 192, stream);  // counts + nretry + fill
  if (!use_y) {
    hipMemsetAsync(slot_token, 0xFF, (size_t)NSLOT * 4, stream);
    hipMemsetAsync(d_out, 0, (size_t)TT * DD * 4, stream);
  }

  // gate (blocks 0..127, dispatched first) + W1/W2 transposes (128..4223)
  prep_kernel<<<128 + 4096, 256, 0, stream>>>(
      W1, W2, w1t, w2t, x, Wg, bg, xb, gate_e, gate_w, counts, nretry, retry);
  gatefix_kernel<<<RETRYCAP / 16, 256, 0, stream>>>(x, Wg, bg, nretry, retry,
                                                    gate_e, gate_w, counts);
  scatter_kernel<<<TT / 256, 256, 0, stream>>>(gate_e, gate_w, counts, fill,
                                               slot_token, slot_w, slot_of);
  {
    dim3 g(HH / 128, MAXTILES);
    gemm1_kernel<<<g, 256, 0, stream>>>(xb, w1t, b1, slot_token, counts, hb);
  }
  {
    dim3 g(DD / 128, MAXTILES);
    if (use_y)
      gemm2_kernel<1><<<g, 256, 0, stream>>>(hb, w2t, b2, slot_token, slot_w,
                                             counts, yw, out);
    else
      gemm2_kernel<0><<<g, 256, 0, stream>>>(hb, w2t, b2, slot_token, slot_w,
                                             counts, yw, out);
  }
  if (use_y) {
    combine_kernel<<<TT * (DD / 8) / 256, 256, 0, stream>>>(yw, slot_of, out);
  }
}

// Round 19
// 160.781 us; speedup vs baseline: 1.4689x; 1.0444x over previous
//
#include <hip/hip_runtime.h>
#include <hip/hip_bf16.h>
#include <math.h>

#define TT 8192
#define DD 512
#define HH 1024
#define EE 16
#define NSLOT 18432   // 144 * 128 max padded slots
#define MAXTILES 144
#define BM 128
#define RETRYCAP 1024

typedef __attribute__((ext_vector_type(8))) short bf16x8;
typedef __attribute__((ext_vector_type(8))) unsigned short u16x8;
typedef __attribute__((ext_vector_type(4))) float f32x4;

__device__ __forceinline__ unsigned short f2bf(float f) {
  union { float f; unsigned u; } v; v.f = f;
  unsigned r = v.u + 0x7fffu + ((v.u >> 16) & 1u);
  return (unsigned short)(r >> 16);
}

__device__ __forceinline__ float bf2f(unsigned short u) {
  union { unsigned u; float f; } v; v.u = ((unsigned)u) << 16;
  return v.f;
}

__device__ __forceinline__ void gload16(const void* g, void* l) {
  __builtin_amdgcn_global_load_lds(
      (const __attribute__((address_space(1))) unsigned int*)g,
      (__attribute__((address_space(3))) unsigned int*)l, 16, 0, 0);
}

// Abramowitz-Stegun 7.1.26 erf approx (|err| <= 1.5e-7)
__device__ __forceinline__ float gelu_f(float v) {
  float s = fabsf(v) * 0.70710678118654752f;
  float t = 1.0f / (1.0f + 0.3275911f * s);
  float poly = t * (0.254829592f +
              t * (-0.284496736f +
              t * (1.421413741f +
              t * (-1.453152027f +
              t * 1.061405429f))));
  float erfa = 1.0f - poly * __expf(-s * s);
  float erfv = (v >= 0.f) ? erfa : -erfa;
  return 0.5f * v * (1.0f + erfv);
}

// expert/row0 from counts: tile mt -> (expert, row0, valid)
__device__ __forceinline__ int tile_decode(const int* __restrict__ counts,
                                           int mt, int* e_out, int* row0_out) {
  int off = 0, rem = mt;
#pragma unroll
  for (int q = 0; q < EE; q++) {
    int tl = (counts[q] + BM - 1) / BM;
    if (rem < tl) { *e_out = q; *row0_out = off + rem * BM; return 1; }
    rem -= tl;
    off += tl * BM;
  }
  return 0;
}

// ---------------- prep: GATE blocks first (bid<128), then transposes --------
__global__ __launch_bounds__(256) void prep_kernel(
    const float* __restrict__ W1, const float* __restrict__ W2,
    unsigned short* __restrict__ w1t, unsigned short* __restrict__ w2t,
    const float* __restrict__ x, const float* __restrict__ Wg,
    const float* __restrict__ bg, unsigned short* __restrict__ xb,
    int* __restrict__ gate_e, float* __restrict__ gate_w,
    int* __restrict__ counts, int* __restrict__ nretry,
    int* __restrict__ retry) {
  __shared__ union { unsigned short t[64][68]; int cnt[EE]; } sm;
  int bid = blockIdx.x;
  int tid = threadIdx.x;
  if (bid < 128) {
    // ---- gate: 64 tokens/block, barrier-free register fragments ----
    int lane = tid & 63;
    int wave = tid >> 6;
    int tok0 = bid * 64 + wave * 16;
    if (tid < EE) sm.cnt[tid] = 0;
    __syncthreads();
    int e = lane & 15;
    int kb = (lane >> 4) * 8;
    bf16x8 bfrag[16];
#pragma unroll
    for (int ks = 0; ks < 16; ks++) {
      int kbase = ks * 32 + kb;
#pragma unroll
      for (int j = 0; j < 8; j++)
        bfrag[ks][j] = (short)f2bf(Wg[(kbase + j) * EE + e]);
    }
    float bge = bg[e];
    f32x4 acc = {0.f, 0.f, 0.f, 0.f};
    const float* xrow = x + (size_t)(tok0 + (lane & 15)) * DD + kb;
    unsigned short* xbrow = xb + (size_t)(tok0 + (lane & 15)) * DD + kb;
#pragma unroll 4
    for (int ks = 0; ks < 16; ks++) {
      int k0 = ks * 32;
      float4 v0 = *(const float4*)(xrow + k0);
      float4 v1 = *(const float4*)(xrow + k0 + 4);
      u16x8 w0;
      w0[0] = f2bf(v0.x); w0[1] = f2bf(v0.y); w0[2] = f2bf(v0.z); w0[3] = f2bf(v0.w);
      w0[4] = f2bf(v1.x); w0[5] = f2bf(v1.y); w0[6] = f2bf(v1.z); w0[7] = f2bf(v1.w);
      *(u16x8*)(xbrow + k0) = w0;
      union { u16x8 u; bf16x8 b; } cv; cv.u = w0;
      acc = __builtin_amdgcn_mfma_f32_16x16x32_bf16(cv.b, bfrag[ks], acc, 0, 0, 0);
    }
#pragma unroll
    for (int r = 0; r < 4; r++) {
      float lf = acc[r] + bge;
      float v1 = -1e30f, v2 = -1e30f, v3 = -1e30f;
      int i1 = 0, i2 = 0;
#pragma unroll
      for (int q = 0; q < EE; q++) {
        float v = __shfl(lf, (lane & 48) | q);
        if (v > v1) { v3 = v2; v2 = v1; i2 = i1; v1 = v; i1 = q; }
        else if (v > v2) { v3 = v2; v2 = v; i2 = q; }
        else if (v > v3) { v3 = v; }
      }
      if ((lane & 15) == 0) {
        int t2 = tok0 + ((lane >> 4) << 2) + r;
        float p = expf(v2 - v1);
        float s = 1.0f / (1.0f + p);
        gate_e[t2 * 2] = i1;
        gate_e[t2 * 2 + 1] = i2;
        gate_w[t2 * 2] = s;
        gate_w[t2 * 2 + 1] = p * s;
        atomicAdd(&sm.cnt[i1], 1);
        atomicAdd(&sm.cnt[i2], 1);
        if (v2 - v3 < 0.02f) {
          int pos = atomicAdd(nretry, 1);
          if (pos < RETRYCAP) retry[pos] = t2;
        }
      }
    }
    __syncthreads();
    if (tid < EE) atomicAdd(&counts[tid], sm.cnt[tid]);
    return;
  }
  // ---- transposes ----
  const float* src;
  unsigned short* dst;
  int R, C, c0, r0;
  int b = bid - 128;
  if (b < 2048) {
    int cx = b & 15, ry = (b >> 4) & 7, mat = b >> 7;
    src = W1 + (size_t)mat * DD * HH; dst = w1t + (size_t)mat * DD * HH;
    R = DD; C = HH; c0 = cx * 64; r0 = ry * 64;
  } else {
    b -= 2048;
    int cx = b & 7, ry = (b >> 3) & 15, mat = b >> 7;
    src = W2 + (size_t)mat * DD * HH; dst = w2t + (size_t)mat * DD * HH;
    R = HH; C = DD; c0 = cx * 64; r0 = ry * 64;
  }
#pragma unroll
  for (int p = 0; p < 4; p++) {
    int r = tid >> 2;
    int c4 = (tid & 3) + p * 4;
    float4 v = *(const float4*)(src + (size_t)(r0 + r) * C + c0 + c4 * 4);
    sm.t[c4 * 4 + 0][r] = f2bf(v.x);
    sm.t[c4 * 4 + 1][r] = f2bf(v.y);
    sm.t[c4 * 4 + 2][r] = f2bf(v.z);
    sm.t[c4 * 4 + 3][r] = f2bf(v.w);
  }
  __syncthreads();
#pragma unroll
  for (int p = 0; p < 4; p++) {
    int oc = (tid >> 4) + p * 16;
    int ch = tid & 15;
    ushort4 v = *(ushort4*)(&sm.t[oc][ch * 4]);
    *(ushort4*)(dst + (size_t)(c0 + oc) * R + r0 + ch * 4) = v;
  }
}

// ---------------- gatefix: exact f64 recompute for near-tie tokens ----------
__global__ __launch_bounds__(256) void gatefix_kernel(
    const float* __restrict__ x, const float* __restrict__ Wg,
    const float* __restrict__ bg, const int* __restrict__ nretry,
    const int* __restrict__ retry, int* __restrict__ gate_e,
    float* __restrict__ gate_w, int* __restrict__ counts) {
  __shared__ float lg[16][17];
  __shared__ int toks[16];
  int tid = threadIdx.x;
  int sl = tid >> 4, e = tid & 15;
  int s = blockIdx.x * 16 + sl;
  int n = *nretry; if (n > RETRYCAP) n = RETRYCAP;
  int active = (s < n);
  int tok = 0;
  if (active) tok = retry[s];
  if (active) {
    const float* xr = x + (size_t)tok * DD;
    double a0 = 0.0, a1 = 0.0, a2 = 0.0, a3 = 0.0;
    for (int i = 0; i < DD / 4; i++) {
      a0 += (double)xr[i * 4 + 0] * (double)Wg[(i * 4 + 0) * EE + e];
      a1 += (double)xr[i * 4 + 1] * (double)Wg[(i * 4 + 1) * EE + e];
      a2 += (double)xr[i * 4 + 2] * (double)Wg[(i * 4 + 2) * EE + e];
      a3 += (double)xr[i * 4 + 3] * (double)Wg[(i * 4 + 3) * EE + e];
    }
    double acc = (a0 + a1) + (a2 + a3);
    lg[sl][e] = (float)(acc + (double)bg[e]);
    toks[sl] = tok;
  }
  __syncthreads();
  if (active && e == 0) {
    float v1 = -1e30f, v2 = -1e30f;
    int i1 = 0, i2 = 0;
#pragma unroll
    for (int q = 0; q < EE; q++) {
      float v = lg[sl][q];
      if (v > v1) { v2 = v1; i2 = i1; v1 = v; i1 = q; }
      else if (v > v2) { v2 = v; i2 = q; }
    }
    int t2 = toks[sl];
    int o1 = gate_e[t2 * 2], o2 = gate_e[t2 * 2 + 1];
    float p = expf(v2 - v1);
    float sc = 1.0f / (1.0f + p);
    gate_e[t2 * 2] = i1;
    gate_e[t2 * 2 + 1] = i2;
    gate_w[t2 * 2] = sc;
    gate_w[t2 * 2 + 1] = p * sc;
    if (o1 != i1 || o2 != i2) {
      atomicSub(&counts[o1], 1);
      atomicSub(&counts[o2], 1);
      atomicAdd(&counts[i1], 1);
      atomicAdd(&counts[i2], 1);
    }
  }
}

// ---------------- scatter: hierarchical; block 0 also writes pad slots ------
__global__ __launch_bounds__(256) void scatter_kernel(
    const int* __restrict__ gate_e, const float* __restrict__ gate_w,
    const int* __restrict__ counts, int* __restrict__ fill,
    int* __restrict__ slot_token, float* __restrict__ slot_w,
    int* __restrict__ slot_of) {
  __shared__ int lcnt[EE];
  __shared__ int lbase[EE];
  __shared__ int offs_s[EE];
  int tid = threadIdx.x;
  int t = blockIdx.x * 256 + tid;
  if (tid < EE) lcnt[tid] = 0;
  if (tid == 0) {
    int off = 0;
    for (int q = 0; q < EE; q++) {
      offs_s[q] = off;
      off += ((counts[q] + BM - 1) / BM) * BM;
    }
  }
  __syncthreads();
  if (blockIdx.x == 0) {
#pragma unroll
    for (int q = 0; q < EE; q++) {
      int cnt = counts[q];
      int lim = ((cnt + BM - 1) / BM) * BM;
      for (int p = cnt + tid; p < lim; p += 256)
        slot_token[offs_s[q] + p] = -1;
    }
  }
  int e0 = gate_e[t * 2], e1 = gate_e[t * 2 + 1];
  int p0 = atomicAdd(&lcnt[e0], 1);
  int p1 = atomicAdd(&lcnt[e1], 1);
  __syncthreads();
  if (tid < EE) lbase[tid] = atomicAdd(&fill[tid], lcnt[tid]);
  __syncthreads();
  int s0 = offs_s[e0] + lbase[e0] + p0;
  int s1 = offs_s[e1] + lbase[e1] + p1;
  slot_token[s0] = t;
  slot_w[s0] = gate_w[t * 2];
  slot_of[t * 2] = s0;
  slot_token[s1] = t;
  slot_w[s1] = gate_w[t * 2 + 1];
  slot_of[t * 2 + 1] = s1;
}

// ---------------- GEMM1: 128x256 tile, BK=32, dbuf + counted-vmcnt ----------
// 8 waves (2M x 4N). B staged in TWO LINEAR passes (gload_lds writes
// wave-uniform base + lane*16 -- per-lane LDS addrs must be tid*16-linear).
// h = gelu(x[slot] @ W1[e] + b1[e]); grid (HH/256, MAXTILES)
__global__ __launch_bounds__(512) void gemm1_kernel(
    const unsigned short* __restrict__ xb, const unsigned short* __restrict__ w1t,
    const float* __restrict__ b1, const int* __restrict__ slot_token,
    const int* __restrict__ counts, unsigned short* __restrict__ hb) {
  int e, row0;
  if (!tile_decode(counts, blockIdx.y, &e, &row0)) return;
  int n0 = blockIdx.x * 256;
  __shared__ unsigned short As[2][128][32];  // 16 KB
  __shared__ unsigned short Bs[2][256][32];  // 32 KB
  int tid = threadIdx.x;
  int lane = tid & 63;
  int wave = tid >> 6;
  int wm = wave >> 2, wn = wave & 3;
  int ra = tid >> 2, c = tid & 3;       // staging: row 0..127, chunk 0..3 (tid*16-linear)
  int tok_a = slot_token[row0 + ra]; if (tok_a < 0) tok_a = 0;
  const unsigned short* wbase = w1t + ((size_t)e * HH * DD);
  const unsigned short* gA  = xb + (size_t)tok_a * DD + c * 8;
  const unsigned short* gB0 = wbase + (size_t)(n0 + ra) * DD + c * 8;
  const unsigned short* gB1 = wbase + (size_t)(n0 + ra + 128) * DD + c * 8;
  f32x4 acc[4][4];
#pragma unroll
  for (int m = 0; m < 4; m++)
#pragma unroll
    for (int n = 0; n < 4; n++) {
      f32x4 z = {0.f, 0.f, 0.f, 0.f};
      acc[m][n] = z;
    }
  const int NK = DD / 32;
  // prologue: stage step 0 into buf 0 (3 loads/thread, each tid*16-linear)
  gload16(gA, &As[0][ra][c * 8]);
  gload16(gB0, &Bs[0][ra][c * 8]);
  gload16(gB1, &Bs[0][ra + 128][c * 8]);
  for (int kk = 0; kk < NK; kk++) {
    int cur = kk & 1;
    if (kk + 1 < NK) {
      int k1 = (kk + 1) * 32;
      int nx = cur ^ 1;
      gload16(gA + k1, &As[nx][ra][c * 8]);
      gload16(gB0 + k1, &Bs[nx][ra][c * 8]);
      gload16(gB1 + k1, &Bs[nx][ra + 128][c * 8]);
      asm volatile("s_waitcnt vmcnt(3)" ::: "memory");
    } else {
      asm volatile("s_waitcnt vmcnt(0)" ::: "memory");
    }
    __builtin_amdgcn_s_barrier();
    bf16x8 a[4], b[4];
#pragma unroll
    for (int m = 0; m < 4; m++)
      a[m] = *(const bf16x8*)(&As[cur][wm * 64 + m * 16 + (lane & 15)][(lane >> 4) * 8]);
#pragma unroll
    for (int n = 0; n < 4; n++)
      b[n] = *(const bf16x8*)(&Bs[cur][wn * 64 + n * 16 + (lane & 15)][(lane >> 4) * 8]);
#pragma unroll
    for (int m = 0; m < 4; m++)
#pragma unroll
      for (int n = 0; n < 4; n++)
        acc[m][n] = __builtin_amdgcn_mfma_f32_16x16x32_bf16(a[m], b[n], acc[m][n], 0, 0, 0);
    asm volatile("" ::: "memory");
    __builtin_amdgcn_s_barrier();
  }
  const float* b1e = b1 + (size_t)e * HH;
#pragma unroll
  for (int m = 0; m < 4; m++) {
#pragma unroll
    for (int r = 0; r < 4; r++) {
      int slot = row0 + wm * 64 + m * 16 + ((lane >> 4) << 2) + r;
      unsigned short* hrow = hb + (size_t)slot * HH;
#pragma unroll
      for (int n = 0; n < 4; n++) {
        int hc = n0 + wn * 64 + n * 16 + (lane & 15);
        float v = acc[m][n][r] + b1e[hc];
        hrow[hc] = f2bf(gelu_f(v));
      }
    }
  }
}

// ---------------- GEMM2: 128x256 tile, BK=32, dbuf + counted-vmcnt ----------
// yw[slot] = w*(h[slot] @ W2[e] + b2[e]); grid (DD/256, MAXTILES)
template <int USE_Y>
__global__ __launch_bounds__(512) void gemm2_kernel(
    const unsigned short* __restrict__ hb, const unsigned short* __restrict__ w2t,
    const float* __restrict__ b2, const int* __restrict__ slot_token,
    const float* __restrict__ slot_w, const int* __restrict__ counts,
    unsigned short* __restrict__ yw, float* __restrict__ out) {
  int e, row0;
  if (!tile_decode(counts, blockIdx.y, &e, &row0)) return;
  int n0 = blockIdx.x * 256;
  __shared__ unsigned short As[2][128][32];
  __shared__ unsigned short Bs[2][256][32];
  int tid = threadIdx.x;
  int lane = tid & 63;
  int wave = tid >> 6;
  int wm = wave >> 2, wn = wave & 3;
  int ra = tid >> 2, c = tid & 3;
  const unsigned short* wbase = w2t + ((size_t)e * DD * HH);
  const unsigned short* gA  = hb + (size_t)(row0 + ra) * HH + c * 8;
  const unsigned short* gB0 = wbase + (size_t)(n0 + ra) * HH + c * 8;
  const unsigned short* gB1 = wbase + (size_t)(n0 + ra + 128) * HH + c * 8;
  f32x4 acc[4][4];
#pragma unroll
  for (int m = 0; m < 4; m++)
#pragma unroll
    for (int n = 0; n < 4; n++) {
      f32x4 z = {0.f, 0.f, 0.f, 0.f};
      acc[m][n] = z;
    }
  const int NK = HH / 32;
  gload16(gA, &As[0][ra][c * 8]);
  gload16(gB0, &Bs[0][ra][c * 8]);
  gload16(gB1, &Bs[0][ra + 128][c * 8]);
  for (int kk = 0; kk < NK; kk++) {
    int cur = kk & 1;
    if (kk + 1 < NK) {
      int k1 = (kk + 1) * 32;
      int nx = cur ^ 1;
      gload16(gA + k1, &As[nx][ra][c * 8]);
      gload16(gB0 + k1, &Bs[nx][ra][c * 8]);
      gload16(gB1 + k1, &Bs[nx][ra + 128][c * 8]);
      asm volatile("s_waitcnt vmcnt(3)" ::: "memory");
    } else {
      asm volatile("s_waitcnt vmcnt(0)" ::: "memory");
    }
    __builtin_amdgcn_s_barrier();
    bf16x8 a[4], b[4];
#pragma unroll
    for (int m = 0; m < 4; m++)
      a[m] = *(const bf16x8*)(&As[cur][wm * 64 + m * 16 + (lane & 15)][(lane >> 4) * 8]);
#pragma unroll
    for (int n = 0; n < 4; n++)
      b[n] = *(const bf16x8*)(&Bs[cur][wn * 64 + n * 16 + (lane & 15)][(lane >> 4) * 8]);
#pragma unroll
    for (int m = 0; m < 4; m++)
#pragma unroll
      for (int n = 0; n < 4; n++)
        acc[m][n] = __builtin_amdgcn_mfma_f32_16x16x32_bf16(a[m], b[n], acc[m][n], 0, 0, 0);
    asm volatile("" ::: "memory");
    __builtin_amdgcn_s_barrier();
  }
  const float* b2e = b2 + (size_t)e * DD;
#pragma unroll
  for (int m = 0; m < 4; m++) {
#pragma unroll
    for (int r = 0; r < 4; r++) {
      int slot = row0 + wm * 64 + m * 16 + ((lane >> 4) << 2) + r;
      if (USE_Y) {
        float w = slot_w[slot];
        unsigned short* yrow = yw + (size_t)slot * DD;
#pragma unroll
        for (int n = 0; n < 4; n++) {
          int dc = n0 + wn * 64 + n * 16 + (lane & 15);
          yrow[dc] = f2bf(w * (acc[m][n][r] + b2e[dc]));
        }
      } else {
        int tok = slot_token[slot];
        if (tok >= 0) {
          float w = slot_w[slot];
          float* orow = out + (size_t)tok * DD;
#pragma unroll
          for (int n = 0; n < 4; n++) {
            int dc = n0 + wn * 64 + n * 16 + (lane & 15);
            float v = acc[m][n][r] + b2e[dc];
            atomicAdd(&orow[dc], w * v);
          }
        }
      }
    }
  }
}

// ---------------- combine: out[t] = yw[s1] + yw[s2] ----------------
__global__ __launch_bounds__(256) void combine_kernel(
    const unsigned short* __restrict__ yw, const int* __restrict__ slot_of,
    float* __restrict__ out) {
  int gid = blockIdx.x * 256 + threadIdx.x;
  int t = gid >> 6;
  int d0 = (gid & 63) * 8;
  int s1 = slot_of[t * 2], s2 = slot_of[t * 2 + 1];
  const ushort4* p1 = (const ushort4*)(yw + (size_t)s1 * DD + d0);
  const ushort4* p2 = (const ushort4*)(yw + (size_t)s2 * DD + d0);
  ushort4 a0 = p1[0], a1 = p1[1];
  ushort4 b0 = p2[0], b1 = p2[1];
  float4 o0, o1;
  o0.x = bf2f(a0.x) + bf2f(b0.x);
  o0.y = bf2f(a0.y) + bf2f(b0.y);
  o0.z = bf2f(a0.z) + bf2f(b0.z);
  o0.w = bf2f(a0.w) + bf2f(b0.w);
  o1.x = bf2f(a1.x) + bf2f(b1.x);
  o1.y = bf2f(a1.y) + bf2f(b1.y);
  o1.z = bf2f(a1.z) + bf2f(b1.z);
  o1.w = bf2f(a1.w) + bf2f(b1.w);
  float* orow = out + (size_t)t * DD + d0;
  ((float4*)orow)[0] = o0;
  ((float4*)orow)[1] = o1;
}

extern "C" void kernel_launch(void* const* d_in, const int* in_sizes, int n_in,
                              void* d_out, int out_size, void* d_ws, size_t ws_size,
                              hipStream_t stream) {
  const float* x  = (const float*)d_in[0];
  const float* Wg = (const float*)d_in[1];
  const float* bg = (const float*)d_in[2];
  const float* W1 = (const float*)d_in[3];
  const float* b1 = (const float*)d_in[4];
  const float* W2 = (const float*)d_in[5];
  const float* b2 = (const float*)d_in[6];
  float* out = (float*)d_out;

  uint8_t* w = (uint8_t*)d_ws;
  size_t o = 0;
  unsigned short* xb  = (unsigned short*)(w + o); o += (size_t)TT * DD * 2;       // 8 MB
  unsigned short* w1t = (unsigned short*)(w + o); o += (size_t)EE * DD * HH * 2;  // 16 MB
  unsigned short* w2t = (unsigned short*)(w + o); o += (size_t)EE * DD * HH * 2;  // 16 MB
  unsigned short* hb  = (unsigned short*)(w + o); o += (size_t)NSLOT * HH * 2;    // 37.7 MB
  int*   slot_token = (int*)(w + o);   o += (size_t)NSLOT * 4;
  float* slot_w     = (float*)(w + o); o += (size_t)NSLOT * 4;
  int*   slot_of    = (int*)(w + o);   o += (size_t)TT * 2 * 4;
  int*   gate_e     = (int*)(w + o);   o += (size_t)TT * 2 * 4;
  float* gate_w     = (float*)(w + o); o += (size_t)TT * 2 * 4;
  int*   counts     = (int*)(w + o);   o += 64;   // counts[16]
  int*   nretry     = (int*)(w + o);   o += 64;
  int*   fill       = (int*)(w + o);   o += 64;   // one 192B memset covers all 3
  int*   retry      = (int*)(w + o);   o += RETRYCAP * 4;
  unsigned short* yw = (unsigned short*)(w + o);
  size_t need_y = o + (size_t)NSLOT * DD * 2;   // +18.9 MB
  int use_y = (ws_size >= need_y);

  hipMemsetAsync(counts, 0, 192, stream);  // counts + nretry + fill
  if (!use_y) {
    hipMemsetAsync(slot_token, 0xFF, (size_t)NSLOT * 4, stream);
    hipMemsetAsync(d_out, 0, (size_t)TT * DD * 4, stream);
  }

  // gate (blocks 0..127, dispatched first) + W1/W2 transposes (128..4223)
  prep_kernel<<<128 + 4096, 256, 0, stream>>>(
      W1, W2, w1t, w2t, x, Wg, bg, xb, gate_e, gate_w, counts, nretry, retry);
  gatefix_kernel<<<RETRYCAP / 16, 256, 0, stream>>>(x, Wg, bg, nretry, retry,
                                                    gate_e, gate_w, counts);
  scatter_kernel<<<TT / 256, 256, 0, stream>>>(gate_e, gate_w, counts, fill,
                                               slot_token, slot_w, slot_of);
  {
    dim3 g(HH / 256, MAXTILES);
    gemm1_kernel<<<g, 512, 0, stream>>>(xb, w1t, b1, slot_token, counts, hb);
  }
  {
    dim3 g(DD / 256, MAXTILES);
    if (use_y)
      gemm2_kernel<1><<<g, 512, 0, stream>>>(hb, w2t, b2, slot_token, slot_w,
                                             counts, yw, out);
    else
      gemm2_kernel<0><<<g, 512, 0, stream>>>(hb, w2t, b2, slot_token, slot_w,
                                             counts, yw, out);
  }
  if (use_y) {
    combine_kernel<<<TT * (DD / 8) / 256, 256, 0, stream>>>(yw, slot_of, out);
  }
}

// Round 20
// 155.504 us; speedup vs baseline: 1.5188x; 1.0339x over previous
//
#include <hip/hip_runtime.h>
#include <hip/hip_bf16.h>
#include <math.h>

#define TT 8192
#define DD 512
#define HH 1024
#define EE 16
#define NSLOT 18432   // 144 * 128 max padded slots
#define MAXTILES 144
#define BM 128
#define RETRYCAP 1024

typedef __attribute__((ext_vector_type(8))) short bf16x8;
typedef __attribute__((ext_vector_type(8))) unsigned short u16x8;
typedef __attribute__((ext_vector_type(4))) float f32x4;

__device__ __forceinline__ unsigned short f2bf(float f) {
  union { float f; unsigned u; } v; v.f = f;
  unsigned r = v.u + 0x7fffu + ((v.u >> 16) & 1u);
  return (unsigned short)(r >> 16);
}

__device__ __forceinline__ float bf2f(unsigned short u) {
  union { unsigned u; float f; } v; v.u = ((unsigned)u) << 16;
  return v.f;
}

__device__ __forceinline__ void gload16(const void* g, void* l) {
  __builtin_amdgcn_global_load_lds(
      (const __attribute__((address_space(1))) unsigned int*)g,
      (__attribute__((address_space(3))) unsigned int*)l, 16, 0, 0);
}

// Abramowitz-Stegun 7.1.26 erf approx (|err| <= 1.5e-7)
__device__ __forceinline__ float gelu_f(float v) {
  float s = fabsf(v) * 0.70710678118654752f;
  float t = 1.0f / (1.0f + 0.3275911f * s);
  float poly = t * (0.254829592f +
              t * (-0.284496736f +
              t * (1.421413741f +
              t * (-1.453152027f +
              t * 1.061405429f))));
  float erfa = 1.0f - poly * __expf(-s * s);
  float erfv = (v >= 0.f) ? erfa : -erfa;
  return 0.5f * v * (1.0f + erfv);
}

// expert/row0 from counts: tile mt -> (expert, row0, valid)
__device__ __forceinline__ int tile_decode(const int* __restrict__ counts,
                                           int mt, int* e_out, int* row0_out) {
  int off = 0, rem = mt;
#pragma unroll
  for (int q = 0; q < EE; q++) {
    int tl = (counts[q] + BM - 1) / BM;
    if (rem < tl) { *e_out = q; *row0_out = off + rem * BM; return 1; }
    rem -= tl;
    off += tl * BM;
  }
  return 0;
}

// ---------------- prep: GATE blocks first (bid<128), then transposes --------
// Gate now stages Wg in LDS (coalesced) instead of 128 scalar global
// gathers per thread -- that gather was the hidden ~40us long pole.
struct GateSm { float wg[DD * EE]; int cnt[EE]; };
union __align__(16) PrepSm {
  unsigned short t[64][68];
  GateSm g;
};

__global__ __launch_bounds__(256) void prep_kernel(
    const float* __restrict__ W1, const float* __restrict__ W2,
    unsigned short* __restrict__ w1t, unsigned short* __restrict__ w2t,
    const float* __restrict__ x, const float* __restrict__ Wg,
    const float* __restrict__ bg, unsigned short* __restrict__ xb,
    int* __restrict__ gate_e, float* __restrict__ gate_w,
    int* __restrict__ counts, int* __restrict__ nretry,
    int* __restrict__ retry) {
  __shared__ PrepSm sm;
  int bid = blockIdx.x;
  int tid = threadIdx.x;
  if (bid < 128) {
    // ---- gate: 64 tokens/block, barrier-free MFMA; Wg from LDS ----
    float* wg_s = sm.g.wg;
    if (tid < EE) sm.g.cnt[tid] = 0;
#pragma unroll
    for (int p = 0; p < 8; p++)
      ((float4*)wg_s)[p * 256 + tid] = ((const float4*)Wg)[p * 256 + tid];
    __syncthreads();
    int lane = tid & 63;
    int wave = tid >> 6;
    int tok0 = bid * 64 + wave * 16;
    int e = lane & 15;
    int kb = (lane >> 4) * 8;
    bf16x8 bfrag[16];
#pragma unroll
    for (int ks = 0; ks < 16; ks++) {
      int kbase = ks * 32 + kb;
#pragma unroll
      for (int j = 0; j < 8; j++)
        bfrag[ks][j] = (short)f2bf(wg_s[(kbase + j) * EE + e]);
    }
    float bge = bg[e];
    f32x4 acc = {0.f, 0.f, 0.f, 0.f};
    const float* xrow = x + (size_t)(tok0 + (lane & 15)) * DD + kb;
    unsigned short* xbrow = xb + (size_t)(tok0 + (lane & 15)) * DD + kb;
#pragma unroll 4
    for (int ks = 0; ks < 16; ks++) {
      int k0 = ks * 32;
      float4 v0 = *(const float4*)(xrow + k0);
      float4 v1 = *(const float4*)(xrow + k0 + 4);
      u16x8 w0;
      w0[0] = f2bf(v0.x); w0[1] = f2bf(v0.y); w0[2] = f2bf(v0.z); w0[3] = f2bf(v0.w);
      w0[4] = f2bf(v1.x); w0[5] = f2bf(v1.y); w0[6] = f2bf(v1.z); w0[7] = f2bf(v1.w);
      *(u16x8*)(xbrow + k0) = w0;
      union { u16x8 u; bf16x8 b; } cv; cv.u = w0;
      acc = __builtin_amdgcn_mfma_f32_16x16x32_bf16(cv.b, bfrag[ks], acc, 0, 0, 0);
    }
#pragma unroll
    for (int r = 0; r < 4; r++) {
      float lf = acc[r] + bge;
      float v1 = -1e30f, v2 = -1e30f, v3 = -1e30f;
      int i1 = 0, i2 = 0;
#pragma unroll
      for (int q = 0; q < EE; q++) {
        float v = __shfl(lf, (lane & 48) | q);
        if (v > v1) { v3 = v2; v2 = v1; i2 = i1; v1 = v; i1 = q; }
        else if (v > v2) { v3 = v2; v2 = v; i2 = q; }
        else if (v > v3) { v3 = v; }
      }
      if ((lane & 15) == 0) {
        int t2 = tok0 + ((lane >> 4) << 2) + r;
        float p = expf(v2 - v1);
        float s = 1.0f / (1.0f + p);
        gate_e[t2 * 2] = i1;
        gate_e[t2 * 2 + 1] = i2;
        gate_w[t2 * 2] = s;
        gate_w[t2 * 2 + 1] = p * s;
        atomicAdd(&sm.g.cnt[i1], 1);
        atomicAdd(&sm.g.cnt[i2], 1);
        if (v2 - v3 < 0.02f) {
          int pos = atomicAdd(nretry, 1);
          if (pos < RETRYCAP) retry[pos] = t2;
        }
      }
    }
    __syncthreads();
    if (tid < EE) atomicAdd(&counts[tid], sm.g.cnt[tid]);
    return;
  }
  // ---- transposes ----
  const float* src;
  unsigned short* dst;
  int R, C, c0, r0;
  int b = bid - 128;
  if (b < 2048) {
    int cx = b & 15, ry = (b >> 4) & 7, mat = b >> 7;
    src = W1 + (size_t)mat * DD * HH; dst = w1t + (size_t)mat * DD * HH;
    R = DD; C = HH; c0 = cx * 64; r0 = ry * 64;
  } else {
    b -= 2048;
    int cx = b & 7, ry = (b >> 3) & 15, mat = b >> 7;
    src = W2 + (size_t)mat * DD * HH; dst = w2t + (size_t)mat * DD * HH;
    R = HH; C = DD; c0 = cx * 64; r0 = ry * 64;
  }
#pragma unroll
  for (int p = 0; p < 4; p++) {
    int r = tid >> 2;
    int c4 = (tid & 3) + p * 4;
    float4 v = *(const float4*)(src + (size_t)(r0 + r) * C + c0 + c4 * 4);
    sm.t[c4 * 4 + 0][r] = f2bf(v.x);
    sm.t[c4 * 4 + 1][r] = f2bf(v.y);
    sm.t[c4 * 4 + 2][r] = f2bf(v.z);
    sm.t[c4 * 4 + 3][r] = f2bf(v.w);
  }
  __syncthreads();
#pragma unroll
  for (int p = 0; p < 4; p++) {
    int oc = (tid >> 4) + p * 16;
    int ch = tid & 15;
    ushort4 v = *(ushort4*)(&sm.t[oc][ch * 4]);
    *(ushort4*)(dst + (size_t)(c0 + oc) * R + r0 + ch * 4) = v;
  }
}

// ---------------- gatefix: exact f64 recompute for near-tie tokens ----------
__global__ __launch_bounds__(256) void gatefix_kernel(
    const float* __restrict__ x, const float* __restrict__ Wg,
    const float* __restrict__ bg, const int* __restrict__ nretry,
    const int* __restrict__ retry, int* __restrict__ gate_e,
    float* __restrict__ gate_w, int* __restrict__ counts) {
  __shared__ float lg[16][17];
  __shared__ int toks[16];
  int tid = threadIdx.x;
  int sl = tid >> 4, e = tid & 15;
  int s = blockIdx.x * 16 + sl;
  int n = *nretry; if (n > RETRYCAP) n = RETRYCAP;
  int active = (s < n);
  int tok = 0;
  if (active) tok = retry[s];
  if (active) {
    const float* xr = x + (size_t)tok * DD;
    double a0 = 0.0, a1 = 0.0, a2 = 0.0, a3 = 0.0;
    for (int i = 0; i < DD / 4; i++) {
      a0 += (double)xr[i * 4 + 0] * (double)Wg[(i * 4 + 0) * EE + e];
      a1 += (double)xr[i * 4 + 1] * (double)Wg[(i * 4 + 1) * EE + e];
      a2 += (double)xr[i * 4 + 2] * (double)Wg[(i * 4 + 2) * EE + e];
      a3 += (double)xr[i * 4 + 3] * (double)Wg[(i * 4 + 3) * EE + e];
    }
    double acc = (a0 + a1) + (a2 + a3);
    lg[sl][e] = (float)(acc + (double)bg[e]);
    toks[sl] = tok;
  }
  __syncthreads();
  if (active && e == 0) {
    float v1 = -1e30f, v2 = -1e30f;
    int i1 = 0, i2 = 0;
#pragma unroll
    for (int q = 0; q < EE; q++) {
      float v = lg[sl][q];
      if (v > v1) { v2 = v1; i2 = i1; v1 = v; i1 = q; }
      else if (v > v2) { v2 = v; i2 = q; }
    }
    int t2 = toks[sl];
    int o1 = gate_e[t2 * 2], o2 = gate_e[t2 * 2 + 1];
    float p = expf(v2 - v1);
    float sc = 1.0f / (1.0f + p);
    gate_e[t2 * 2] = i1;
    gate_e[t2 * 2 + 1] = i2;
    gate_w[t2 * 2] = sc;
    gate_w[t2 * 2 + 1] = p * sc;
    if (o1 != i1 || o2 != i2) {
      atomicSub(&counts[o1], 1);
      atomicSub(&counts[o2], 1);
      atomicAdd(&counts[i1], 1);
      atomicAdd(&counts[i2], 1);
    }
  }
}

// ---------------- scatter: hierarchical; block 0 also writes pad slots ------
__global__ __launch_bounds__(256) void scatter_kernel(
    const int* __restrict__ gate_e, const float* __restrict__ gate_w,
    const int* __restrict__ counts, int* __restrict__ fill,
    int* __restrict__ slot_token, float* __restrict__ slot_w,
    int* __restrict__ slot_of) {
  __shared__ int lcnt[EE];
  __shared__ int lbase[EE];
  __shared__ int offs_s[EE];
  int tid = threadIdx.x;
  int t = blockIdx.x * 256 + tid;
  if (tid < EE) lcnt[tid] = 0;
  if (tid == 0) {
    int off = 0;
    for (int q = 0; q < EE; q++) {
      offs_s[q] = off;
      off += ((counts[q] + BM - 1) / BM) * BM;
    }
  }
  __syncthreads();
  if (blockIdx.x == 0) {
#pragma unroll
    for (int q = 0; q < EE; q++) {
      int cnt = counts[q];
      int lim = ((cnt + BM - 1) / BM) * BM;
      for (int p = cnt + tid; p < lim; p += 256)
        slot_token[offs_s[q] + p] = -1;
    }
  }
  int e0 = gate_e[t * 2], e1 = gate_e[t * 2 + 1];
  int p0 = atomicAdd(&lcnt[e0], 1);
  int p1 = atomicAdd(&lcnt[e1], 1);
  __syncthreads();
  if (tid < EE) lbase[tid] = atomicAdd(&fill[tid], lcnt[tid]);
  __syncthreads();
  int s0 = offs_s[e0] + lbase[e0] + p0;
  int s1 = offs_s[e1] + lbase[e1] + p1;
  slot_token[s0] = t;
  slot_w[s0] = gate_w[t * 2];
  slot_of[t * 2] = s0;
  slot_token[s1] = t;
  slot_w[s1] = gate_w[t * 2 + 1];
  slot_of[t * 2 + 1] = s1;
}

// ---------------- GEMM1: 128x256 tile, BK=32, dbuf + counted-vmcnt ----------
// h = gelu(x[slot] @ W1[e] + b1[e]); grid (HH/256, MAXTILES)
__global__ __launch_bounds__(512) void gemm1_kernel(
    const unsigned short* __restrict__ xb, const unsigned short* __restrict__ w1t,
    const float* __restrict__ b1, const int* __restrict__ slot_token,
    const int* __restrict__ counts, unsigned short* __restrict__ hb) {
  int e, row0;
  if (!tile_decode(counts, blockIdx.y, &e, &row0)) return;
  int n0 = blockIdx.x * 256;
  __shared__ unsigned short As[2][128][32];  // 16 KB
  __shared__ unsigned short Bs[2][256][32];  // 32 KB
  int tid = threadIdx.x;
  int lane = tid & 63;
  int wave = tid >> 6;
  int wm = wave >> 2, wn = wave & 3;
  int ra = tid >> 2, c = tid & 3;       // staging: row 0..127, chunk 0..3 (tid*16-linear)
  int tok_a = slot_token[row0 + ra]; if (tok_a < 0) tok_a = 0;
  const unsigned short* wbase = w1t + ((size_t)e * HH * DD);
  const unsigned short* gA  = xb + (size_t)tok_a * DD + c * 8;
  const unsigned short* gB0 = wbase + (size_t)(n0 + ra) * DD + c * 8;
  const unsigned short* gB1 = wbase + (size_t)(n0 + ra + 128) * DD + c * 8;
  f32x4 acc[4][4];
#pragma unroll
  for (int m = 0; m < 4; m++)
#pragma unroll
    for (int n = 0; n < 4; n++) {
      f32x4 z = {0.f, 0.f, 0.f, 0.f};
      acc[m][n] = z;
    }
  const int NK = DD / 32;
  gload16(gA, &As[0][ra][c * 8]);
  gload16(gB0, &Bs[0][ra][c * 8]);
  gload16(gB1, &Bs[0][ra + 128][c * 8]);
  for (int kk = 0; kk < NK; kk++) {
    int cur = kk & 1;
    if (kk + 1 < NK) {
      int k1 = (kk + 1) * 32;
      int nx = cur ^ 1;
      gload16(gA + k1, &As[nx][ra][c * 8]);
      gload16(gB0 + k1, &Bs[nx][ra][c * 8]);
      gload16(gB1 + k1, &Bs[nx][ra + 128][c * 8]);
      asm volatile("s_waitcnt vmcnt(3)" ::: "memory");
    } else {
      asm volatile("s_waitcnt vmcnt(0)" ::: "memory");
    }
    __builtin_amdgcn_s_barrier();
    bf16x8 a[4], b[4];
#pragma unroll
    for (int m = 0; m < 4; m++)
      a[m] = *(const bf16x8*)(&As[cur][wm * 64 + m * 16 + (lane & 15)][(lane >> 4) * 8]);
#pragma unroll
    for (int n = 0; n < 4; n++)
      b[n] = *(const bf16x8*)(&Bs[cur][wn * 64 + n * 16 + (lane & 15)][(lane >> 4) * 8]);
#pragma unroll
    for (int m = 0; m < 4; m++)
#pragma unroll
      for (int n = 0; n < 4; n++)
        acc[m][n] = __builtin_amdgcn_mfma_f32_16x16x32_bf16(a[m], b[n], acc[m][n], 0, 0, 0);
    asm volatile("" ::: "memory");
    __builtin_amdgcn_s_barrier();
  }
  const float* b1e = b1 + (size_t)e * HH;
#pragma unroll
  for (int m = 0; m < 4; m++) {
#pragma unroll
    for (int r = 0; r < 4; r++) {
      int slot = row0 + wm * 64 + m * 16 + ((lane >> 4) << 2) + r;
      unsigned short* hrow = hb + (size_t)slot * HH;
#pragma unroll
      for (int n = 0; n < 4; n++) {
        int hc = n0 + wn * 64 + n * 16 + (lane & 15);
        float v = acc[m][n][r] + b1e[hc];
        hrow[hc] = f2bf(gelu_f(v));
      }
    }
  }
}

// ---------------- GEMM2: 128x256 tile, BK=32, dbuf + counted-vmcnt ----------
// yw[slot] = w*(h[slot] @ W2[e] + b2[e]); grid (DD/256, MAXTILES)
template <int USE_Y>
__global__ __launch_bounds__(512) void gemm2_kernel(
    const unsigned short* __restrict__ hb, const unsigned short* __restrict__ w2t,
    const float* __restrict__ b2, const int* __restrict__ slot_token,
    const float* __restrict__ slot_w, const int* __restrict__ counts,
    unsigned short* __restrict__ yw, float* __restrict__ out) {
  int e, row0;
  if (!tile_decode(counts, blockIdx.y, &e, &row0)) return;
  int n0 = blockIdx.x * 256;
  __shared__ unsigned short As[2][128][32];
  __shared__ unsigned short Bs[2][256][32];
  int tid = threadIdx.x;
  int lane = tid & 63;
  int wave = tid >> 6;
  int wm = wave >> 2, wn = wave & 3;
  int ra = tid >> 2, c = tid & 3;
  const unsigned short* wbase = w2t + ((size_t)e * DD * HH);
  const unsigned short* gA  = hb + (size_t)(row0 + ra) * HH + c * 8;
  const unsigned short* gB0 = wbase + (size_t)(n0 + ra) * HH + c * 8;
  const unsigned short* gB1 = wbase + (size_t)(n0 + ra + 128) * HH + c * 8;
  f32x4 acc[4][4];
#pragma unroll
  for (int m = 0; m < 4; m++)
#pragma unroll
    for (int n = 0; n < 4; n++) {
      f32x4 z = {0.f, 0.f, 0.f, 0.f};
      acc[m][n] = z;
    }
  const int NK = HH / 32;
  gload16(gA, &As[0][ra][c * 8]);
  gload16(gB0, &Bs[0][ra][c * 8]);
  gload16(gB1, &Bs[0][ra + 128][c * 8]);
  for (int kk = 0; kk < NK; kk++) {
    int cur = kk & 1;
    if (kk + 1 < NK) {
      int k1 = (kk + 1) * 32;
      int nx = cur ^ 1;
      gload16(gA + k1, &As[nx][ra][c * 8]);
      gload16(gB0 + k1, &Bs[nx][ra][c * 8]);
      gload16(gB1 + k1, &Bs[nx][ra + 128][c * 8]);
      asm volatile("s_waitcnt vmcnt(3)" ::: "memory");
    } else {
      asm volatile("s_waitcnt vmcnt(0)" ::: "memory");
    }
    __builtin_amdgcn_s_barrier();
    bf16x8 a[4], b[4];
#pragma unroll
    for (int m = 0; m < 4; m++)
      a[m] = *(const bf16x8*)(&As[cur][wm * 64 + m * 16 + (lane & 15)][(lane >> 4) * 8]);
#pragma unroll
    for (int n = 0; n < 4; n++)
      b[n] = *(const bf16x8*)(&Bs[cur][wn * 64 + n * 16 + (lane & 15)][(lane >> 4) * 8]);
#pragma unroll
    for (int m = 0; m < 4; m++)
#pragma unroll
      for (int n = 0; n < 4; n++)
        acc[m][n] = __builtin_amdgcn_mfma_f32_16x16x32_bf16(a[m], b[n], acc[m][n], 0, 0, 0);
    asm volatile("" ::: "memory");
    __builtin_amdgcn_s_barrier();
  }
  const float* b2e = b2 + (size_t)e * DD;
#pragma unroll
  for (int m = 0; m < 4; m++) {
#pragma unroll
    for (int r = 0; r < 4; r++) {
      int slot = row0 + wm * 64 + m * 16 + ((lane >> 4) << 2) + r;
      if (USE_Y) {
        float w = slot_w[slot];
        unsigned short* yrow = yw + (size_t)slot * DD;
#pragma unroll
        for (int n = 0; n < 4; n++) {
          int dc = n0 + wn * 64 + n * 16 + (lane & 15);
          yrow[dc] = f2bf(w * (acc[m][n][r] + b2e[dc]));
        }
      } else {
        int tok = slot_token[slot];
        if (tok >= 0) {
          float w = slot_w[slot];
          float* orow = out + (size_t)tok * DD;
#pragma unroll
          for (int n = 0; n < 4; n++) {
            int dc = n0 + wn * 64 + n * 16 + (lane & 15);
            float v = acc[m][n][r] + b2e[dc];
            atomicAdd(&orow[dc], w * v);
          }
        }
      }
    }
  }
}

// ---------------- combine: out[t] = yw[s1] + yw[s2] ----------------
__global__ __launch_bounds__(256) void combine_kernel(
    const unsigned short* __restrict__ yw, const int* __restrict__ slot_of,
    float* __restrict__ out) {
  int gid = blockIdx.x * 256 + threadIdx.x;
  int t = gid >> 6;
  int d0 = (gid & 63) * 8;
  int s1 = slot_of[t * 2], s2 = slot_of[t * 2 + 1];
  const ushort4* p1 = (const ushort4*)(yw + (size_t)s1 * DD + d0);
  const ushort4* p2 = (const ushort4*)(yw + (size_t)s2 * DD + d0);
  ushort4 a0 = p1[0], a1 = p1[1];
  ushort4 b0 = p2[0], b1 = p2[1];
  float4 o0, o1;
  o0.x = bf2f(a0.x) + bf2f(b0.x);
  o0.y = bf2f(a0.y) + bf2f(b0.y);
  o0.z = bf2f(a0.z) + bf2f(b0.z);
  o0.w = bf2f(a0.w) + bf2f(b0.w);
  o1.x = bf2f(a1.x) + bf2f(b1.x);
  o1.y = bf2f(a1.y) + bf2f(b1.y);
  o1.z = bf2f(a1.z) + bf2f(b1.z);
  o1.w = bf2f(a1.w) + bf2f(b1.w);
  float* orow = out + (size_t)t * DD + d0;
  ((float4*)orow)[0] = o0;
  ((float4*)orow)[1] = o1;
}

extern "C" void kernel_launch(void* const* d_in, const int* in_sizes, int n_in,
                              void* d_out, int out_size, void* d_ws, size_t ws_size,
                              hipStream_t stream) {
  const float* x  = (const float*)d_in[0];
  const float* Wg = (const float*)d_in[1];
  const float* bg = (const float*)d_in[2];
  const float* W1 = (const float*)d_in[3];
  const float* b1 = (const float*)d_in[4];
  const float* W2 = (const float*)d_in[5];
  const float* b2 = (const float*)d_in[6];
  float* out = (float*)d_out;

  uint8_t* w = (uint8_t*)d_ws;
  size_t o = 0;
  unsigned short* xb  = (unsigned short*)(w + o); o += (size_t)TT * DD * 2;       // 8 MB
  unsigned short* w1t = (unsigned short*)(w + o); o += (size_t)EE * DD * HH * 2;  // 16 MB
  unsigned short* w2t = (unsigned short*)(w + o); o += (size_t)EE * DD * HH * 2;  // 16 MB
  unsigned short* hb  = (unsigned short*)(w + o); o += (size_t)NSLOT * HH * 2;    // 37.7 MB
  int*   slot_token = (int*)(w + o);   o += (size_t)NSLOT * 4;
  float* slot_w     = (float*)(w + o); o += (size_t)NSLOT * 4;
  int*   slot_of    = (int*)(w + o);   o += (size_t)TT * 2 * 4;
  int*   gate_e     = (int*)(w + o);   o += (size_t)TT * 2 * 4;
  float* gate_w     = (float*)(w + o); o += (size_t)TT * 2 * 4;
  int*   counts     = (int*)(w + o);   o += 64;   // counts[16]
  int*   nretry     = (int*)(w + o);   o += 64;
  int*   fill       = (int*)(w + o);   o += 64;   // one 192B memset covers all 3
  int*   retry      = (int*)(w + o);   o += RETRYCAP * 4;
  unsigned short* yw = (unsigned short*)(w + o);
  size_t need_y = o + (size_t)NSLOT * DD * 2;   // +18.9 MB
  int use_y = (ws_size >= need_y);

  hipMemsetAsync(counts, 0, 192, stream);  // counts + nretry + fill
  if (!use_y) {
    hipMemsetAsync(slot_token, 0xFF, (size_t)NSLOT * 4, stream);
    hipMemsetAsync(d_out, 0, (size_t)TT * DD * 4, stream);
  }

  // gate (blocks 0..127, dispatched first) + W1/W2 transposes (128..4223)
  prep_kernel<<<128 + 4096, 256, 0, stream>>>(
      W1, W2, w1t, w2t, x, Wg, bg, xb, gate_e, gate_w, counts, nretry, retry);
  gatefix_kernel<<<RETRYCAP / 16, 256, 0, stream>>>(x, Wg, bg, nretry, retry,
                                                    gate_e, gate_w, counts);
  scatter_kernel<<<TT / 256, 256, 0, stream>>>(gate_e, gate_w, counts, fill,
                                               slot_token, slot_w, slot_of);
  {
    dim3 g(HH / 256, MAXTILES);
    gemm1_kernel<<<g, 512, 0, stream>>>(xb, w1t, b1, slot_token, counts, hb);
  }
  {
    dim3 g(DD / 256, MAXTILES);
    if (use_y)
      gemm2_kernel<1><<<g, 512, 0, stream>>>(hb, w2t, b2, slot_token, slot_w,
                                             counts, yw, out);
    else
      gemm2_kernel<0><<<g, 512, 0, stream>>>(hb, w2t, b2, slot_token, slot_w,
                                             counts, yw, out);
  }
  if (use_y) {
    combine_kernel<<<TT * (DD / 8) / 256, 256, 0, stream>>>(yw, slot_of, out);
  }
}